// Round 1
// baseline (1847.667 us; speedup 1.0000x reference)
//
#include <hip/hip_runtime.h>

#define N_NODES 50000
#define N_EDGES 600000
#define HID 128

// ---------------------------------------------------------------------------
// Weight transpose: Wt[k][c] = W[c][k] so lanes (c-major) read coalesced.
// 7 matrices: Wp1,Wl1,Wr1,Wp2,Wl2,Wr2 (128x128), Wlin (256x128).
// Output layout in ws: 6 x 16384 floats, then 32768 floats.
// ---------------------------------------------------------------------------
__global__ void transpose_weights(const float* __restrict__ Wp1,
                                  const float* __restrict__ Wl1,
                                  const float* __restrict__ Wr1,
                                  const float* __restrict__ Wp2,
                                  const float* __restrict__ Wl2,
                                  const float* __restrict__ Wr2,
                                  const float* __restrict__ Wlin,
                                  float* __restrict__ out) {
    int which = blockIdx.y;
    const float* W;
    float* O;
    int OUTC = 128;
    switch (which) {
        case 0: W = Wp1; O = out + 0 * 16384; break;
        case 1: W = Wl1; O = out + 1 * 16384; break;
        case 2: W = Wr1; O = out + 2 * 16384; break;
        case 3: W = Wp2; O = out + 3 * 16384; break;
        case 4: W = Wl2; O = out + 4 * 16384; break;
        case 5: W = Wr2; O = out + 5 * 16384; break;
        default: W = Wlin; O = out + 6 * 16384; OUTC = 256; break;
    }
    int idx = blockIdx.x * 256 + threadIdx.x;
    int total = OUTC * 128;
    if (idx < total) {
        int c = idx / 128;
        int k = idx % 128;
        O[k * OUTC + c] = W[c * 128 + k];
    }
}

__device__ __forceinline__ float gelu_tanh(float x) {
    float x3 = x * x * x;
    float u = 0.7978845608028654f * (x + 0.044715f * x3);
    float t = tanhf(u);
    return 0.5f * x * (1.0f + t);
}

// ---------------------------------------------------------------------------
// out[n][c] = act( bias[c] + sum_k in1[n][k]*W1t[k][c] (+ sum_k in2[n][k]*W2t[k][c]) )
// block = 256 threads, 16 rows per block.
// OUTC=128: 4 row-groups x 4 rows, thread owns 2 consecutive c.
// OUTC=256: 2 row-groups x 8 rows, thread owns 2 consecutive c.
// ACT: 0 = none, 1 = gelu
// ---------------------------------------------------------------------------
template <int OUTC, bool DUAL, int ACT>
__global__ __launch_bounds__(256) void linear_kernel(
        const float* __restrict__ in1, const float* __restrict__ in2,
        const float* __restrict__ W1t, const float* __restrict__ W2t,
        const float* __restrict__ bias, float* __restrict__ out) {
    constexpr int ROWS = 16;
    __shared__ float x1[ROWS][HID];
    __shared__ float x2[DUAL ? ROWS : 1][HID];

    const int rowBase = blockIdx.x * ROWS;
    const int t = threadIdx.x;

    // cooperative stage of input tiles (coalesced float4)
    for (int i = t; i < ROWS * HID / 4; i += 256) {
        int r = i >> 5;          // 32 float4 per row
        int kc = i & 31;
        ((float4*)x1[r])[kc] = ((const float4*)(in1 + (size_t)(rowBase + r) * HID))[kc];
        if (DUAL)
            ((float4*)x2[r])[kc] = ((const float4*)(in2 + (size_t)(rowBase + r) * HID))[kc];
    }
    __syncthreads();

    constexpr int CG = (OUTC == 128) ? 64 : 128;  // threads covering c (2 c each)
    constexpr int NG = 256 / CG;                  // row groups
    constexpr int RPG = ROWS / NG;                // rows per group
    const int c0 = (t % CG) * 2;
    const int g = t / CG;

    float acc[RPG][2];
    float2 b2 = *(const float2*)(bias + c0);
#pragma unroll
    for (int r = 0; r < RPG; ++r) { acc[r][0] = b2.x; acc[r][1] = b2.y; }

#pragma unroll 4
    for (int k0 = 0; k0 < HID; k0 += 4) {
        float2 w[4];
#pragma unroll
        for (int kk = 0; kk < 4; ++kk)
            w[kk] = *(const float2*)(W1t + (size_t)(k0 + kk) * OUTC + c0);
#pragma unroll
        for (int r = 0; r < RPG; ++r) {
            float4 xv = *(const float4*)&x1[g * RPG + r][k0];
            acc[r][0] += xv.x * w[0].x + xv.y * w[1].x + xv.z * w[2].x + xv.w * w[3].x;
            acc[r][1] += xv.x * w[0].y + xv.y * w[1].y + xv.z * w[2].y + xv.w * w[3].y;
        }
    }
    if (DUAL) {
#pragma unroll 4
        for (int k0 = 0; k0 < HID; k0 += 4) {
            float2 w[4];
#pragma unroll
            for (int kk = 0; kk < 4; ++kk)
                w[kk] = *(const float2*)(W2t + (size_t)(k0 + kk) * OUTC + c0);
#pragma unroll
            for (int r = 0; r < RPG; ++r) {
                float4 xv = *(const float4*)&x2[g * RPG + r][k0];
                acc[r][0] += xv.x * w[0].x + xv.y * w[1].x + xv.z * w[2].x + xv.w * w[3].x;
                acc[r][1] += xv.x * w[0].y + xv.y * w[1].y + xv.z * w[2].y + xv.w * w[3].y;
            }
        }
    }

#pragma unroll
    for (int r = 0; r < RPG; ++r) {
        float2 o;
        if (ACT == 1) {
            o.x = gelu_tanh(acc[r][0]);
            o.y = gelu_tanh(acc[r][1]);
        } else {
            o.x = acc[r][0];
            o.y = acc[r][1];
        }
        *(float2*)(out + (size_t)(rowBase + g * RPG + r) * OUTC + c0) = o;
    }
}

// ---------------------------------------------------------------------------
// Segment max over edges: agg[dst][c] = max(agg[dst][c], y[src][c]) for y>0.
// agg is zero-initialized; skipping v<=0 realizes relu(max(...)) semantics
// (max of relu == relu of max; isolated nodes stay 0).
// uint atomicMax is order-preserving for non-negative IEEE floats.
// 32 threads per edge, 4 channels per thread.
// ---------------------------------------------------------------------------
__global__ __launch_bounds__(256) void scatter_max(const float* __restrict__ y,
                                                   const int* __restrict__ ei,
                                                   unsigned int* __restrict__ agg) {
    int t = threadIdx.x;
    int e = blockIdx.x * 8 + (t >> 5);
    if (e >= N_EDGES) return;
    int cb = (t & 31) * 4;
    int src = ei[e];
    int dst = ei[N_EDGES + e];
    float4 v = *(const float4*)(y + (size_t)src * HID + cb);
    unsigned int* a = agg + (size_t)dst * HID + cb;
    if (v.x > 0.f) atomicMax(a + 0, __float_as_uint(v.x));
    if (v.y > 0.f) atomicMax(a + 1, __float_as_uint(v.y));
    if (v.z > 0.f) atomicMax(a + 2, __float_as_uint(v.z));
    if (v.w > 0.f) atomicMax(a + 3, __float_as_uint(v.w));
}

// edge_index echoed into output tail as float
__global__ void edge_copy(const int* __restrict__ ei, float* __restrict__ out) {
    int i = blockIdx.x * 256 + threadIdx.x;
    if (i < 2 * N_EDGES) out[i] = (float)ei[i];
}

extern "C" void kernel_launch(void* const* d_in, const int* in_sizes, int n_in,
                              void* d_out, int out_size, void* d_ws, size_t ws_size,
                              hipStream_t stream) {
    const float* x    = (const float*)d_in[0];
    const int*   ei   = (const int*)d_in[1];
    const float* Wp1  = (const float*)d_in[2];
    const float* bp1  = (const float*)d_in[3];
    const float* Wl1  = (const float*)d_in[4];
    const float* bl1  = (const float*)d_in[5];
    const float* Wr1  = (const float*)d_in[6];
    const float* Wp2  = (const float*)d_in[7];
    const float* bp2  = (const float*)d_in[8];
    const float* Wl2  = (const float*)d_in[9];
    const float* bl2  = (const float*)d_in[10];
    const float* Wr2  = (const float*)d_in[11];
    const float* Wlin = (const float*)d_in[12];
    const float* blin = (const float*)d_in[13];
    float* out = (float*)d_out;

    // ws layout (floats)
    float* wt   = (float*)d_ws;                 // 131072 floats (all transposed weights)
    float* y    = wt + 131072;                  // 50000*128
    float* agg  = y + (size_t)N_NODES * HID;    // 50000*128
    float* h1   = agg + (size_t)N_NODES * HID;  // 50000*128
    const float* Wp1t = wt + 0 * 16384;
    const float* Wl1t = wt + 1 * 16384;
    const float* Wr1t = wt + 2 * 16384;
    const float* Wp2t = wt + 3 * 16384;
    const float* Wl2t = wt + 4 * 16384;
    const float* Wr2t = wt + 5 * 16384;
    const float* Wlint = wt + 6 * 16384;

    const int NB = N_NODES / 16;  // 3125, exact

    // 0. transpose all weights
    dim3 tg(128, 7);
    hipLaunchKernelGGL(transpose_weights, tg, dim3(256), 0, stream,
                       Wp1, Wl1, Wr1, Wp2, Wl2, Wr2, Wlin, wt);

    // ---------------- layer 1 ----------------
    // y = x @ Wp1^T + bp1
    hipLaunchKernelGGL((linear_kernel<128, false, 0>), dim3(NB), dim3(256), 0, stream,
                       x, x, Wp1t, Wp1t, bp1, y);
    // agg = 0
    hipMemsetAsync(agg, 0, (size_t)N_NODES * HID * sizeof(float), stream);
    // agg = segment-relu-max
    hipLaunchKernelGGL(scatter_max, dim3(N_EDGES / 8), dim3(256), 0, stream,
                       y, ei, (unsigned int*)agg);
    // h1 = gelu(agg @ Wl1^T + bl1 + x @ Wr1^T)
    hipLaunchKernelGGL((linear_kernel<128, true, 1>), dim3(NB), dim3(256), 0, stream,
                       agg, x, Wl1t, Wr1t, bl1, h1);

    // ---------------- layer 2 ----------------
    // y = h1 @ Wp2^T + bp2
    hipLaunchKernelGGL((linear_kernel<128, false, 0>), dim3(NB), dim3(256), 0, stream,
                       h1, h1, Wp2t, Wp2t, bp2, y);
    hipMemsetAsync(agg, 0, (size_t)N_NODES * HID * sizeof(float), stream);
    hipLaunchKernelGGL(scatter_max, dim3(N_EDGES / 8), dim3(256), 0, stream,
                       y, ei, (unsigned int*)agg);
    // h2 = gelu(agg @ Wl2^T + bl2 + h1 @ Wr2^T)  -> reuse y buffer as h2
    hipLaunchKernelGGL((linear_kernel<128, true, 1>), dim3(NB), dim3(256), 0, stream,
                       agg, h1, Wl2t, Wr2t, bl2, y);

    // ---------------- final linear ----------------
    // out[:, :256] = gelu(h2 @ Wlin^T + blin)
    hipLaunchKernelGGL((linear_kernel<256, false, 1>), dim3(NB), dim3(256), 0, stream,
                       y, y, Wlint, Wlint, blin, out);

    // edge_index echo as float
    hipLaunchKernelGGL(edge_copy, dim3((2 * N_EDGES + 255) / 256), dim3(256), 0, stream,
                       ei, out + (size_t)N_NODES * 256);
}

// Round 2
// 507.243 us; speedup vs baseline: 3.6426x; 3.6426x over previous
//
#include <hip/hip_runtime.h>

#define N_NODES 50000
#define N_EDGES 600000
#define HID 128

// ---------------------------------------------------------------------------
// Weight transpose: Wt[k][c] = W[c][k] so lanes (c-major) read coalesced.
// ---------------------------------------------------------------------------
__global__ void transpose_weights(const float* __restrict__ Wp1,
                                  const float* __restrict__ Wl1,
                                  const float* __restrict__ Wr1,
                                  const float* __restrict__ Wp2,
                                  const float* __restrict__ Wl2,
                                  const float* __restrict__ Wr2,
                                  const float* __restrict__ Wlin,
                                  float* __restrict__ out) {
    int which = blockIdx.y;
    const float* W;
    float* O;
    int OUTC = 128;
    switch (which) {
        case 0: W = Wp1; O = out + 0 * 16384; break;
        case 1: W = Wl1; O = out + 1 * 16384; break;
        case 2: W = Wr1; O = out + 2 * 16384; break;
        case 3: W = Wp2; O = out + 3 * 16384; break;
        case 4: W = Wl2; O = out + 4 * 16384; break;
        case 5: W = Wr2; O = out + 5 * 16384; break;
        default: W = Wlin; O = out + 6 * 16384; OUTC = 256; break;
    }
    int idx = blockIdx.x * 256 + threadIdx.x;
    int total = OUTC * 128;
    if (idx < total) {
        int c = idx / 128;
        int k = idx % 128;
        O[k * OUTC + c] = W[c * 128 + k];
    }
}

__device__ __forceinline__ float gelu_tanh(float x) {
    float x3 = x * x * x;
    float u = 0.7978845608028654f * (x + 0.044715f * x3);
    float t = tanhf(u);
    return 0.5f * x * (1.0f + t);
}

// ---------------------------------------------------------------------------
// out[n][c] = act( bias[c] + in1[n]·W1t[:,c] (+ in2[n]·W2t[:,c]) )
// 256 threads, 32 rows/block. Thread owns 2 consecutive c.
// ---------------------------------------------------------------------------
template <int OUTC, bool DUAL, int ACT>
__global__ __launch_bounds__(256) void linear_kernel(
        const float* __restrict__ in1, const float* __restrict__ in2,
        const float* __restrict__ W1t, const float* __restrict__ W2t,
        const float* __restrict__ bias, float* __restrict__ out) {
    constexpr int ROWS = 32;
    __shared__ float x1[ROWS][HID];
    __shared__ float x2[DUAL ? ROWS : 1][HID];

    const int rowBase = blockIdx.x * ROWS;
    const int t = threadIdx.x;

    // cooperative stage of input tiles (coalesced float4); clamp tail rows
    for (int i = t; i < ROWS * HID / 4; i += 256) {
        int r = i >> 5;  // 32 float4 per row
        int kc = i & 31;
        int rsrc = rowBase + r;
        if (rsrc > N_NODES - 1) rsrc = N_NODES - 1;
        ((float4*)x1[r])[kc] = ((const float4*)(in1 + (size_t)rsrc * HID))[kc];
        if (DUAL)
            ((float4*)x2[r])[kc] = ((const float4*)(in2 + (size_t)rsrc * HID))[kc];
    }
    __syncthreads();

    constexpr int CG = (OUTC == 128) ? 64 : 128;  // threads covering c (2 c each)
    constexpr int NG = 256 / CG;                  // row groups
    constexpr int RPG = ROWS / NG;                // rows per group
    const int c0 = (t % CG) * 2;
    const int g = t / CG;

    float acc[RPG][2];
    float2 b2 = *(const float2*)(bias + c0);
#pragma unroll
    for (int r = 0; r < RPG; ++r) { acc[r][0] = b2.x; acc[r][1] = b2.y; }

#pragma unroll 4
    for (int k0 = 0; k0 < HID; k0 += 4) {
        float2 w[4];
#pragma unroll
        for (int kk = 0; kk < 4; ++kk)
            w[kk] = *(const float2*)(W1t + (size_t)(k0 + kk) * OUTC + c0);
#pragma unroll
        for (int r = 0; r < RPG; ++r) {
            float4 xv = *(const float4*)&x1[g * RPG + r][k0];
            acc[r][0] += xv.x * w[0].x + xv.y * w[1].x + xv.z * w[2].x + xv.w * w[3].x;
            acc[r][1] += xv.x * w[0].y + xv.y * w[1].y + xv.z * w[2].y + xv.w * w[3].y;
        }
    }
    if (DUAL) {
#pragma unroll 4
        for (int k0 = 0; k0 < HID; k0 += 4) {
            float2 w[4];
#pragma unroll
            for (int kk = 0; kk < 4; ++kk)
                w[kk] = *(const float2*)(W2t + (size_t)(k0 + kk) * OUTC + c0);
#pragma unroll
            for (int r = 0; r < RPG; ++r) {
                float4 xv = *(const float4*)&x2[g * RPG + r][k0];
                acc[r][0] += xv.x * w[0].x + xv.y * w[1].x + xv.z * w[2].x + xv.w * w[3].x;
                acc[r][1] += xv.x * w[0].y + xv.y * w[1].y + xv.z * w[2].y + xv.w * w[3].y;
            }
        }
    }

#pragma unroll
    for (int r = 0; r < RPG; ++r) {
        int row = rowBase + g * RPG + r;
        if (row < N_NODES) {
            float2 o;
            if (ACT == 1) {
                o.x = gelu_tanh(acc[r][0]);
                o.y = gelu_tanh(acc[r][1]);
            } else {
                o.x = acc[r][0];
                o.y = acc[r][1];
            }
            *(float2*)(out + (size_t)row * OUTC + c0) = o;
        }
    }
}

// ---------------------------------------------------------------------------
// CSR build: counting sort of edges by dst. deg -> scan -> fill.
// ---------------------------------------------------------------------------
__global__ void count_deg(const int* __restrict__ ei, int* __restrict__ deg) {
    int e = blockIdx.x * 256 + threadIdx.x;
    if (e < N_EDGES) atomicAdd(&deg[ei[N_EDGES + e]], 1);
}

__global__ void deg_partial(const int* __restrict__ deg, int* __restrict__ partial) {
    __shared__ int sm[256];
    int i = blockIdx.x * 256 + threadIdx.x;
    sm[threadIdx.x] = (i < N_NODES) ? deg[i] : 0;
    __syncthreads();
    for (int s = 128; s > 0; s >>= 1) {
        if (threadIdx.x < s) sm[threadIdx.x] += sm[threadIdx.x + s];
        __syncthreads();
    }
    if (threadIdx.x == 0) partial[blockIdx.x] = sm[0];
}

__global__ void scan_partials(int* __restrict__ partial, int np) {
    __shared__ int sm[256];
    int v = (threadIdx.x < np) ? partial[threadIdx.x] : 0;
    sm[threadIdx.x] = v;
    __syncthreads();
    for (int s = 1; s < 256; s <<= 1) {
        int tv = (threadIdx.x >= s) ? sm[threadIdx.x - s] : 0;
        __syncthreads();
        sm[threadIdx.x] += tv;
        __syncthreads();
    }
    if (threadIdx.x < np) partial[threadIdx.x] = sm[threadIdx.x] - v;  // exclusive
}

__global__ void deg_scan_out(const int* __restrict__ deg, const int* __restrict__ partial,
                             int* __restrict__ off) {
    __shared__ int sm[256];
    int i = blockIdx.x * 256 + threadIdx.x;
    int v = (i < N_NODES) ? deg[i] : 0;
    sm[threadIdx.x] = v;
    __syncthreads();
    for (int s = 1; s < 256; s <<= 1) {
        int tv = (threadIdx.x >= s) ? sm[threadIdx.x - s] : 0;
        __syncthreads();
        sm[threadIdx.x] += tv;
        __syncthreads();
    }
    if (i < N_NODES) off[i] = partial[blockIdx.x] + sm[threadIdx.x] - v;
}

__global__ void fill_csr(const int* __restrict__ ei, const int* __restrict__ off,
                         int* __restrict__ cnt, int* __restrict__ csr) {
    int e = blockIdx.x * 256 + threadIdx.x;
    if (e < N_EDGES) {
        int dst = ei[N_EDGES + e];
        int p = atomicAdd(&cnt[dst], 1);
        csr[off[dst] + p] = ei[e];  // store src node id
    }
}

// ---------------------------------------------------------------------------
// Gather-based segment max: one wave (64 lanes) per node, float2 per lane.
// acc=0 init realizes relu(max(.)) and isolated-node-zero exactly.
// ---------------------------------------------------------------------------
__global__ __launch_bounds__(256) void seg_max(const float* __restrict__ y,
                                               const int* __restrict__ csr,
                                               const int* __restrict__ off,
                                               const int* __restrict__ deg,
                                               float* __restrict__ agg) {
    int n = blockIdx.x * 4 + (threadIdx.x >> 6);
    int lane = threadIdx.x & 63;
    int s = off[n];
    int d = deg[n];
    const float* yb = y + lane * 2;
    float2 acc = make_float2(0.f, 0.f);
    int i = 0;
    for (; i + 2 <= d; i += 2) {
        int s0 = csr[s + i];
        int s1 = csr[s + i + 1];
        float2 v0 = *(const float2*)(yb + (size_t)s0 * HID);
        float2 v1 = *(const float2*)(yb + (size_t)s1 * HID);
        acc.x = fmaxf(acc.x, fmaxf(v0.x, v1.x));
        acc.y = fmaxf(acc.y, fmaxf(v0.y, v1.y));
    }
    if (i < d) {
        int s0 = csr[s + i];
        float2 v0 = *(const float2*)(yb + (size_t)s0 * HID);
        acc.x = fmaxf(acc.x, v0.x);
        acc.y = fmaxf(acc.y, v0.y);
    }
    *(float2*)(agg + (size_t)n * HID + lane * 2) = acc;
}

// edge_index echoed into output tail as float
__global__ void edge_copy(const int* __restrict__ ei, float* __restrict__ out) {
    int i = blockIdx.x * 256 + threadIdx.x;
    if (i < 2 * N_EDGES) out[i] = (float)ei[i];
}

extern "C" void kernel_launch(void* const* d_in, const int* in_sizes, int n_in,
                              void* d_out, int out_size, void* d_ws, size_t ws_size,
                              hipStream_t stream) {
    const float* x    = (const float*)d_in[0];
    const int*   ei   = (const int*)d_in[1];
    const float* Wp1  = (const float*)d_in[2];
    const float* bp1  = (const float*)d_in[3];
    const float* Wl1  = (const float*)d_in[4];
    const float* bl1  = (const float*)d_in[5];
    const float* Wr1  = (const float*)d_in[6];
    const float* Wp2  = (const float*)d_in[7];
    const float* bp2  = (const float*)d_in[8];
    const float* Wl2  = (const float*)d_in[9];
    const float* bl2  = (const float*)d_in[10];
    const float* Wr2  = (const float*)d_in[11];
    const float* Wlin = (const float*)d_in[12];
    const float* blin = (const float*)d_in[13];
    float* out = (float*)d_out;

    // ws layout
    float* wt   = (float*)d_ws;                 // 131072 floats
    float* y    = wt + 131072;                  // 50000*128
    float* agg  = y + (size_t)N_NODES * HID;    // 50000*128
    float* h1   = agg + (size_t)N_NODES * HID;  // 50000*128
    int* deg    = (int*)(h1 + (size_t)N_NODES * HID);  // 50000
    int* off    = deg + N_NODES;                        // 50000
    int* cnt    = off + N_NODES;                        // 50000
    int* partial= cnt + N_NODES;                        // 256
    int* csr    = partial + 256;                        // 600000

    const float* Wp1t = wt + 0 * 16384;
    const float* Wl1t = wt + 1 * 16384;
    const float* Wr1t = wt + 2 * 16384;
    const float* Wp2t = wt + 3 * 16384;
    const float* Wl2t = wt + 4 * 16384;
    const float* Wr2t = wt + 5 * 16384;
    const float* Wlint = wt + 6 * 16384;

    const int NB  = (N_NODES + 31) / 32;   // linear blocks (32 rows each)
    const int EB  = (N_EDGES + 255) / 256; // edge blocks
    const int NPB = (N_NODES + 255) / 256; // node scan blocks (196)

    // 0. transpose all weights
    hipLaunchKernelGGL(transpose_weights, dim3(128, 7), dim3(256), 0, stream,
                       Wp1, Wl1, Wr1, Wp2, Wl2, Wr2, Wlin, wt);

    // 1. CSR build (once; reused by both layers)
    hipMemsetAsync(deg, 0, N_NODES * sizeof(int), stream);
    hipMemsetAsync(cnt, 0, N_NODES * sizeof(int), stream);
    hipLaunchKernelGGL(count_deg, dim3(EB), dim3(256), 0, stream, ei, deg);
    hipLaunchKernelGGL(deg_partial, dim3(NPB), dim3(256), 0, stream, deg, partial);
    hipLaunchKernelGGL(scan_partials, dim3(1), dim3(256), 0, stream, partial, NPB);
    hipLaunchKernelGGL(deg_scan_out, dim3(NPB), dim3(256), 0, stream, deg, partial, off);
    hipLaunchKernelGGL(fill_csr, dim3(EB), dim3(256), 0, stream, ei, off, cnt, csr);

    // ---------------- layer 1 ----------------
    hipLaunchKernelGGL((linear_kernel<128, false, 0>), dim3(NB), dim3(256), 0, stream,
                       x, x, Wp1t, Wp1t, bp1, y);
    hipLaunchKernelGGL(seg_max, dim3(N_NODES / 4), dim3(256), 0, stream,
                       y, csr, off, deg, agg);
    hipLaunchKernelGGL((linear_kernel<128, true, 1>), dim3(NB), dim3(256), 0, stream,
                       agg, x, Wl1t, Wr1t, bl1, h1);

    // ---------------- layer 2 ----------------
    hipLaunchKernelGGL((linear_kernel<128, false, 0>), dim3(NB), dim3(256), 0, stream,
                       h1, h1, Wp2t, Wp2t, bp2, y);
    hipLaunchKernelGGL(seg_max, dim3(N_NODES / 4), dim3(256), 0, stream,
                       y, csr, off, deg, agg);
    // h2 = gelu(agg @ Wl2^T + bl2 + h1 @ Wr2^T) -> write into y
    hipLaunchKernelGGL((linear_kernel<128, true, 1>), dim3(NB), dim3(256), 0, stream,
                       agg, h1, Wl2t, Wr2t, bl2, y);

    // ---------------- final linear ----------------
    hipLaunchKernelGGL((linear_kernel<256, false, 1>), dim3(NB), dim3(256), 0, stream,
                       y, y, Wlint, Wlint, blin, out);

    // edge_index echo as float
    hipLaunchKernelGGL(edge_copy, dim3((2 * N_EDGES + 255) / 256), dim3(256), 0, stream,
                       ei, out + (size_t)N_NODES * 256);
}

// Round 3
// 335.613 us; speedup vs baseline: 5.5053x; 1.5114x over previous
//
#include <hip/hip_runtime.h>

#define N_NODES 50000
#define N_EDGES 600000
#define HID 128

typedef __attribute__((ext_vector_type(8))) short short8;
typedef __attribute__((ext_vector_type(4))) float f32x4;

__device__ __forceinline__ unsigned short f2bf(float f) {
    unsigned u = __float_as_uint(f);
    unsigned r = u + 0x7FFFu + ((u >> 16) & 1u);  // RNE
    return (unsigned short)(r >> 16);
}
__device__ __forceinline__ float bf2f(unsigned short h) {
    return __uint_as_float(((unsigned)h) << 16);
}

__device__ __forceinline__ float gelu_tanh(float x) {
    float x3 = x * x * x;
    float u = 0.7978845608028654f * (x + 0.044715f * x3);
    float t = tanhf(u);
    return 0.5f * x * (1.0f + t);
}

// ---------------------------------------------------------------------------
// Pack weights into MFMA B-fragment order, bf16 hi + lo.
// For v_mfma_f32_16x16x32_bf16 B-operand: lane holds B[k][n] with
// n = ntile*16 + (lane&15), k = kstep*32 + (lane>>4)*8 + j, j=0..7.
// Packed: [ntile][kstep][lane][j] ushort; hi region then lo region.
// Matrix m (128x128): 16384 ushort per region. Wlin (256x128): 32768.
// ---------------------------------------------------------------------------
__global__ void pack_weights(const float* __restrict__ Wp1,
                             const float* __restrict__ Wl1,
                             const float* __restrict__ Wr1,
                             const float* __restrict__ Wp2,
                             const float* __restrict__ Wl2,
                             const float* __restrict__ Wr2,
                             const float* __restrict__ Wlin,
                             unsigned short* __restrict__ out) {
    int which = blockIdx.y;
    const float* W;
    int count;  // elements in hi region
    int base;
    switch (which) {
        case 0: W = Wp1; count = 16384; base = 0; break;
        case 1: W = Wl1; count = 16384; base = 32768; break;
        case 2: W = Wr1; count = 16384; base = 65536; break;
        case 3: W = Wp2; count = 16384; base = 98304; break;
        case 4: W = Wl2; count = 16384; base = 131072; break;
        case 5: W = Wr2; count = 16384; base = 163840; break;
        default: W = Wlin; count = 32768; base = 196608; break;
    }
    int idx = blockIdx.x * 256 + threadIdx.x;
    if (idx >= count) return;
    int j = idx & 7;
    int lane = (idx >> 3) & 63;
    int ks = (idx >> 9) & 3;
    int nt = idx >> 11;
    int c = nt * 16 + (lane & 15);
    int k = ks * 32 + (lane >> 4) * 8 + j;
    float v = W[c * 128 + k];
    unsigned short hi = f2bf(v);
    unsigned short lo = f2bf(v - bf2f(hi));
    out[base + idx] = hi;
    out[base + count + idx] = lo;
}

// ---------------------------------------------------------------------------
// MFMA linear: out[n][c] = act(bias[c] + in1[n]·W1[:,c] (+ in2[n]·W2[:,c]))
// bf16-split: acc = Ahi*Bhi + Ahi*Blo + Alo*Bhi (f32 accumulate).
// Block = 256 thr (4 waves), 64 rows/block; wave owns 16 rows x OUTC cols.
// A staged in LDS (hi/lo, XOR-swizzled); B read from packed global (L1/L2-hot).
// ---------------------------------------------------------------------------
template <int NT, bool DUAL, int ACT>
__global__ __launch_bounds__(256) void mfma_linear(
        const float* __restrict__ in1, const float* __restrict__ in2,
        const unsigned short* __restrict__ B1, const unsigned short* __restrict__ B2,
        const float* __restrict__ bias, float* __restrict__ out) {
    constexpr int OUTC = NT * 16;
    constexpr int NBUF = DUAL ? 4 : 2;
    constexpr int LOOFF = NT * 2048;  // ushorts in hi region
    __shared__ unsigned short A[NBUF * 64 * 128];

    const int t = threadIdx.x;
    const int blockRow = blockIdx.x * 64;

    // ---- stage A: f32 -> bf16 hi/lo into swizzled LDS ----
    for (int i = t; i < 64 * 32; i += 256) {
        int row = i >> 5;
        int kc = (i & 31) * 4;  // float index
        int rsrc = blockRow + row;
        if (rsrc > N_NODES - 1) rsrc = N_NODES - 1;
        int kb = (kc * 2) ^ ((row & 7) << 4);  // swizzled byte offset in row
        {
            float4 v = *(const float4*)(in1 + (size_t)rsrc * HID + kc);
            unsigned short h0 = f2bf(v.x), h1 = f2bf(v.y), h2 = f2bf(v.z), h3 = f2bf(v.w);
            uint2 hp = make_uint2((unsigned)h0 | ((unsigned)h1 << 16),
                                  (unsigned)h2 | ((unsigned)h3 << 16));
            unsigned short l0 = f2bf(v.x - bf2f(h0)), l1 = f2bf(v.y - bf2f(h1));
            unsigned short l2 = f2bf(v.z - bf2f(h2)), l3 = f2bf(v.w - bf2f(h3));
            uint2 lp = make_uint2((unsigned)l0 | ((unsigned)l1 << 16),
                                  (unsigned)l2 | ((unsigned)l3 << 16));
            *(uint2*)((char*)A + 0 * 16384 + row * 256 + kb) = hp;
            *(uint2*)((char*)A + 1 * 16384 + row * 256 + kb) = lp;
        }
        if (DUAL) {
            float4 v = *(const float4*)(in2 + (size_t)rsrc * HID + kc);
            unsigned short h0 = f2bf(v.x), h1 = f2bf(v.y), h2 = f2bf(v.z), h3 = f2bf(v.w);
            uint2 hp = make_uint2((unsigned)h0 | ((unsigned)h1 << 16),
                                  (unsigned)h2 | ((unsigned)h3 << 16));
            unsigned short l0 = f2bf(v.x - bf2f(h0)), l1 = f2bf(v.y - bf2f(h1));
            unsigned short l2 = f2bf(v.z - bf2f(h2)), l3 = f2bf(v.w - bf2f(h3));
            uint2 lp = make_uint2((unsigned)l0 | ((unsigned)l1 << 16),
                                  (unsigned)l2 | ((unsigned)l3 << 16));
            *(uint2*)((char*)A + 2 * 16384 + row * 256 + kb) = hp;
            *(uint2*)((char*)A + 3 * 16384 + row * 256 + kb) = lp;
        }
    }
    __syncthreads();

    const int w = t >> 6;
    const int l = t & 63;
    const int rl = w * 16 + (l & 15);     // A-frag row (local)
    const int koff = (l >> 4) * 16;       // byte offset of this lane's 8 bf16 in a 32-k step
    const int swz = (rl & 7) << 4;

    // ---- load all A fragments (4 ksteps, hi+lo, x2 if DUAL) ----
    short8 a1h[4], a1l[4];
    short8 a2h[4], a2l[4];
#pragma unroll
    for (int ks = 0; ks < 4; ++ks) {
        int kb = (ks * 64 + koff) ^ swz;
        a1h[ks] = *(const short8*)((const char*)A + 0 * 16384 + rl * 256 + kb);
        a1l[ks] = *(const short8*)((const char*)A + 1 * 16384 + rl * 256 + kb);
        if (DUAL) {
            a2h[ks] = *(const short8*)((const char*)A + 2 * 16384 + rl * 256 + kb);
            a2l[ks] = *(const short8*)((const char*)A + 3 * 16384 + rl * 256 + kb);
        }
    }

    const int r0 = (l >> 4) * 4;          // C/D row base within 16-row tile
    const int orowBase = blockRow + w * 16;
    const int cLane = l & 15;

    for (int nt = 0; nt < NT; ++nt) {
        f32x4 acc = {0.f, 0.f, 0.f, 0.f};
#pragma unroll
        for (int ks = 0; ks < 4; ++ks) {
            const unsigned short* bp = B1 + ((size_t)(nt * 4 + ks) * 64 + l) * 8;
            short8 bh = *(const short8*)bp;
            short8 bl = *(const short8*)(bp + LOOFF);
            acc = __builtin_amdgcn_mfma_f32_16x16x32_bf16(a1h[ks], bh, acc, 0, 0, 0);
            acc = __builtin_amdgcn_mfma_f32_16x16x32_bf16(a1h[ks], bl, acc, 0, 0, 0);
            acc = __builtin_amdgcn_mfma_f32_16x16x32_bf16(a1l[ks], bh, acc, 0, 0, 0);
            if (DUAL) {
                const unsigned short* bp2 = B2 + ((size_t)(nt * 4 + ks) * 64 + l) * 8;
                short8 b2h = *(const short8*)bp2;
                short8 b2l = *(const short8*)(bp2 + LOOFF);
                acc = __builtin_amdgcn_mfma_f32_16x16x32_bf16(a2h[ks], b2h, acc, 0, 0, 0);
                acc = __builtin_amdgcn_mfma_f32_16x16x32_bf16(a2h[ks], b2l, acc, 0, 0, 0);
                acc = __builtin_amdgcn_mfma_f32_16x16x32_bf16(a2l[ks], b2h, acc, 0, 0, 0);
            }
        }
        float bc = bias[nt * 16 + cLane];
#pragma unroll
        for (int reg = 0; reg < 4; ++reg) {
            int row = orowBase + r0 + reg;
            if (row < N_NODES) {
                float v = acc[reg] + bc;
                if (ACT == 1) v = gelu_tanh(v);
                out[(size_t)row * OUTC + nt * 16 + cLane] = v;
            }
        }
    }
}

// ---------------------------------------------------------------------------
// CSR build: counting sort of edges by dst. deg -> scan -> fill.
// ---------------------------------------------------------------------------
__global__ void count_deg(const int* __restrict__ ei, int* __restrict__ deg) {
    int e = blockIdx.x * 256 + threadIdx.x;
    if (e < N_EDGES) atomicAdd(&deg[ei[N_EDGES + e]], 1);
}

__global__ void deg_partial(const int* __restrict__ deg, int* __restrict__ partial) {
    __shared__ int sm[256];
    int i = blockIdx.x * 256 + threadIdx.x;
    sm[threadIdx.x] = (i < N_NODES) ? deg[i] : 0;
    __syncthreads();
    for (int s = 128; s > 0; s >>= 1) {
        if (threadIdx.x < s) sm[threadIdx.x] += sm[threadIdx.x + s];
        __syncthreads();
    }
    if (threadIdx.x == 0) partial[blockIdx.x] = sm[0];
}

__global__ void scan_partials(int* __restrict__ partial, int np) {
    __shared__ int sm[256];
    int v = (threadIdx.x < np) ? partial[threadIdx.x] : 0;
    sm[threadIdx.x] = v;
    __syncthreads();
    for (int s = 1; s < 256; s <<= 1) {
        int tv = (threadIdx.x >= s) ? sm[threadIdx.x - s] : 0;
        __syncthreads();
        sm[threadIdx.x] += tv;
        __syncthreads();
    }
    if (threadIdx.x < np) partial[threadIdx.x] = sm[threadIdx.x] - v;  // exclusive
}

__global__ void deg_scan_out(const int* __restrict__ deg, const int* __restrict__ partial,
                             int* __restrict__ off) {
    __shared__ int sm[256];
    int i = blockIdx.x * 256 + threadIdx.x;
    int v = (i < N_NODES) ? deg[i] : 0;
    sm[threadIdx.x] = v;
    __syncthreads();
    for (int s = 1; s < 256; s <<= 1) {
        int tv = (threadIdx.x >= s) ? sm[threadIdx.x - s] : 0;
        __syncthreads();
        sm[threadIdx.x] += tv;
        __syncthreads();
    }
    if (i < N_NODES) off[i] = partial[blockIdx.x] + sm[threadIdx.x] - v;
}

__global__ void fill_csr(const int* __restrict__ ei, const int* __restrict__ off,
                         int* __restrict__ cnt, int* __restrict__ csr) {
    int e = blockIdx.x * 256 + threadIdx.x;
    if (e < N_EDGES) {
        int dst = ei[N_EDGES + e];
        int p = atomicAdd(&cnt[dst], 1);
        csr[off[dst] + p] = ei[e];  // store src node id
    }
}

// ---------------------------------------------------------------------------
// Gather-based segment max: one wave per node, float2 per lane.
// acc=0 init realizes relu(max(.)) and isolated-node-zero exactly.
// ---------------------------------------------------------------------------
__global__ __launch_bounds__(256) void seg_max(const float* __restrict__ y,
                                               const int* __restrict__ csr,
                                               const int* __restrict__ off,
                                               const int* __restrict__ deg,
                                               float* __restrict__ agg) {
    int n = blockIdx.x * 4 + (threadIdx.x >> 6);
    int lane = threadIdx.x & 63;
    int s = off[n];
    int d = deg[n];
    const float* yb = y + lane * 2;
    float2 acc = make_float2(0.f, 0.f);
    int i = 0;
    for (; i + 2 <= d; i += 2) {
        int s0 = csr[s + i];
        int s1 = csr[s + i + 1];
        float2 v0 = *(const float2*)(yb + (size_t)s0 * HID);
        float2 v1 = *(const float2*)(yb + (size_t)s1 * HID);
        acc.x = fmaxf(acc.x, fmaxf(v0.x, v1.x));
        acc.y = fmaxf(acc.y, fmaxf(v0.y, v1.y));
    }
    if (i < d) {
        int s0 = csr[s + i];
        float2 v0 = *(const float2*)(yb + (size_t)s0 * HID);
        acc.x = fmaxf(acc.x, v0.x);
        acc.y = fmaxf(acc.y, v0.y);
    }
    *(float2*)(agg + (size_t)n * HID + lane * 2) = acc;
}

// edge_index echoed into output tail as float
__global__ void edge_copy(const int* __restrict__ ei, float* __restrict__ out) {
    int i = blockIdx.x * 256 + threadIdx.x;
    if (i < 2 * N_EDGES) out[i] = (float)ei[i];
}

extern "C" void kernel_launch(void* const* d_in, const int* in_sizes, int n_in,
                              void* d_out, int out_size, void* d_ws, size_t ws_size,
                              hipStream_t stream) {
    const float* x    = (const float*)d_in[0];
    const int*   ei   = (const int*)d_in[1];
    const float* Wp1  = (const float*)d_in[2];
    const float* bp1  = (const float*)d_in[3];
    const float* Wl1  = (const float*)d_in[4];
    const float* bl1  = (const float*)d_in[5];
    const float* Wr1  = (const float*)d_in[6];
    const float* Wp2  = (const float*)d_in[7];
    const float* bp2  = (const float*)d_in[8];
    const float* Wl2  = (const float*)d_in[9];
    const float* bl2  = (const float*)d_in[10];
    const float* Wr2  = (const float*)d_in[11];
    const float* Wlin = (const float*)d_in[12];
    const float* blin = (const float*)d_in[13];
    float* out = (float*)d_out;

    // ws layout: packed weights (262144 ushort = 131072 floats), then f32 bufs
    unsigned short* wpack = (unsigned short*)d_ws;
    float* y    = (float*)d_ws + 131072;        // 50000*128
    float* agg  = y + (size_t)N_NODES * HID;    // 50000*128
    float* h1   = agg + (size_t)N_NODES * HID;  // 50000*128
    int* deg    = (int*)(h1 + (size_t)N_NODES * HID);
    int* off    = deg + N_NODES;
    int* cnt    = off + N_NODES;
    int* partial= cnt + N_NODES;
    int* csr    = partial + 256;

    const unsigned short* Bp1 = wpack + 0;
    const unsigned short* Bl1 = wpack + 32768;
    const unsigned short* Br1 = wpack + 65536;
    const unsigned short* Bp2 = wpack + 98304;
    const unsigned short* Bl2 = wpack + 131072;
    const unsigned short* Br2 = wpack + 163840;
    const unsigned short* Blin = wpack + 196608;

    const int RB  = (N_NODES + 63) / 64;   // mfma linear blocks (782)
    const int EB  = (N_EDGES + 255) / 256;
    const int NPB = (N_NODES + 255) / 256;

    // 0. pack weights (bf16 hi/lo, MFMA B-frag order)
    hipLaunchKernelGGL(pack_weights, dim3(128, 7), dim3(256), 0, stream,
                       Wp1, Wl1, Wr1, Wp2, Wl2, Wr2, Wlin, wpack);

    // 1. CSR build (reused by both layers)
    hipMemsetAsync(deg, 0, N_NODES * sizeof(int), stream);
    hipMemsetAsync(cnt, 0, N_NODES * sizeof(int), stream);
    hipLaunchKernelGGL(count_deg, dim3(EB), dim3(256), 0, stream, ei, deg);
    hipLaunchKernelGGL(deg_partial, dim3(NPB), dim3(256), 0, stream, deg, partial);
    hipLaunchKernelGGL(scan_partials, dim3(1), dim3(256), 0, stream, partial, NPB);
    hipLaunchKernelGGL(deg_scan_out, dim3(NPB), dim3(256), 0, stream, deg, partial, off);
    hipLaunchKernelGGL(fill_csr, dim3(EB), dim3(256), 0, stream, ei, off, cnt, csr);

    // ---------------- layer 1 ----------------
    hipLaunchKernelGGL((mfma_linear<8, false, 0>), dim3(RB), dim3(256), 0, stream,
                       x, x, Bp1, Bp1, bp1, y);
    hipLaunchKernelGGL(seg_max, dim3(N_NODES / 4), dim3(256), 0, stream,
                       y, csr, off, deg, agg);
    hipLaunchKernelGGL((mfma_linear<8, true, 1>), dim3(RB), dim3(256), 0, stream,
                       agg, x, Bl1, Br1, bl1, h1);

    // ---------------- layer 2 ----------------
    hipLaunchKernelGGL((mfma_linear<8, false, 0>), dim3(RB), dim3(256), 0, stream,
                       h1, h1, Bp2, Bp2, bp2, y);
    hipLaunchKernelGGL(seg_max, dim3(N_NODES / 4), dim3(256), 0, stream,
                       y, csr, off, deg, agg);
    // h2 = gelu(agg @ Wl2^T + bl2 + h1 @ Wr2^T) -> write into y
    hipLaunchKernelGGL((mfma_linear<8, true, 1>), dim3(RB), dim3(256), 0, stream,
                       agg, h1, Bl2, Br2, bl2, y);

    // ---------------- final linear ----------------
    hipLaunchKernelGGL((mfma_linear<16, false, 1>), dim3(RB), dim3(256), 0, stream,
                       y, y, Blin, Blin, blin, out);

    // edge_index echo as float
    hipLaunchKernelGGL(edge_copy, dim3((2 * N_EDGES + 255) / 256), dim3(256), 0, stream,
                       ei, out + (size_t)N_NODES * 256);
}

// Round 4
// 271.324 us; speedup vs baseline: 6.8098x; 1.2369x over previous
//
#include <hip/hip_runtime.h>

#define N_NODES 50000
#define N_EDGES 600000
#define HID 128

typedef __attribute__((ext_vector_type(8))) short short8;
typedef __attribute__((ext_vector_type(4))) float f32x4;

__device__ __forceinline__ unsigned short f2bf(float f) {
    unsigned u = __float_as_uint(f);
    unsigned r = u + 0x7FFFu + ((u >> 16) & 1u);  // RNE
    return (unsigned short)(r >> 16);
}
__device__ __forceinline__ float bf2f(unsigned short h) {
    return __uint_as_float(((unsigned)h) << 16);
}

__device__ __forceinline__ float gelu_tanh(float x) {
    float x3 = x * x * x;
    float u = 0.7978845608028654f * (x + 0.044715f * x3);
    float t = tanhf(u);
    return 0.5f * x * (1.0f + t);
}

// ---------------------------------------------------------------------------
// Pack weights into MFMA B-fragment order, bf16 hi + lo regions.
// B-frag (16x16x32): n = nt*16 + (lane&15), k = ks*32 + (lane>>4)*8 + j.
// Layout verified empirically in R3.
// ---------------------------------------------------------------------------
__global__ void pack_weights(const float* __restrict__ Wp1,
                             const float* __restrict__ Wl1,
                             const float* __restrict__ Wr1,
                             const float* __restrict__ Wp2,
                             const float* __restrict__ Wl2,
                             const float* __restrict__ Wr2,
                             const float* __restrict__ Wlin,
                             unsigned short* __restrict__ out) {
    int which = blockIdx.y;
    const float* W;
    int count, base;
    switch (which) {
        case 0: W = Wp1; count = 16384; base = 0; break;
        case 1: W = Wl1; count = 16384; base = 32768; break;
        case 2: W = Wr1; count = 16384; base = 65536; break;
        case 3: W = Wp2; count = 16384; base = 98304; break;
        case 4: W = Wl2; count = 16384; base = 131072; break;
        case 5: W = Wr2; count = 16384; base = 163840; break;
        default: W = Wlin; count = 32768; base = 196608; break;
    }
    int idx = blockIdx.x * 256 + threadIdx.x;
    if (idx >= count) return;
    int j = idx & 7;
    int lane = (idx >> 3) & 63;
    int ks = (idx >> 9) & 3;
    int nt = idx >> 11;
    int c = nt * 16 + (lane & 15);
    int k = ks * 32 + (lane >> 4) * 8 + j;
    float v = W[c * 128 + k];
    unsigned short hi = f2bf(v);
    unsigned short lo = f2bf(v - bf2f(hi));
    out[base + idx] = hi;
    out[base + count + idx] = lo;
}

// x f32 -> bf16 (one-time)
__global__ void cvt_x(const float* __restrict__ in, unsigned short* __restrict__ out) {
    int tid = blockIdx.x * 256 + threadIdx.x;
    size_t i8 = (size_t)tid * 8;
    if (i8 >= (size_t)N_NODES * HID) return;
    float4 v0 = *(const float4*)(in + i8);
    float4 v1 = *(const float4*)(in + i8 + 4);
    short8 o;
    o[0] = f2bf(v0.x); o[1] = f2bf(v0.y); o[2] = f2bf(v0.z); o[3] = f2bf(v0.w);
    o[4] = f2bf(v1.x); o[5] = f2bf(v1.y); o[6] = f2bf(v1.z); o[7] = f2bf(v1.w);
    *(short8*)(out + i8) = o;
}

// ---------------------------------------------------------------------------
// MFMA linear (A bf16 direct from global, B packed hi/lo, 2-term split):
// out[n][c] = act(bias[c] + in1[n]·W1[:,c] (+ in2[n]·W2[:,c]))
// 256 thr = 4 waves, 64 rows/block; wave owns 16 rows x OUTC.
// ---------------------------------------------------------------------------
template <int NT, bool DUAL, int ACT, bool OBF>
__global__ __launch_bounds__(256) void mfma_linear(
        const unsigned short* __restrict__ in1, const unsigned short* __restrict__ in2,
        const unsigned short* __restrict__ B1, const unsigned short* __restrict__ B2,
        const float* __restrict__ bias, void* __restrict__ outp) {
    constexpr int OUTC = NT * 16;
    constexpr int LOOFF = NT * 2048;  // ushorts in hi region
    const int t = threadIdx.x;
    const int w = t >> 6;
    const int l = t & 63;
    const int blockRow = blockIdx.x * 64;

    int r = blockRow + w * 16 + (l & 15);
    if (r > N_NODES - 1) r = N_NODES - 1;  // clamped A read for tail block
    const int ko = (l >> 4) * 8;           // ushort offset of this lane's 8 bf16

    short8 a1[4], a2[4];
#pragma unroll
    for (int ks = 0; ks < 4; ++ks) {
        a1[ks] = *(const short8*)(in1 + (size_t)r * HID + ks * 32 + ko);
        if (DUAL) a2[ks] = *(const short8*)(in2 + (size_t)r * HID + ks * 32 + ko);
    }

    const int r0 = (l >> 4) * 4;
    const int orow = blockRow + w * 16 + r0;
    const int cL = l & 15;

    for (int nt = 0; nt < NT; ++nt) {
        f32x4 acc = {0.f, 0.f, 0.f, 0.f};
#pragma unroll
        for (int ks = 0; ks < 4; ++ks) {
            const unsigned short* bp = B1 + ((size_t)(nt * 4 + ks) * 64 + l) * 8;
            short8 bh = *(const short8*)bp;
            short8 bl = *(const short8*)(bp + LOOFF);
            acc = __builtin_amdgcn_mfma_f32_16x16x32_bf16(a1[ks], bh, acc, 0, 0, 0);
            acc = __builtin_amdgcn_mfma_f32_16x16x32_bf16(a1[ks], bl, acc, 0, 0, 0);
            if (DUAL) {
                const unsigned short* bp2 = B2 + ((size_t)(nt * 4 + ks) * 64 + l) * 8;
                short8 b2h = *(const short8*)bp2;
                short8 b2l = *(const short8*)(bp2 + LOOFF);
                acc = __builtin_amdgcn_mfma_f32_16x16x32_bf16(a2[ks], b2h, acc, 0, 0, 0);
                acc = __builtin_amdgcn_mfma_f32_16x16x32_bf16(a2[ks], b2l, acc, 0, 0, 0);
            }
        }
        float bc = bias[nt * 16 + cL];
#pragma unroll
        for (int reg = 0; reg < 4; ++reg) {
            int row = orow + reg;
            if (row < N_NODES) {
                float v = acc[reg] + bc;
                if (ACT == 1) v = gelu_tanh(v);
                if (OBF)
                    ((unsigned short*)outp)[(size_t)row * OUTC + nt * 16 + cL] = f2bf(v);
                else
                    ((float*)outp)[(size_t)row * OUTC + nt * 16 + cL] = v;
            }
        }
    }
}

// ---------------------------------------------------------------------------
// CSR build.  count_deg fused with edge-index echo (both read ei once).
// ---------------------------------------------------------------------------
__global__ void count_deg_echo(const int* __restrict__ ei, int* __restrict__ deg,
                               float* __restrict__ echo) {
    int e = blockIdx.x * 256 + threadIdx.x;
    if (e < 2 * N_EDGES) {
        int v = ei[e];
        echo[e] = (float)v;
        if (e >= N_EDGES) atomicAdd(&deg[v], 1);
    }
}

// One-kernel exclusive scan via atomic cursor. Block bases are assigned in
// nondeterministic order, but per-node segments hold the same element SET, and
// segment-max is order-invariant -> final output bit-identical.
__global__ void build_off(const int* __restrict__ deg, int* __restrict__ off,
                          int* __restrict__ cursor) {
    __shared__ int sm[256];
    __shared__ int base;
    int t = threadIdx.x;
    int i = blockIdx.x * 256 + t;
    int v = (i < N_NODES) ? deg[i] : 0;
    sm[t] = v;
    __syncthreads();
    for (int s = 1; s < 256; s <<= 1) {
        int tv = (t >= s) ? sm[t - s] : 0;
        __syncthreads();
        sm[t] += tv;
        __syncthreads();
    }
    if (t == 255) base = atomicAdd(cursor, sm[255]);
    __syncthreads();
    if (i < N_NODES) off[i] = base + sm[t] - v;
}

__global__ void fill_csr(const int* __restrict__ ei, const int* __restrict__ off,
                         int* __restrict__ cnt, int* __restrict__ csr) {
    int e = blockIdx.x * 256 + threadIdx.x;
    if (e < N_EDGES) {
        int dst = ei[N_EDGES + e];
        int p = atomicAdd(&cnt[dst], 1);
        csr[off[dst] + p] = ei[e];  // store src node id
    }
}

// ---------------------------------------------------------------------------
// Gather segment max over bf16 rows: one wave per node, ushort2 (1 dword)/lane.
// acc=0 init realizes relu(max(.)) + isolated-node-zero. Output bf16 exact.
// ---------------------------------------------------------------------------
__global__ __launch_bounds__(256) void seg_max_bf(const unsigned short* __restrict__ y,
                                                  const int* __restrict__ csr,
                                                  const int* __restrict__ off,
                                                  const int* __restrict__ deg,
                                                  unsigned short* __restrict__ agg) {
    int n = blockIdx.x * 4 + (threadIdx.x >> 6);
    int lane = threadIdx.x & 63;
    int s = off[n];
    int d = deg[n];
    const unsigned short* yb = y + lane * 2;
    float a0 = 0.f, a1 = 0.f;
    int i = 0;
    for (; i + 4 <= d; i += 4) {
        int s0 = csr[s + i], s1 = csr[s + i + 1], s2 = csr[s + i + 2], s3 = csr[s + i + 3];
        unsigned v0 = *(const unsigned*)(yb + (size_t)s0 * HID);
        unsigned v1 = *(const unsigned*)(yb + (size_t)s1 * HID);
        unsigned v2 = *(const unsigned*)(yb + (size_t)s2 * HID);
        unsigned v3 = *(const unsigned*)(yb + (size_t)s3 * HID);
        a0 = fmaxf(a0, fmaxf(fmaxf(__uint_as_float(v0 << 16), __uint_as_float(v1 << 16)),
                             fmaxf(__uint_as_float(v2 << 16), __uint_as_float(v3 << 16))));
        a1 = fmaxf(a1, fmaxf(fmaxf(__uint_as_float(v0 & 0xffff0000u), __uint_as_float(v1 & 0xffff0000u)),
                             fmaxf(__uint_as_float(v2 & 0xffff0000u), __uint_as_float(v3 & 0xffff0000u))));
    }
    for (; i < d; ++i) {
        int s0 = csr[s + i];
        unsigned v0 = *(const unsigned*)(yb + (size_t)s0 * HID);
        a0 = fmaxf(a0, __uint_as_float(v0 << 16));
        a1 = fmaxf(a1, __uint_as_float(v0 & 0xffff0000u));
    }
    // a0/a1 are maxes of bf16-representable values (or 0) -> f2bf exact
    unsigned o = (unsigned)f2bf(a0) | ((unsigned)f2bf(a1) << 16);
    *(unsigned*)(agg + (size_t)n * HID + lane * 2) = o;
}

extern "C" void kernel_launch(void* const* d_in, const int* in_sizes, int n_in,
                              void* d_out, int out_size, void* d_ws, size_t ws_size,
                              hipStream_t stream) {
    const float* x    = (const float*)d_in[0];
    const int*   ei   = (const int*)d_in[1];
    const float* Wp1  = (const float*)d_in[2];
    const float* bp1  = (const float*)d_in[3];
    const float* Wl1  = (const float*)d_in[4];
    const float* bl1  = (const float*)d_in[5];
    const float* Wr1  = (const float*)d_in[6];
    const float* Wp2  = (const float*)d_in[7];
    const float* bp2  = (const float*)d_in[8];
    const float* Wl2  = (const float*)d_in[9];
    const float* bl2  = (const float*)d_in[10];
    const float* Wr2  = (const float*)d_in[11];
    const float* Wlin = (const float*)d_in[12];
    const float* blin = (const float*)d_in[13];
    float* out = (float*)d_out;

    // ws layout (ushort units for bf16 region)
    unsigned short* wpack = (unsigned short*)d_ws;            // 262144
    unsigned short* xbf   = wpack + 262144;                   // 6.4M
    unsigned short* ybf   = xbf + (size_t)N_NODES * HID;      // 6.4M
    unsigned short* aggbf = ybf + (size_t)N_NODES * HID;      // 6.4M
    unsigned short* h1bf  = aggbf + (size_t)N_NODES * HID;    // 6.4M
    int* deg    = (int*)(h1bf + (size_t)N_NODES * HID);
    int* cnt    = deg + N_NODES;
    int* cursor = cnt + N_NODES;   // 1 int (zeroed together with deg/cnt)
    int* off    = cursor + 2;      // keep 8B alignment
    int* csr    = off + N_NODES;

    const unsigned short* Bp1 = wpack + 0;
    const unsigned short* Bl1 = wpack + 32768;
    const unsigned short* Br1 = wpack + 65536;
    const unsigned short* Bp2 = wpack + 98304;
    const unsigned short* Bl2 = wpack + 131072;
    const unsigned short* Br2 = wpack + 163840;
    const unsigned short* Blin = wpack + 196608;

    const int RB  = (N_NODES + 63) / 64;      // 782
    const int NPB = (N_NODES + 255) / 256;    // 196

    // prep: pack weights, convert x, zero deg/cnt/cursor
    hipLaunchKernelGGL(pack_weights, dim3(128, 7), dim3(256), 0, stream,
                       Wp1, Wl1, Wr1, Wp2, Wl2, Wr2, Wlin, wpack);
    hipLaunchKernelGGL(cvt_x, dim3((N_NODES * HID / 8 + 255) / 256), dim3(256), 0, stream,
                       x, xbf);
    hipMemsetAsync(deg, 0, (2 * N_NODES + 2) * sizeof(int), stream);

    // CSR build (+ edge echo fused)
    hipLaunchKernelGGL(count_deg_echo, dim3((2 * N_EDGES + 255) / 256), dim3(256), 0, stream,
                       ei, deg, out + (size_t)N_NODES * 256);
    hipLaunchKernelGGL(build_off, dim3(NPB), dim3(256), 0, stream, deg, off, cursor);
    hipLaunchKernelGGL(fill_csr, dim3((N_EDGES + 255) / 256), dim3(256), 0, stream,
                       ei, off, cnt, csr);

    // ---------------- layer 1 ----------------
    hipLaunchKernelGGL((mfma_linear<8, false, 0, true>), dim3(RB), dim3(256), 0, stream,
                       xbf, xbf, Bp1, Bp1, bp1, ybf);
    hipLaunchKernelGGL(seg_max_bf, dim3(N_NODES / 4), dim3(256), 0, stream,
                       ybf, csr, off, deg, aggbf);
    hipLaunchKernelGGL((mfma_linear<8, true, 1, true>), dim3(RB), dim3(256), 0, stream,
                       aggbf, xbf, Bl1, Br1, bl1, h1bf);

    // ---------------- layer 2 ----------------
    hipLaunchKernelGGL((mfma_linear<8, false, 0, true>), dim3(RB), dim3(256), 0, stream,
                       h1bf, h1bf, Bp2, Bp2, bp2, ybf);
    hipLaunchKernelGGL(seg_max_bf, dim3(N_NODES / 4), dim3(256), 0, stream,
                       ybf, csr, off, deg, aggbf);
    // h2 -> reuse ybf
    hipLaunchKernelGGL((mfma_linear<8, true, 1, true>), dim3(RB), dim3(256), 0, stream,
                       aggbf, h1bf, Bl2, Br2, bl2, ybf);

    // ---------------- final linear (f32 out) ----------------
    hipLaunchKernelGGL((mfma_linear<16, false, 1, false>), dim3(RB), dim3(256), 0, stream,
                       ybf, ybf, Blin, Blin, blin, out);
}

// Round 5
// 247.830 us; speedup vs baseline: 7.4554x; 1.0948x over previous
//
#include <hip/hip_runtime.h>

#define N_NODES 50000
#define N_EDGES 600000
#define HID 128

typedef __attribute__((ext_vector_type(8))) short short8;
typedef __attribute__((ext_vector_type(4))) short short4_t;
typedef __attribute__((ext_vector_type(4))) float f32x4;

__device__ __forceinline__ unsigned short f2bf(float f) {
    unsigned u = __float_as_uint(f);
    unsigned r = u + 0x7FFFu + ((u >> 16) & 1u);  // RNE
    return (unsigned short)(r >> 16);
}
__device__ __forceinline__ float bf2f(unsigned short h) {
    return __uint_as_float(((unsigned)h) << 16);
}

// gelu(tanh approx) == x / (1 + exp(-2u)), u = 0.79788456*(x + 0.044715 x^3)
__device__ __forceinline__ float gelu_fast(float x) {
    float u = 0.7978845608028654f * (x + 0.044715f * x * x * x);
    return x / (1.0f + __expf(-2.0f * u));
}

// ---------------------------------------------------------------------------
// Pack weights into MFMA B-fragment order, bf16 hi + lo regions.
// B-frag (16x16x32): n = nt*16 + (lane&15), k = ks*32 + (lane>>4)*8 + j.
// Layout verified empirically in R3.
// ---------------------------------------------------------------------------
__global__ void pack_weights(const float* __restrict__ Wp1,
                             const float* __restrict__ Wl1,
                             const float* __restrict__ Wr1,
                             const float* __restrict__ Wp2,
                             const float* __restrict__ Wl2,
                             const float* __restrict__ Wr2,
                             const float* __restrict__ Wlin,
                             unsigned short* __restrict__ out) {
    int which = blockIdx.y;
    const float* W;
    int count, base;
    switch (which) {
        case 0: W = Wp1; count = 16384; base = 0; break;
        case 1: W = Wl1; count = 16384; base = 32768; break;
        case 2: W = Wr1; count = 16384; base = 65536; break;
        case 3: W = Wp2; count = 16384; base = 98304; break;
        case 4: W = Wl2; count = 16384; base = 131072; break;
        case 5: W = Wr2; count = 16384; base = 163840; break;
        default: W = Wlin; count = 32768; base = 196608; break;
    }
    int idx = blockIdx.x * 256 + threadIdx.x;
    if (idx >= count) return;
    int j = idx & 7;
    int lane = (idx >> 3) & 63;
    int ks = (idx >> 9) & 3;
    int nt = idx >> 11;
    int c = nt * 16 + (lane & 15);
    int k = ks * 32 + (lane >> 4) * 8 + j;
    float v = W[c * 128 + k];
    unsigned short hi = f2bf(v);
    unsigned short lo = f2bf(v - bf2f(hi));
    out[base + idx] = hi;
    out[base + count + idx] = lo;
}

// x f32 -> bf16 (one-time)
__global__ void cvt_x(const float* __restrict__ in, unsigned short* __restrict__ out) {
    int tid = blockIdx.x * 256 + threadIdx.x;
    size_t i8 = (size_t)tid * 8;
    if (i8 >= (size_t)N_NODES * HID) return;
    float4 v0 = *(const float4*)(in + i8);
    float4 v1 = *(const float4*)(in + i8 + 4);
    short8 o;
    o[0] = f2bf(v0.x); o[1] = f2bf(v0.y); o[2] = f2bf(v0.z); o[3] = f2bf(v0.w);
    o[4] = f2bf(v1.x); o[5] = f2bf(v1.y); o[6] = f2bf(v1.z); o[7] = f2bf(v1.w);
    *(short8*)(out + i8) = o;
}

// ---------------------------------------------------------------------------
// MFMA linear, 2-term bf16 split (A exact bf16):
// out[n][c] = act(bias[c] + in1[n]·W1[:,c] (+ in2[n]·W2[:,c]))
// 128 thr = 2 waves; each wave owns 32 rows (2 row-frags sharing B loads).
// B loads software-pipelined 1 step; epilogue coalesced via wave-private
// LDS bounce (tile stride 20 floats -> 16B-aligned float4, <=2-way banks).
// ---------------------------------------------------------------------------
template <int NT, bool DUAL, int ACT, bool OBF>
__global__ __launch_bounds__(128) void mfma_linear(
        const unsigned short* __restrict__ in1, const unsigned short* __restrict__ in2,
        const unsigned short* __restrict__ B1, const unsigned short* __restrict__ B2,
        const float* __restrict__ bias, void* __restrict__ outp) {
    constexpr int OUTC = NT * 16;
    constexpr int LOOFF = NT * 2048;  // ushorts in hi region
    __shared__ alignas(16) float tile[2][2][16][20];

    const int t = threadIdx.x;
    const int w = t >> 6;
    const int l = t & 63;
    const int waveRow = blockIdx.x * 64 + w * 32;

    // A fragment rows (clamped for tail block)
    int r0 = waveRow + (l & 15);
    int r1 = r0 + 16;
    if (r0 > N_NODES - 1) r0 = N_NODES - 1;
    if (r1 > N_NODES - 1) r1 = N_NODES - 1;
    const int ko = (l >> 4) * 8;

    short8 a1[2][4], a2[2][4];
#pragma unroll
    for (int ks = 0; ks < 4; ++ks) {
        a1[0][ks] = *(const short8*)(in1 + (size_t)r0 * HID + ks * 32 + ko);
        a1[1][ks] = *(const short8*)(in1 + (size_t)r1 * HID + ks * 32 + ko);
        if (DUAL) {
            a2[0][ks] = *(const short8*)(in2 + (size_t)r0 * HID + ks * 32 + ko);
            a2[1][ks] = *(const short8*)(in2 + (size_t)r1 * HID + ks * 32 + ko);
        }
    }

    const int cL = l & 15;
    const int rfrag = (l >> 4) * 4;   // compute-lane row base in 16-row tile
    const int rr = l >> 2;            // bounce-read row
    const int c4 = (l & 3) * 4;       // bounce-read col base

    // B double-buffer (statically indexed under full unroll)
    short8 bh[2], bl[2], b2h[2], b2l[2];
    {
        const unsigned short* bp = B1 + (size_t)l * 8;
        bh[0] = *(const short8*)bp;
        bl[0] = *(const short8*)(bp + LOOFF);
        if (DUAL) {
            const unsigned short* bp2 = B2 + (size_t)l * 8;
            b2h[0] = *(const short8*)bp2;
            b2l[0] = *(const short8*)(bp2 + LOOFF);
        }
    }

#pragma unroll
    for (int nt = 0; nt < NT; ++nt) {
        f32x4 acc0 = {0.f, 0.f, 0.f, 0.f};
        f32x4 acc1 = {0.f, 0.f, 0.f, 0.f};
#pragma unroll
        for (int ks = 0; ks < 4; ++ks) {
            const int idx = nt * 4 + ks;
            const int cur = idx & 1;
            const int nxt = cur ^ 1;
            if (idx + 1 < NT * 4) {  // prefetch next B pair
                const unsigned short* bp = B1 + ((size_t)(idx + 1) * 64 + l) * 8;
                bh[nxt] = *(const short8*)bp;
                bl[nxt] = *(const short8*)(bp + LOOFF);
                if (DUAL) {
                    const unsigned short* bp2 = B2 + ((size_t)(idx + 1) * 64 + l) * 8;
                    b2h[nxt] = *(const short8*)bp2;
                    b2l[nxt] = *(const short8*)(bp2 + LOOFF);
                }
            }
            acc0 = __builtin_amdgcn_mfma_f32_16x16x32_bf16(a1[0][ks], bh[cur], acc0, 0, 0, 0);
            acc1 = __builtin_amdgcn_mfma_f32_16x16x32_bf16(a1[1][ks], bh[cur], acc1, 0, 0, 0);
            acc0 = __builtin_amdgcn_mfma_f32_16x16x32_bf16(a1[0][ks], bl[cur], acc0, 0, 0, 0);
            acc1 = __builtin_amdgcn_mfma_f32_16x16x32_bf16(a1[1][ks], bl[cur], acc1, 0, 0, 0);
            if (DUAL) {
                acc0 = __builtin_amdgcn_mfma_f32_16x16x32_bf16(a2[0][ks], b2h[cur], acc0, 0, 0, 0);
                acc1 = __builtin_amdgcn_mfma_f32_16x16x32_bf16(a2[1][ks], b2h[cur], acc1, 0, 0, 0);
                acc0 = __builtin_amdgcn_mfma_f32_16x16x32_bf16(a2[0][ks], b2l[cur], acc0, 0, 0, 0);
                acc1 = __builtin_amdgcn_mfma_f32_16x16x32_bf16(a2[1][ks], b2l[cur], acc1, 0, 0, 0);
            }
        }

        // epilogue: bias + act at compute lanes, bounce via LDS, coalesced store
        float bc = bias[nt * 16 + cL];
#pragma unroll
        for (int reg = 0; reg < 4; ++reg) {
            float v0 = acc0[reg] + bc;
            float v1 = acc1[reg] + bc;
            if (ACT == 1) { v0 = gelu_fast(v0); v1 = gelu_fast(v1); }
            tile[w][0][rfrag + reg][cL] = v0;
            tile[w][1][rfrag + reg][cL] = v1;
        }
        asm volatile("s_waitcnt lgkmcnt(0)" ::: "memory");
#pragma unroll
        for (int f = 0; f < 2; ++f) {
            float4 vv = *(const float4*)&tile[w][f][rr][c4];
            int row = waveRow + f * 16 + rr;
            if (row < N_NODES) {
                if (OBF) {
                    short4_t o;
                    o[0] = f2bf(vv.x); o[1] = f2bf(vv.y);
                    o[2] = f2bf(vv.z); o[3] = f2bf(vv.w);
                    *(short4_t*)((unsigned short*)outp + (size_t)row * OUTC + nt * 16 + c4) = o;
                } else {
                    *(float4*)((float*)outp + (size_t)row * OUTC + nt * 16 + c4) = vv;
                }
            }
        }
        asm volatile("s_waitcnt lgkmcnt(0)" ::: "memory");  // reads done before next nt overwrites
    }
}

// ---------------------------------------------------------------------------
// CSR build.  count_deg fused with edge-index echo (both read ei once).
// ---------------------------------------------------------------------------
__global__ void count_deg_echo(const int* __restrict__ ei, int* __restrict__ deg,
                               float* __restrict__ echo) {
    int e = blockIdx.x * 256 + threadIdx.x;
    if (e < 2 * N_EDGES) {
        int v = ei[e];
        echo[e] = (float)v;
        if (e >= N_EDGES) atomicAdd(&deg[v], 1);
    }
}

// One-kernel exclusive scan via atomic cursor. Block bases are assigned in
// nondeterministic order, but per-node segments hold the same element SET, and
// segment-max is order-invariant -> final output bit-identical.
__global__ void build_off(const int* __restrict__ deg, int* __restrict__ off,
                          int* __restrict__ cursor) {
    __shared__ int sm[256];
    __shared__ int base;
    int t = threadIdx.x;
    int i = blockIdx.x * 256 + t;
    int v = (i < N_NODES) ? deg[i] : 0;
    sm[t] = v;
    __syncthreads();
    for (int s = 1; s < 256; s <<= 1) {
        int tv = (t >= s) ? sm[t - s] : 0;
        __syncthreads();
        sm[t] += tv;
        __syncthreads();
    }
    if (t == 255) base = atomicAdd(cursor, sm[255]);
    __syncthreads();
    if (i < N_NODES) off[i] = base + sm[t] - v;
}

__global__ void fill_csr(const int* __restrict__ ei, const int* __restrict__ off,
                         int* __restrict__ cnt, int* __restrict__ csr) {
    int e = blockIdx.x * 256 + threadIdx.x;
    if (e < N_EDGES) {
        int dst = ei[N_EDGES + e];
        int p = atomicAdd(&cnt[dst], 1);
        csr[off[dst] + p] = ei[e];  // store src node id
    }
}

// ---------------------------------------------------------------------------
// Gather segment max over bf16 rows: one wave per node, ushort2 (1 dword)/lane.
// acc=0 init realizes relu(max(.)) + isolated-node-zero. Output bf16 exact.
// ---------------------------------------------------------------------------
__global__ __launch_bounds__(256) void seg_max_bf(const unsigned short* __restrict__ y,
                                                  const int* __restrict__ csr,
                                                  const int* __restrict__ off,
                                                  const int* __restrict__ deg,
                                                  unsigned short* __restrict__ agg) {
    int n = blockIdx.x * 4 + (threadIdx.x >> 6);
    int lane = threadIdx.x & 63;
    int s = off[n];
    int d = deg[n];
    const unsigned short* yb = y + lane * 2;
    float a0 = 0.f, a1 = 0.f;
    int i = 0;
    for (; i + 4 <= d; i += 4) {
        int s0 = csr[s + i], s1 = csr[s + i + 1], s2 = csr[s + i + 2], s3 = csr[s + i + 3];
        unsigned v0 = *(const unsigned*)(yb + (size_t)s0 * HID);
        unsigned v1 = *(const unsigned*)(yb + (size_t)s1 * HID);
        unsigned v2 = *(const unsigned*)(yb + (size_t)s2 * HID);
        unsigned v3 = *(const unsigned*)(yb + (size_t)s3 * HID);
        a0 = fmaxf(a0, fmaxf(fmaxf(__uint_as_float(v0 << 16), __uint_as_float(v1 << 16)),
                             fmaxf(__uint_as_float(v2 << 16), __uint_as_float(v3 << 16))));
        a1 = fmaxf(a1, fmaxf(fmaxf(__uint_as_float(v0 & 0xffff0000u), __uint_as_float(v1 & 0xffff0000u)),
                             fmaxf(__uint_as_float(v2 & 0xffff0000u), __uint_as_float(v3 & 0xffff0000u))));
    }
    for (; i < d; ++i) {
        int s0 = csr[s + i];
        unsigned v0 = *(const unsigned*)(yb + (size_t)s0 * HID);
        a0 = fmaxf(a0, __uint_as_float(v0 << 16));
        a1 = fmaxf(a1, __uint_as_float(v0 & 0xffff0000u));
    }
    unsigned o = (unsigned)f2bf(a0) | ((unsigned)f2bf(a1) << 16);
    *(unsigned*)(agg + (size_t)n * HID + lane * 2) = o;
}

extern "C" void kernel_launch(void* const* d_in, const int* in_sizes, int n_in,
                              void* d_out, int out_size, void* d_ws, size_t ws_size,
                              hipStream_t stream) {
    const float* x    = (const float*)d_in[0];
    const int*   ei   = (const int*)d_in[1];
    const float* Wp1  = (const float*)d_in[2];
    const float* bp1  = (const float*)d_in[3];
    const float* Wl1  = (const float*)d_in[4];
    const float* bl1  = (const float*)d_in[5];
    const float* Wr1  = (const float*)d_in[6];
    const float* Wp2  = (const float*)d_in[7];
    const float* bp2  = (const float*)d_in[8];
    const float* Wl2  = (const float*)d_in[9];
    const float* bl2  = (const float*)d_in[10];
    const float* Wr2  = (const float*)d_in[11];
    const float* Wlin = (const float*)d_in[12];
    const float* blin = (const float*)d_in[13];
    float* out = (float*)d_out;

    // ws layout (ushort units for bf16 region)
    unsigned short* wpack = (unsigned short*)d_ws;            // 262144
    unsigned short* xbf   = wpack + 262144;
    unsigned short* ybf   = xbf + (size_t)N_NODES * HID;
    unsigned short* aggbf = ybf + (size_t)N_NODES * HID;
    unsigned short* h1bf  = aggbf + (size_t)N_NODES * HID;
    int* deg    = (int*)(h1bf + (size_t)N_NODES * HID);
    int* cnt    = deg + N_NODES;
    int* cursor = cnt + N_NODES;   // zeroed with deg/cnt
    int* off    = cursor + 2;
    int* csr    = off + N_NODES;

    const unsigned short* Bp1 = wpack + 0;
    const unsigned short* Bl1 = wpack + 32768;
    const unsigned short* Br1 = wpack + 65536;
    const unsigned short* Bp2 = wpack + 98304;
    const unsigned short* Bl2 = wpack + 131072;
    const unsigned short* Br2 = wpack + 163840;
    const unsigned short* Blin = wpack + 196608;

    const int RB  = (N_NODES + 63) / 64;      // 782 blocks of 128 thr (64 rows)
    const int NPB = (N_NODES + 255) / 256;

    // prep: pack weights, convert x, zero deg/cnt/cursor
    hipLaunchKernelGGL(pack_weights, dim3(128, 7), dim3(256), 0, stream,
                       Wp1, Wl1, Wr1, Wp2, Wl2, Wr2, Wlin, wpack);
    hipLaunchKernelGGL(cvt_x, dim3((N_NODES * HID / 8 + 255) / 256), dim3(256), 0, stream,
                       x, xbf);
    hipMemsetAsync(deg, 0, (2 * N_NODES + 2) * sizeof(int), stream);

    // CSR build (+ edge echo fused)
    hipLaunchKernelGGL(count_deg_echo, dim3((2 * N_EDGES + 255) / 256), dim3(256), 0, stream,
                       ei, deg, out + (size_t)N_NODES * 256);
    hipLaunchKernelGGL(build_off, dim3(NPB), dim3(256), 0, stream, deg, off, cursor);
    hipLaunchKernelGGL(fill_csr, dim3((N_EDGES + 255) / 256), dim3(256), 0, stream,
                       ei, off, cnt, csr);

    // ---------------- layer 1 ----------------
    hipLaunchKernelGGL((mfma_linear<8, false, 0, true>), dim3(RB), dim3(128), 0, stream,
                       xbf, xbf, Bp1, Bp1, bp1, ybf);
    hipLaunchKernelGGL(seg_max_bf, dim3(N_NODES / 4), dim3(256), 0, stream,
                       ybf, csr, off, deg, aggbf);
    hipLaunchKernelGGL((mfma_linear<8, true, 1, true>), dim3(RB), dim3(128), 0, stream,
                       aggbf, xbf, Bl1, Br1, bl1, h1bf);

    // ---------------- layer 2 ----------------
    hipLaunchKernelGGL((mfma_linear<8, false, 0, true>), dim3(RB), dim3(128), 0, stream,
                       h1bf, h1bf, Bp2, Bp2, bp2, ybf);
    hipLaunchKernelGGL(seg_max_bf, dim3(N_NODES / 4), dim3(256), 0, stream,
                       ybf, csr, off, deg, aggbf);
    hipLaunchKernelGGL((mfma_linear<8, true, 1, true>), dim3(RB), dim3(128), 0, stream,
                       aggbf, h1bf, Bl2, Br2, bl2, ybf);

    // ---------------- final linear (f32 out) ----------------
    hipLaunchKernelGGL((mfma_linear<16, false, 1, false>), dim3(RB), dim3(128), 0, stream,
                       ybf, ybf, Blin, Blin, blin, out);
}

// Round 6
// 244.603 us; speedup vs baseline: 7.5537x; 1.0132x over previous
//
#include <hip/hip_runtime.h>

#define N_NODES 50000
#define N_EDGES 600000
#define HID 128

typedef __attribute__((ext_vector_type(8))) short short8;
typedef __attribute__((ext_vector_type(4))) short short4_t;
typedef __attribute__((ext_vector_type(4))) float f32x4;

__device__ __forceinline__ unsigned short f2bf(float f) {
    unsigned u = __float_as_uint(f);
    unsigned r = u + 0x7FFFu + ((u >> 16) & 1u);  // RNE
    return (unsigned short)(r >> 16);
}
__device__ __forceinline__ float bf2f(unsigned short h) {
    return __uint_as_float(((unsigned)h) << 16);
}

// gelu(tanh approx) == x / (1 + exp(-2u)), u = 0.79788456*(x + 0.044715 x^3)
__device__ __forceinline__ float gelu_fast(float x) {
    float u = 0.7978845608028654f * (x + 0.044715f * x * x * x);
    return x / (1.0f + __expf(-2.0f * u));
}

// ---------------------------------------------------------------------------
// prep: fused weight pack (blocks 0..895) + x f32->bf16 convert (rest).
// Pack: MFMA B-frag order, bf16 hi+lo regions (layout verified R3).
//   n = nt*16 + (lane&15), k = ks*32 + (lane>>4)*8 + j.
// ---------------------------------------------------------------------------
#define PACK_BLOCKS 896          // 7 matrices x 128 blocks
#define CVT_BLOCKS  3125         // 50000*128/8/256
__global__ void prep(const float* __restrict__ x, unsigned short* __restrict__ xbf,
                     const float* __restrict__ Wp1, const float* __restrict__ Wl1,
                     const float* __restrict__ Wr1, const float* __restrict__ Wp2,
                     const float* __restrict__ Wl2, const float* __restrict__ Wr2,
                     const float* __restrict__ Wlin, unsigned short* __restrict__ wpack) {
    int b = blockIdx.x;
    if (b < PACK_BLOCKS) {
        int which = b >> 7;  // /128
        const float* W;
        int count, base;
        switch (which) {
            case 0: W = Wp1; count = 16384; base = 0; break;
            case 1: W = Wl1; count = 16384; base = 32768; break;
            case 2: W = Wr1; count = 16384; base = 65536; break;
            case 3: W = Wp2; count = 16384; base = 98304; break;
            case 4: W = Wl2; count = 16384; base = 131072; break;
            case 5: W = Wr2; count = 16384; base = 163840; break;
            default: W = Wlin; count = 32768; base = 196608; break;
        }
        int idx = (b & 127) * 256 + threadIdx.x;
        if (which == 6) idx = ((b & 127) & 63) * 512 + threadIdx.x * 2;  // unused path guard
        // simpler: recompute for which==6 with 128 blocks covering 32768 via 2/thread
        if (which < 6) {
            if (idx >= count) return;
            int j = idx & 7;
            int lane = (idx >> 3) & 63;
            int ks = (idx >> 9) & 3;
            int nt = idx >> 11;
            int c = nt * 16 + (lane & 15);
            int k = ks * 32 + (lane >> 4) * 8 + j;
            float v = W[c * 128 + k];
            unsigned short hi = f2bf(v);
            unsigned short lo = f2bf(v - bf2f(hi));
            wpack[base + idx] = hi;
            wpack[base + count + idx] = lo;
        } else {
            int i0 = (b & 127) * 256 + threadIdx.x;
#pragma unroll
            for (int rep = 0; rep < 2; ++rep) {
                int idx2 = i0 + rep * 16384;
                int j = idx2 & 7;
                int lane = (idx2 >> 3) & 63;
                int ks = (idx2 >> 9) & 3;
                int nt = idx2 >> 11;
                int c = nt * 16 + (lane & 15);
                int k = ks * 32 + (lane >> 4) * 8 + j;
                float v = W[c * 128 + k];
                unsigned short hi = f2bf(v);
                unsigned short lo = f2bf(v - bf2f(hi));
                wpack[base + idx2] = hi;
                wpack[base + count + idx2] = lo;
            }
        }
    } else {
        int tid = (b - PACK_BLOCKS) * 256 + threadIdx.x;
        size_t i8 = (size_t)tid * 8;
        if (i8 >= (size_t)N_NODES * HID) return;
        float4 v0 = *(const float4*)(x + i8);
        float4 v1 = *(const float4*)(x + i8 + 4);
        short8 o;
        o[0] = f2bf(v0.x); o[1] = f2bf(v0.y); o[2] = f2bf(v0.z); o[3] = f2bf(v0.w);
        o[4] = f2bf(v1.x); o[5] = f2bf(v1.y); o[6] = f2bf(v1.z); o[7] = f2bf(v1.w);
        *(short8*)(xbf + i8) = o;
    }
}

// zero deg/cnt/cursor: replaces hipMemsetAsync (which lowered to a 41us
// tiny-grid fillBuffer — 17% of total runtime!).  uint4 stores, full grid.
__global__ void zero_init(int* __restrict__ p, int n4) {
    int i = blockIdx.x * 256 + threadIdx.x;
    if (i < n4) ((int4*)p)[i] = make_int4(0, 0, 0, 0);
}

// ---------------------------------------------------------------------------
// MFMA linear, 2-term bf16 split (A exact bf16):
// out[n][c] = act(bias[c] + in1[n]·W1[:,c] (+ in2[n]·W2[:,c]))
// 128 thr = 2 waves; each wave owns 32 rows (2 row-frags sharing B loads).
// B loads software-pipelined 1 step; epilogue coalesced via wave-private
// LDS bounce (stride 20 floats -> 16B-aligned float4, <=2-way banks).
// ---------------------------------------------------------------------------
template <int NT, bool DUAL, int ACT, bool OBF>
__global__ __launch_bounds__(128) void mfma_linear(
        const unsigned short* __restrict__ in1, const unsigned short* __restrict__ in2,
        const unsigned short* __restrict__ B1, const unsigned short* __restrict__ B2,
        const float* __restrict__ bias, void* __restrict__ outp) {
    constexpr int OUTC = NT * 16;
    constexpr int LOOFF = NT * 2048;  // ushorts in hi region
    __shared__ alignas(16) float tile[2][2][16][20];

    const int t = threadIdx.x;
    const int w = t >> 6;
    const int l = t & 63;
    const int waveRow = blockIdx.x * 64 + w * 32;

    int r0 = waveRow + (l & 15);
    int r1 = r0 + 16;
    if (r0 > N_NODES - 1) r0 = N_NODES - 1;
    if (r1 > N_NODES - 1) r1 = N_NODES - 1;
    const int ko = (l >> 4) * 8;

    short8 a1[2][4], a2[2][4];
#pragma unroll
    for (int ks = 0; ks < 4; ++ks) {
        a1[0][ks] = *(const short8*)(in1 + (size_t)r0 * HID + ks * 32 + ko);
        a1[1][ks] = *(const short8*)(in1 + (size_t)r1 * HID + ks * 32 + ko);
        if (DUAL) {
            a2[0][ks] = *(const short8*)(in2 + (size_t)r0 * HID + ks * 32 + ko);
            a2[1][ks] = *(const short8*)(in2 + (size_t)r1 * HID + ks * 32 + ko);
        }
    }

    const int cL = l & 15;
    const int rfrag = (l >> 4) * 4;
    const int rr = l >> 2;
    const int c4 = (l & 3) * 4;

    short8 bh[2], bl[2], b2h[2], b2l[2];
    {
        const unsigned short* bp = B1 + (size_t)l * 8;
        bh[0] = *(const short8*)bp;
        bl[0] = *(const short8*)(bp + LOOFF);
        if (DUAL) {
            const unsigned short* bp2 = B2 + (size_t)l * 8;
            b2h[0] = *(const short8*)bp2;
            b2l[0] = *(const short8*)(bp2 + LOOFF);
        }
    }

#pragma unroll
    for (int nt = 0; nt < NT; ++nt) {
        f32x4 acc0 = {0.f, 0.f, 0.f, 0.f};
        f32x4 acc1 = {0.f, 0.f, 0.f, 0.f};
#pragma unroll
        for (int ks = 0; ks < 4; ++ks) {
            const int idx = nt * 4 + ks;
            const int cur = idx & 1;
            const int nxt = cur ^ 1;
            if (idx + 1 < NT * 4) {
                const unsigned short* bp = B1 + ((size_t)(idx + 1) * 64 + l) * 8;
                bh[nxt] = *(const short8*)bp;
                bl[nxt] = *(const short8*)(bp + LOOFF);
                if (DUAL) {
                    const unsigned short* bp2 = B2 + ((size_t)(idx + 1) * 64 + l) * 8;
                    b2h[nxt] = *(const short8*)bp2;
                    b2l[nxt] = *(const short8*)(bp2 + LOOFF);
                }
            }
            acc0 = __builtin_amdgcn_mfma_f32_16x16x32_bf16(a1[0][ks], bh[cur], acc0, 0, 0, 0);
            acc1 = __builtin_amdgcn_mfma_f32_16x16x32_bf16(a1[1][ks], bh[cur], acc1, 0, 0, 0);
            acc0 = __builtin_amdgcn_mfma_f32_16x16x32_bf16(a1[0][ks], bl[cur], acc0, 0, 0, 0);
            acc1 = __builtin_amdgcn_mfma_f32_16x16x32_bf16(a1[1][ks], bl[cur], acc1, 0, 0, 0);
            if (DUAL) {
                acc0 = __builtin_amdgcn_mfma_f32_16x16x32_bf16(a2[0][ks], b2h[cur], acc0, 0, 0, 0);
                acc1 = __builtin_amdgcn_mfma_f32_16x16x32_bf16(a2[1][ks], b2h[cur], acc1, 0, 0, 0);
                acc0 = __builtin_amdgcn_mfma_f32_16x16x32_bf16(a2[0][ks], b2l[cur], acc0, 0, 0, 0);
                acc1 = __builtin_amdgcn_mfma_f32_16x16x32_bf16(a2[1][ks], b2l[cur], acc1, 0, 0, 0);
            }
        }

        float bc = bias[nt * 16 + cL];
#pragma unroll
        for (int reg = 0; reg < 4; ++reg) {
            float v0 = acc0[reg] + bc;
            float v1 = acc1[reg] + bc;
            if (ACT == 1) { v0 = gelu_fast(v0); v1 = gelu_fast(v1); }
            tile[w][0][rfrag + reg][cL] = v0;
            tile[w][1][rfrag + reg][cL] = v1;
        }
        asm volatile("s_waitcnt lgkmcnt(0)" ::: "memory");
#pragma unroll
        for (int f = 0; f < 2; ++f) {
            float4 vv = *(const float4*)&tile[w][f][rr][c4];
            int row = waveRow + f * 16 + rr;
            if (row < N_NODES) {
                if (OBF) {
                    short4_t o;
                    o[0] = f2bf(vv.x); o[1] = f2bf(vv.y);
                    o[2] = f2bf(vv.z); o[3] = f2bf(vv.w);
                    *(short4_t*)((unsigned short*)outp + (size_t)row * OUTC + nt * 16 + c4) = o;
                } else {
                    *(float4*)((float*)outp + (size_t)row * OUTC + nt * 16 + c4) = vv;
                }
            }
        }
        asm volatile("s_waitcnt lgkmcnt(0)" ::: "memory");
    }
}

// ---------------------------------------------------------------------------
// CSR build.  count_deg fused with edge-index echo (both read ei once).
// ---------------------------------------------------------------------------
__global__ void count_deg_echo(const int* __restrict__ ei, int* __restrict__ deg,
                               float* __restrict__ echo) {
    int e = blockIdx.x * 256 + threadIdx.x;
    if (e < 2 * N_EDGES) {
        int v = ei[e];
        echo[e] = (float)v;
        if (e >= N_EDGES) atomicAdd(&deg[v], 1);
    }
}

// One-kernel exclusive scan via atomic cursor. Block bases are assigned in
// nondeterministic order, but per-node segments hold the same element SET, and
// segment-max is order-invariant -> final output bit-identical.
__global__ void build_off(const int* __restrict__ deg, int* __restrict__ off,
                          int* __restrict__ cursor) {
    __shared__ int sm[256];
    __shared__ int base;
    int t = threadIdx.x;
    int i = blockIdx.x * 256 + t;
    int v = (i < N_NODES) ? deg[i] : 0;
    sm[t] = v;
    __syncthreads();
    for (int s = 1; s < 256; s <<= 1) {
        int tv = (t >= s) ? sm[t - s] : 0;
        __syncthreads();
        sm[t] += tv;
        __syncthreads();
    }
    if (t == 255) base = atomicAdd(cursor, sm[255]);
    __syncthreads();
    if (i < N_NODES) off[i] = base + sm[t] - v;
}

__global__ void fill_csr(const int* __restrict__ ei, const int* __restrict__ off,
                         int* __restrict__ cnt, int* __restrict__ csr) {
    int e = blockIdx.x * 256 + threadIdx.x;
    if (e < N_EDGES) {
        int dst = ei[N_EDGES + e];
        int p = atomicAdd(&cnt[dst], 1);
        csr[off[dst] + p] = ei[e];  // store src node id
    }
}

// ---------------------------------------------------------------------------
// Gather segment max over bf16 rows: one wave per node, ushort2 (1 dword)/lane.
// acc=0 init realizes relu(max(.)) + isolated-node-zero. Output bf16 exact.
// ---------------------------------------------------------------------------
__global__ __launch_bounds__(256) void seg_max_bf(const unsigned short* __restrict__ y,
                                                  const int* __restrict__ csr,
                                                  const int* __restrict__ off,
                                                  const int* __restrict__ deg,
                                                  unsigned short* __restrict__ agg) {
    int n = blockIdx.x * 4 + (threadIdx.x >> 6);
    int lane = threadIdx.x & 63;
    int s = off[n];
    int d = deg[n];
    const unsigned short* yb = y + lane * 2;
    float a0 = 0.f, a1 = 0.f;
    int i = 0;
    for (; i + 4 <= d; i += 4) {
        int s0 = csr[s + i], s1 = csr[s + i + 1], s2 = csr[s + i + 2], s3 = csr[s + i + 3];
        unsigned v0 = *(const unsigned*)(yb + (size_t)s0 * HID);
        unsigned v1 = *(const unsigned*)(yb + (size_t)s1 * HID);
        unsigned v2 = *(const unsigned*)(yb + (size_t)s2 * HID);
        unsigned v3 = *(const unsigned*)(yb + (size_t)s3 * HID);
        a0 = fmaxf(a0, fmaxf(fmaxf(__uint_as_float(v0 << 16), __uint_as_float(v1 << 16)),
                             fmaxf(__uint_as_float(v2 << 16), __uint_as_float(v3 << 16))));
        a1 = fmaxf(a1, fmaxf(fmaxf(__uint_as_float(v0 & 0xffff0000u), __uint_as_float(v1 & 0xffff0000u)),
                             fmaxf(__uint_as_float(v2 & 0xffff0000u), __uint_as_float(v3 & 0xffff0000u))));
    }
    for (; i < d; ++i) {
        int s0 = csr[s + i];
        unsigned v0 = *(const unsigned*)(yb + (size_t)s0 * HID);
        a0 = fmaxf(a0, __uint_as_float(v0 << 16));
        a1 = fmaxf(a1, __uint_as_float(v0 & 0xffff0000u));
    }
    unsigned o = (unsigned)f2bf(a0) | ((unsigned)f2bf(a1) << 16);
    *(unsigned*)(agg + (size_t)n * HID + lane * 2) = o;
}

extern "C" void kernel_launch(void* const* d_in, const int* in_sizes, int n_in,
                              void* d_out, int out_size, void* d_ws, size_t ws_size,
                              hipStream_t stream) {
    const float* x    = (const float*)d_in[0];
    const int*   ei   = (const int*)d_in[1];
    const float* Wp1  = (const float*)d_in[2];
    const float* bp1  = (const float*)d_in[3];
    const float* Wl1  = (const float*)d_in[4];
    const float* bl1  = (const float*)d_in[5];
    const float* Wr1  = (const float*)d_in[6];
    const float* Wp2  = (const float*)d_in[7];
    const float* bp2  = (const float*)d_in[8];
    const float* Wl2  = (const float*)d_in[9];
    const float* bl2  = (const float*)d_in[10];
    const float* Wr2  = (const float*)d_in[11];
    const float* Wlin = (const float*)d_in[12];
    const float* blin = (const float*)d_in[13];
    float* out = (float*)d_out;

    // ws layout (ushort units for bf16 region)
    unsigned short* wpack = (unsigned short*)d_ws;            // 262144
    unsigned short* xbf   = wpack + 262144;
    unsigned short* ybf   = xbf + (size_t)N_NODES * HID;
    unsigned short* aggbf = ybf + (size_t)N_NODES * HID;
    unsigned short* h1bf  = aggbf + (size_t)N_NODES * HID;
    int* deg    = (int*)(h1bf + (size_t)N_NODES * HID);
    int* cnt    = deg + N_NODES;
    int* cursor = cnt + N_NODES;   // zeroed with deg/cnt
    int* off    = cursor + 4;      // 16B-aligned for int4 zeroing
    int* csr    = off + N_NODES;

    const unsigned short* Bp1 = wpack + 0;
    const unsigned short* Bl1 = wpack + 32768;
    const unsigned short* Br1 = wpack + 65536;
    const unsigned short* Bp2 = wpack + 98304;
    const unsigned short* Bl2 = wpack + 131072;
    const unsigned short* Br2 = wpack + 163840;
    const unsigned short* Blin = wpack + 196608;

    const int RB  = (N_NODES + 63) / 64;      // 782 blocks of 128 thr
    const int NPB = (N_NODES + 255) / 256;

    // prep: pack weights + convert x (one launch); zero deg/cnt/cursor
    hipLaunchKernelGGL(prep, dim3(PACK_BLOCKS + CVT_BLOCKS), dim3(256), 0, stream,
                       x, xbf, Wp1, Wl1, Wr1, Wp2, Wl2, Wr2, Wlin, wpack);
    const int ZN4 = (2 * N_NODES + 4 + 3) / 4;  // int4 count covering deg..cursor
    hipLaunchKernelGGL(zero_init, dim3((ZN4 + 255) / 256), dim3(256), 0, stream,
                       deg, ZN4);

    // CSR build (+ edge echo fused)
    hipLaunchKernelGGL(count_deg_echo, dim3((2 * N_EDGES + 255) / 256), dim3(256), 0, stream,
                       ei, deg, out + (size_t)N_NODES * 256);
    hipLaunchKernelGGL(build_off, dim3(NPB), dim3(256), 0, stream, deg, off, cursor);
    hipLaunchKernelGGL(fill_csr, dim3((N_EDGES + 255) / 256), dim3(256), 0, stream,
                       ei, off, cnt, csr);

    // ---------------- layer 1 ----------------
    hipLaunchKernelGGL((mfma_linear<8, false, 0, true>), dim3(RB), dim3(128), 0, stream,
                       xbf, xbf, Bp1, Bp1, bp1, ybf);
    hipLaunchKernelGGL(seg_max_bf, dim3(N_NODES / 4), dim3(256), 0, stream,
                       ybf, csr, off, deg, aggbf);
    hipLaunchKernelGGL((mfma_linear<8, true, 1, true>), dim3(RB), dim3(128), 0, stream,
                       aggbf, xbf, Bl1, Br1, bl1, h1bf);

    // ---------------- layer 2 ----------------
    hipLaunchKernelGGL((mfma_linear<8, false, 0, true>), dim3(RB), dim3(128), 0, stream,
                       h1bf, h1bf, Bp2, Bp2, bp2, ybf);
    hipLaunchKernelGGL(seg_max_bf, dim3(N_NODES / 4), dim3(256), 0, stream,
                       ybf, csr, off, deg, aggbf);
    hipLaunchKernelGGL((mfma_linear<8, true, 1, true>), dim3(RB), dim3(128), 0, stream,
                       aggbf, h1bf, Bl2, Br2, bl2, ybf);

    // ---------------- final linear (f32 out) ----------------
    hipLaunchKernelGGL((mfma_linear<16, false, 1, false>), dim3(RB), dim3(128), 0, stream,
                       ybf, ybf, Blin, Blin, blin, out);
}

// Round 7
// 233.495 us; speedup vs baseline: 7.9131x; 1.0476x over previous
//
#include <hip/hip_runtime.h>

#define N_NODES 50000
#define N_EDGES 600000
#define HID 128

typedef __attribute__((ext_vector_type(8))) short short8;
typedef __attribute__((ext_vector_type(4))) short short4_t;
typedef __attribute__((ext_vector_type(4))) float f32x4;

__device__ __forceinline__ unsigned short f2bf(float f) {
    unsigned u = __float_as_uint(f);
    unsigned r = u + 0x7FFFu + ((u >> 16) & 1u);  // RNE
    return (unsigned short)(r >> 16);
}
__device__ __forceinline__ float bf2f(unsigned short h) {
    return __uint_as_float(((unsigned)h) << 16);
}

// gelu(tanh approx) == x / (1 + exp(-2u)), u = 0.79788456*(x + 0.044715 x^3)
__device__ __forceinline__ float gelu_fast(float x) {
    float u = 0.7978845608028654f * (x + 0.044715f * x * x * x);
    return x / (1.0f + __expf(-2.0f * u));
}

// ---------------------------------------------------------------------------
// prep: weight pack (blocks 0..895) + zero deg/cnt/cursor (next 98 blocks)
//       + x f32->bf16 convert (rest).
// Pack layout (verified R3-R6): n = nt*16+(lane&15), k = ks*32+(lane>>4)*8+j.
// R6 ERRATA: which==6 path had OOB idx (i0+rep*16384 up to 49151 >= 32768),
// corrupting xbf via race -> absmax 5.875. 128 blocks x 256 thr = 32768
// = count exactly; one element per thread, same path as other matrices.
// ---------------------------------------------------------------------------
#define PACK_BLOCKS 896          // 7 matrices x 128 blocks
#define ZERO_BLOCKS 98           // 25001 int4 = deg+cnt+cursor exactly
#define CVT_BLOCKS  3125         // 50000*128/8/256
__global__ void prep(const float* __restrict__ x, unsigned short* __restrict__ xbf,
                     const float* __restrict__ Wp1, const float* __restrict__ Wl1,
                     const float* __restrict__ Wr1, const float* __restrict__ Wp2,
                     const float* __restrict__ Wl2, const float* __restrict__ Wr2,
                     const float* __restrict__ Wlin, unsigned short* __restrict__ wpack,
                     int* __restrict__ zbase) {
    int b = blockIdx.x;
    if (b < PACK_BLOCKS) {
        int which = b >> 7;
        const float* W;
        int count, base;
        switch (which) {
            case 0: W = Wp1; count = 16384; base = 0; break;
            case 1: W = Wl1; count = 16384; base = 32768; break;
            case 2: W = Wr1; count = 16384; base = 65536; break;
            case 3: W = Wp2; count = 16384; base = 98304; break;
            case 4: W = Wl2; count = 16384; base = 131072; break;
            case 5: W = Wr2; count = 16384; base = 163840; break;
            default: W = Wlin; count = 32768; base = 196608; break;
        }
        int idx = (b & 127) * 256 + threadIdx.x;
        if (idx >= count) return;
        int j = idx & 7;
        int lane = (idx >> 3) & 63;
        int ks = (idx >> 9) & 3;
        int nt = idx >> 11;
        int c = nt * 16 + (lane & 15);
        int k = ks * 32 + (lane >> 4) * 8 + j;
        float v = W[c * 128 + k];
        unsigned short hi = f2bf(v);
        unsigned short lo = f2bf(v - bf2f(hi));
        wpack[base + idx] = hi;
        wpack[base + count + idx] = lo;
    } else if (b < PACK_BLOCKS + ZERO_BLOCKS) {
        int i = (b - PACK_BLOCKS) * 256 + threadIdx.x;
        if (i < 25001) ((int4*)zbase)[i] = make_int4(0, 0, 0, 0);
    } else {
        int tid = (b - PACK_BLOCKS - ZERO_BLOCKS) * 256 + threadIdx.x;
        size_t i8 = (size_t)tid * 8;
        if (i8 >= (size_t)N_NODES * HID) return;
        float4 v0 = *(const float4*)(x + i8);
        float4 v1 = *(const float4*)(x + i8 + 4);
        short8 o;
        o[0] = f2bf(v0.x); o[1] = f2bf(v0.y); o[2] = f2bf(v0.z); o[3] = f2bf(v0.w);
        o[4] = f2bf(v1.x); o[5] = f2bf(v1.y); o[6] = f2bf(v1.z); o[7] = f2bf(v1.w);
        *(short8*)(xbf + i8) = o;
    }
}

// ---------------------------------------------------------------------------
// MFMA linear with optional fused second GEMM stage.
// Stage 1: h = act1(bias1 + in1@W1 (+ in2@W2))  [2-term bf16 split per matrix]
//          -> optionally stored bf16 to out1; kept in wave-private LDS (hA).
// Stage 2 (FUSE2): out2 = act2(bias3 + h@W3), A-frags re-read from hA with
//          XOR swizzle (byte ^= (row&7)<<4) -> conflict-free-ish transpose.
// 128 thr = 2 waves; wave owns 32 rows (2 row-frags share B loads);
// B loads software-pipelined 1 step; epilogues coalesced via LDS bounce.
// ---------------------------------------------------------------------------
template <int NT1, bool DUAL, int ACT1, bool STORE1, bool FUSE2, int NT2, int ACT2, bool OBF2>
__global__ __launch_bounds__(128) void mfma_linear(
        const unsigned short* __restrict__ in1, const unsigned short* __restrict__ in2,
        const unsigned short* __restrict__ B1, const unsigned short* __restrict__ B2,
        const float* __restrict__ bias1, void* __restrict__ out1,
        const unsigned short* __restrict__ B3, const float* __restrict__ bias3,
        void* __restrict__ out2) {
    constexpr int LO1 = NT1 * 2048;
    constexpr int LO2 = NT2 * 2048;
    __shared__ alignas(16) float tile[2][2][16][20];
    __shared__ alignas(16) unsigned short hA[FUSE2 ? 2 : 1][32][128];

    const int t = threadIdx.x;
    const int w = t >> 6;
    const int l = t & 63;
    const int waveRow = blockIdx.x * 64 + w * 32;

    int r0 = waveRow + (l & 15);
    int r1 = r0 + 16;
    if (r0 > N_NODES - 1) r0 = N_NODES - 1;
    if (r1 > N_NODES - 1) r1 = N_NODES - 1;
    const int ko = (l >> 4) * 8;

    short8 a1[2][4], a2[2][4];
#pragma unroll
    for (int ks = 0; ks < 4; ++ks) {
        a1[0][ks] = *(const short8*)(in1 + (size_t)r0 * HID + ks * 32 + ko);
        a1[1][ks] = *(const short8*)(in1 + (size_t)r1 * HID + ks * 32 + ko);
        if (DUAL) {
            a2[0][ks] = *(const short8*)(in2 + (size_t)r0 * HID + ks * 32 + ko);
            a2[1][ks] = *(const short8*)(in2 + (size_t)r1 * HID + ks * 32 + ko);
        }
    }

    const int cL = l & 15;
    const int rfrag = (l >> 4) * 4;
    const int rr = l >> 2;
    const int c4 = (l & 3) * 4;

    short8 bh[2], bl[2], b2h[2], b2l[2];
    {
        const unsigned short* bp = B1 + (size_t)l * 8;
        bh[0] = *(const short8*)bp;
        bl[0] = *(const short8*)(bp + LO1);
        if (DUAL) {
            const unsigned short* bp2 = B2 + (size_t)l * 8;
            b2h[0] = *(const short8*)bp2;
            b2l[0] = *(const short8*)(bp2 + LO1);
        }
    }

#pragma unroll
    for (int nt = 0; nt < NT1; ++nt) {
        f32x4 acc0 = {0.f, 0.f, 0.f, 0.f};
        f32x4 acc1 = {0.f, 0.f, 0.f, 0.f};
#pragma unroll
        for (int ks = 0; ks < 4; ++ks) {
            const int idx = nt * 4 + ks;
            const int cur = idx & 1;
            const int nxt = cur ^ 1;
            if (idx + 1 < NT1 * 4) {
                const unsigned short* bp = B1 + ((size_t)(idx + 1) * 64 + l) * 8;
                bh[nxt] = *(const short8*)bp;
                bl[nxt] = *(const short8*)(bp + LO1);
                if (DUAL) {
                    const unsigned short* bp2 = B2 + ((size_t)(idx + 1) * 64 + l) * 8;
                    b2h[nxt] = *(const short8*)bp2;
                    b2l[nxt] = *(const short8*)(bp2 + LO1);
                }
            }
            acc0 = __builtin_amdgcn_mfma_f32_16x16x32_bf16(a1[0][ks], bh[cur], acc0, 0, 0, 0);
            acc1 = __builtin_amdgcn_mfma_f32_16x16x32_bf16(a1[1][ks], bh[cur], acc1, 0, 0, 0);
            acc0 = __builtin_amdgcn_mfma_f32_16x16x32_bf16(a1[0][ks], bl[cur], acc0, 0, 0, 0);
            acc1 = __builtin_amdgcn_mfma_f32_16x16x32_bf16(a1[1][ks], bl[cur], acc1, 0, 0, 0);
            if (DUAL) {
                acc0 = __builtin_amdgcn_mfma_f32_16x16x32_bf16(a2[0][ks], b2h[cur], acc0, 0, 0, 0);
                acc1 = __builtin_amdgcn_mfma_f32_16x16x32_bf16(a2[1][ks], b2h[cur], acc1, 0, 0, 0);
                acc0 = __builtin_amdgcn_mfma_f32_16x16x32_bf16(a2[0][ks], b2l[cur], acc0, 0, 0, 0);
                acc1 = __builtin_amdgcn_mfma_f32_16x16x32_bf16(a2[1][ks], b2l[cur], acc1, 0, 0, 0);
            }
        }

        float bc = bias1[nt * 16 + cL];
#pragma unroll
        for (int reg = 0; reg < 4; ++reg) {
            float v0 = acc0[reg] + bc;
            float v1 = acc1[reg] + bc;
            if (ACT1 == 1) { v0 = gelu_fast(v0); v1 = gelu_fast(v1); }
            if (STORE1) {
                tile[w][0][rfrag + reg][cL] = v0;
                tile[w][1][rfrag + reg][cL] = v1;
            }
            if (FUSE2) {
                int rl = rfrag + reg;
                int cs = (nt * 16 + cL) ^ ((rl & 7) << 3);  // ushort-index swizzle
                hA[w][rl][cs] = f2bf(v0);
                hA[w][rl + 16][cs] = f2bf(v1);
            }
        }
        if (STORE1) {
            asm volatile("s_waitcnt lgkmcnt(0)" ::: "memory");
#pragma unroll
            for (int f = 0; f < 2; ++f) {
                float4 vv = *(const float4*)&tile[w][f][rr][c4];
                int row = waveRow + f * 16 + rr;
                if (row < N_NODES) {
                    short4_t o;
                    o[0] = f2bf(vv.x); o[1] = f2bf(vv.y);
                    o[2] = f2bf(vv.z); o[3] = f2bf(vv.w);
                    *(short4_t*)((unsigned short*)out1 + (size_t)row * (NT1 * 16) + nt * 16 + c4) = o;
                }
            }
            asm volatile("s_waitcnt lgkmcnt(0)" ::: "memory");
        }
    }

    // ---------------- fused second GEMM: out2 = act2(hA @ W3 + bias3) -------
    if (FUSE2) {
        asm volatile("s_waitcnt lgkmcnt(0)" ::: "memory");  // hA writes visible (wave-private)
        short8 c1[2][4];
        const int rA = l & 15;
#pragma unroll
        for (int ks = 0; ks < 4; ++ks) {
            int kk = ks * 32 + ko;
            int cs = kk ^ ((rA & 7) << 3);
            c1[0][ks] = *(const short8*)&hA[w][rA][cs];
            c1[1][ks] = *(const short8*)&hA[w][rA + 16][cs];
        }
        {
            const unsigned short* bp = B3 + (size_t)l * 8;
            bh[0] = *(const short8*)bp;
            bl[0] = *(const short8*)(bp + LO2);
        }
#pragma unroll
        for (int nt = 0; nt < NT2; ++nt) {
            f32x4 acc0 = {0.f, 0.f, 0.f, 0.f};
            f32x4 acc1 = {0.f, 0.f, 0.f, 0.f};
#pragma unroll
            for (int ks = 0; ks < 4; ++ks) {
                const int idx = nt * 4 + ks;
                const int cur = idx & 1;
                const int nxt = cur ^ 1;
                if (idx + 1 < NT2 * 4) {
                    const unsigned short* bp = B3 + ((size_t)(idx + 1) * 64 + l) * 8;
                    bh[nxt] = *(const short8*)bp;
                    bl[nxt] = *(const short8*)(bp + LO2);
                }
                acc0 = __builtin_amdgcn_mfma_f32_16x16x32_bf16(c1[0][ks], bh[cur], acc0, 0, 0, 0);
                acc1 = __builtin_amdgcn_mfma_f32_16x16x32_bf16(c1[1][ks], bh[cur], acc1, 0, 0, 0);
                acc0 = __builtin_amdgcn_mfma_f32_16x16x32_bf16(c1[0][ks], bl[cur], acc0, 0, 0, 0);
                acc1 = __builtin_amdgcn_mfma_f32_16x16x32_bf16(c1[1][ks], bl[cur], acc1, 0, 0, 0);
            }
            float bc = bias3[nt * 16 + cL];
#pragma unroll
            for (int reg = 0; reg < 4; ++reg) {
                float v0 = acc0[reg] + bc;
                float v1 = acc1[reg] + bc;
                if (ACT2 == 1) { v0 = gelu_fast(v0); v1 = gelu_fast(v1); }
                tile[w][0][rfrag + reg][cL] = v0;
                tile[w][1][rfrag + reg][cL] = v1;
            }
            asm volatile("s_waitcnt lgkmcnt(0)" ::: "memory");
#pragma unroll
            for (int f = 0; f < 2; ++f) {
                float4 vv = *(const float4*)&tile[w][f][rr][c4];
                int row = waveRow + f * 16 + rr;
                if (row < N_NODES) {
                    if (OBF2) {
                        short4_t o;
                        o[0] = f2bf(vv.x); o[1] = f2bf(vv.y);
                        o[2] = f2bf(vv.z); o[3] = f2bf(vv.w);
                        *(short4_t*)((unsigned short*)out2 + (size_t)row * (NT2 * 16) + nt * 16 + c4) = o;
                    } else {
                        *(float4*)((float*)out2 + (size_t)row * (NT2 * 16) + nt * 16 + c4) = vv;
                    }
                }
            }
            asm volatile("s_waitcnt lgkmcnt(0)" ::: "memory");
        }
    }
}

// ---------------------------------------------------------------------------
// CSR build.  count_deg fused with edge-index echo (both read ei once).
// ---------------------------------------------------------------------------
__global__ void count_deg_echo(const int* __restrict__ ei, int* __restrict__ deg,
                               float* __restrict__ echo) {
    int e = blockIdx.x * 256 + threadIdx.x;
    if (e < 2 * N_EDGES) {
        int v = ei[e];
        echo[e] = (float)v;
        if (e >= N_EDGES) atomicAdd(&deg[v], 1);
    }
}

// One-kernel exclusive scan via atomic cursor. Block bases nondeterministic,
// but per-node segment SETS are identical and max is order-invariant.
__global__ void build_off(const int* __restrict__ deg, int* __restrict__ off,
                          int* __restrict__ cursor) {
    __shared__ int sm[256];
    __shared__ int base;
    int t = threadIdx.x;
    int i = blockIdx.x * 256 + t;
    int v = (i < N_NODES) ? deg[i] : 0;
    sm[t] = v;
    __syncthreads();
    for (int s = 1; s < 256; s <<= 1) {
        int tv = (t >= s) ? sm[t - s] : 0;
        __syncthreads();
        sm[t] += tv;
        __syncthreads();
    }
    if (t == 255) base = atomicAdd(cursor, sm[255]);
    __syncthreads();
    if (i < N_NODES) off[i] = base + sm[t] - v;
}

__global__ void fill_csr(const int* __restrict__ ei, const int* __restrict__ off,
                         int* __restrict__ cnt, int* __restrict__ csr) {
    int e = blockIdx.x * 256 + threadIdx.x;
    if (e < N_EDGES) {
        int dst = ei[N_EDGES + e];
        int p = atomicAdd(&cnt[dst], 1);
        csr[off[dst] + p] = ei[e];
    }
}

// ---------------------------------------------------------------------------
// Gather segment max over bf16 rows: one wave per node, ushort2 per lane.
// acc=0 init realizes relu(max(.)) + isolated-node-zero. Output bf16 exact.
// ---------------------------------------------------------------------------
__global__ __launch_bounds__(256) void seg_max_bf(const unsigned short* __restrict__ y,
                                                  const int* __restrict__ csr,
                                                  const int* __restrict__ off,
                                                  const int* __restrict__ deg,
                                                  unsigned short* __restrict__ agg) {
    int n = blockIdx.x * 4 + (threadIdx.x >> 6);
    int lane = threadIdx.x & 63;
    int s = off[n];
    int d = deg[n];
    const unsigned short* yb = y + lane * 2;
    float a0 = 0.f, a1 = 0.f;
    int i = 0;
    for (; i + 4 <= d; i += 4) {
        int s0 = csr[s + i], s1 = csr[s + i + 1], s2 = csr[s + i + 2], s3 = csr[s + i + 3];
        unsigned v0 = *(const unsigned*)(yb + (size_t)s0 * HID);
        unsigned v1 = *(const unsigned*)(yb + (size_t)s1 * HID);
        unsigned v2 = *(const unsigned*)(yb + (size_t)s2 * HID);
        unsigned v3 = *(const unsigned*)(yb + (size_t)s3 * HID);
        a0 = fmaxf(a0, fmaxf(fmaxf(__uint_as_float(v0 << 16), __uint_as_float(v1 << 16)),
                             fmaxf(__uint_as_float(v2 << 16), __uint_as_float(v3 << 16))));
        a1 = fmaxf(a1, fmaxf(fmaxf(__uint_as_float(v0 & 0xffff0000u), __uint_as_float(v1 & 0xffff0000u)),
                             fmaxf(__uint_as_float(v2 & 0xffff0000u), __uint_as_float(v3 & 0xffff0000u))));
    }
    for (; i < d; ++i) {
        int s0 = csr[s + i];
        unsigned v0 = *(const unsigned*)(yb + (size_t)s0 * HID);
        a0 = fmaxf(a0, __uint_as_float(v0 << 16));
        a1 = fmaxf(a1, __uint_as_float(v0 & 0xffff0000u));
    }
    unsigned o = (unsigned)f2bf(a0) | ((unsigned)f2bf(a1) << 16);
    *(unsigned*)(agg + (size_t)n * HID + lane * 2) = o;
}

extern "C" void kernel_launch(void* const* d_in, const int* in_sizes, int n_in,
                              void* d_out, int out_size, void* d_ws, size_t ws_size,
                              hipStream_t stream) {
    const float* x    = (const float*)d_in[0];
    const int*   ei   = (const int*)d_in[1];
    const float* Wp1  = (const float*)d_in[2];
    const float* bp1  = (const float*)d_in[3];
    const float* Wl1  = (const float*)d_in[4];
    const float* bl1  = (const float*)d_in[5];
    const float* Wr1  = (const float*)d_in[6];
    const float* Wp2  = (const float*)d_in[7];
    const float* bp2  = (const float*)d_in[8];
    const float* Wl2  = (const float*)d_in[9];
    const float* bl2  = (const float*)d_in[10];
    const float* Wr2  = (const float*)d_in[11];
    const float* Wlin = (const float*)d_in[12];
    const float* blin = (const float*)d_in[13];
    float* out = (float*)d_out;

    // ws layout (ushort units for bf16 region)
    unsigned short* wpack = (unsigned short*)d_ws;            // 262144
    unsigned short* xbf   = wpack + 262144;
    unsigned short* ybf   = xbf + (size_t)N_NODES * HID;
    unsigned short* aggbf = ybf + (size_t)N_NODES * HID;
    unsigned short* h1bf  = aggbf + (size_t)N_NODES * HID;
    int* deg    = (int*)(h1bf + (size_t)N_NODES * HID);
    int* cnt    = deg + N_NODES;
    int* cursor = cnt + N_NODES;   // 4 ints, zeroed with deg/cnt (25001 int4)
    int* off    = cursor + 4;
    int* csr    = off + N_NODES;

    const unsigned short* Bp1 = wpack + 0;
    const unsigned short* Bl1 = wpack + 32768;
    const unsigned short* Br1 = wpack + 65536;
    const unsigned short* Bp2 = wpack + 98304;
    const unsigned short* Bl2 = wpack + 131072;
    const unsigned short* Br2 = wpack + 163840;
    const unsigned short* Blin = wpack + 196608;

    const int RB  = (N_NODES + 63) / 64;      // 782 blocks of 128 thr
    const int NPB = (N_NODES + 255) / 256;

    // prep: pack weights + zero deg/cnt/cursor + convert x (one launch)
    hipLaunchKernelGGL(prep, dim3(PACK_BLOCKS + ZERO_BLOCKS + CVT_BLOCKS), dim3(256), 0, stream,
                       x, xbf, Wp1, Wl1, Wr1, Wp2, Wl2, Wr2, Wlin, wpack, deg);

    // CSR build (+ edge echo fused)
    hipLaunchKernelGGL(count_deg_echo, dim3((2 * N_EDGES + 255) / 256), dim3(256), 0, stream,
                       ei, deg, out + (size_t)N_NODES * 256);
    hipLaunchKernelGGL(build_off, dim3(NPB), dim3(256), 0, stream, deg, off, cursor);
    hipLaunchKernelGGL(fill_csr, dim3((N_EDGES + 255) / 256), dim3(256), 0, stream,
                       ei, off, cnt, csr);

    // ---------------- layer 1: y1 = xbf @ Wp1 + bp1 ----------------
    hipLaunchKernelGGL((mfma_linear<8, false, 0, true, false, 8, 0, true>),
                       dim3(RB), dim3(128), 0, stream,
                       xbf, xbf, Bp1, Bp1, bp1, ybf, Bp1, bp1, ybf);
    hipLaunchKernelGGL(seg_max_bf, dim3(N_NODES / 4), dim3(256), 0, stream,
                       ybf, csr, off, deg, aggbf);

    // fused: h1 = gelu(agg@Wl1 + x@Wr1 + bl1) [store]; y2 = h1@Wp2 + bp2
    hipLaunchKernelGGL((mfma_linear<8, true, 1, true, true, 8, 0, true>),
                       dim3(RB), dim3(128), 0, stream,
                       aggbf, xbf, Bl1, Br1, bl1, h1bf, Bp2, bp2, ybf);

    // ---------------- layer 2 ----------------
    hipLaunchKernelGGL(seg_max_bf, dim3(N_NODES / 4), dim3(256), 0, stream,
                       ybf, csr, off, deg, aggbf);

    // fused: h2 = gelu(agg@Wl2 + h1@Wr2 + bl2) [no store]; out = gelu(h2@Wlin + blin) f32
    hipLaunchKernelGGL((mfma_linear<8, true, 1, false, true, 16, 1, false>),
                       dim3(RB), dim3(128), 0, stream,
                       aggbf, h1bf, Bl2, Br2, bl2, nullptr, Blin, blin, out);
}

// Round 8
// 222.617 us; speedup vs baseline: 8.2997x; 1.0489x over previous
//
#include <hip/hip_runtime.h>

#define N_NODES 50000
#define N_EDGES 600000
#define HID 128

typedef __attribute__((ext_vector_type(8))) short short8;
typedef __attribute__((ext_vector_type(4))) short short4_t;
typedef __attribute__((ext_vector_type(4))) float f32x4;

__device__ __forceinline__ unsigned short f2bf(float f) {
    unsigned u = __float_as_uint(f);
    unsigned r = u + 0x7FFFu + ((u >> 16) & 1u);  // RNE
    return (unsigned short)(r >> 16);
}
__device__ __forceinline__ float bf2f(unsigned short h) {
    return __uint_as_float(((unsigned)h) << 16);
}

// gelu(tanh approx) == x / (1 + exp(-2u)), u = 0.79788456*(x + 0.044715 x^3)
__device__ __forceinline__ float gelu_fast(float x) {
    float u = 0.7978845608028654f * (x + 0.044715f * x * x * x);
    return x / (1.0f + __expf(-2.0f * u));
}

// ---------------------------------------------------------------------------
// prep: weight pack (blocks 0..895) + zero deg/cnt/cursor (next 98 blocks)
//       + x f32->bf16 convert (rest).
// Pack layout (verified R3-R7): n = nt*16+(lane&15), k = ks*32+(lane>>4)*8+j.
// (R6 ERRATA: a 2-elem/thread Wlin path was OOB; one elem/thread is exact.)
// ---------------------------------------------------------------------------
#define PACK_BLOCKS 896          // 7 matrices x 128 blocks
#define ZERO_BLOCKS 98           // 25001 int4 = deg+cnt+cursor exactly
#define CVT_BLOCKS  3125         // 50000*128/8/256
__global__ void prep(const float* __restrict__ x, unsigned short* __restrict__ xbf,
                     const float* __restrict__ Wp1, const float* __restrict__ Wl1,
                     const float* __restrict__ Wr1, const float* __restrict__ Wp2,
                     const float* __restrict__ Wl2, const float* __restrict__ Wr2,
                     const float* __restrict__ Wlin, unsigned short* __restrict__ wpack,
                     int* __restrict__ zbase) {
    int b = blockIdx.x;
    if (b < PACK_BLOCKS) {
        int which = b >> 7;
        const float* W;
        int count, base;
        switch (which) {
            case 0: W = Wp1; count = 16384; base = 0; break;
            case 1: W = Wl1; count = 16384; base = 32768; break;
            case 2: W = Wr1; count = 16384; base = 65536; break;
            case 3: W = Wp2; count = 16384; base = 98304; break;
            case 4: W = Wl2; count = 16384; base = 131072; break;
            case 5: W = Wr2; count = 16384; base = 163840; break;
            default: W = Wlin; count = 32768; base = 196608; break;
        }
        int idx = (b & 127) * 256 + threadIdx.x;
        if (idx >= count) return;
        int j = idx & 7;
        int lane = (idx >> 3) & 63;
        int ks = (idx >> 9) & 3;
        int nt = idx >> 11;
        int c = nt * 16 + (lane & 15);
        int k = ks * 32 + (lane >> 4) * 8 + j;
        float v = W[c * 128 + k];
        unsigned short hi = f2bf(v);
        unsigned short lo = f2bf(v - bf2f(hi));
        wpack[base + idx] = hi;
        wpack[base + count + idx] = lo;
    } else if (b < PACK_BLOCKS + ZERO_BLOCKS) {
        int i = (b - PACK_BLOCKS) * 256 + threadIdx.x;
        if (i < 25001) ((int4*)zbase)[i] = make_int4(0, 0, 0, 0);
    } else {
        int tid = (b - PACK_BLOCKS - ZERO_BLOCKS) * 256 + threadIdx.x;
        size_t i8 = (size_t)tid * 8;
        if (i8 >= (size_t)N_NODES * HID) return;
        float4 v0 = *(const float4*)(x + i8);
        float4 v1 = *(const float4*)(x + i8 + 4);
        short8 o;
        o[0] = f2bf(v0.x); o[1] = f2bf(v0.y); o[2] = f2bf(v0.z); o[3] = f2bf(v0.w);
        o[4] = f2bf(v1.x); o[5] = f2bf(v1.y); o[6] = f2bf(v1.z); o[7] = f2bf(v1.w);
        *(short8*)(xbf + i8) = o;
    }
}

// ---------------------------------------------------------------------------
// MFMA linear, column-split across 4 waves (R8 restructure).
// Block = 256 thr = 4 waves over 32 rows; wave w owns output tiles
// nt in [w*NT/4, (w+1)*NT/4) of each stage -> grid doubles (1563 blocks),
// per-block B traffic = ONE full B sweep (shared by col-split), occupancy
// 2-3x the R7 structure (which was 1.5 waves/SIMD, Occupancy=13%).
// Stage 1: h = act1(bias1 + in1@W1 (+ in2@W2)); optional bf16 store (out1);
//          if FUSE2, h also goes to block-shared swizzled hA[32][128].
// __syncthreads, then Stage 2: out2 = act2(bias3 + h@W3), A from hA.
// Swizzle: ushort col index ^= (row&7)<<3 (write and read agree).
// ---------------------------------------------------------------------------
template <int NT1, bool DUAL, int ACT1, bool STORE1, bool FUSE2, int NT2, int ACT2, bool OBF2>
__global__ __launch_bounds__(256, 2) void mfma_linear(
        const unsigned short* __restrict__ in1, const unsigned short* __restrict__ in2,
        const unsigned short* __restrict__ B1, const unsigned short* __restrict__ B2,
        const float* __restrict__ bias1, void* __restrict__ out1,
        const unsigned short* __restrict__ B3, const float* __restrict__ bias3,
        void* __restrict__ out2) {
    constexpr int LO1 = NT1 * 2048;  // ushorts in hi region of B1/B2
    constexpr int LO2 = NT2 * 2048;
    constexpr int MY1 = NT1 / 4;     // stage-1 tiles per wave
    constexpr int MY2 = NT2 / 4;     // stage-2 tiles per wave
    __shared__ alignas(16) float tile[4][2][16][20];
    __shared__ alignas(16) unsigned short hA[FUSE2 ? 32 : 1][128];

    const int t = threadIdx.x;
    const int w = t >> 6;
    const int l = t & 63;
    const int blockRow = blockIdx.x * 32;

    int r0 = blockRow + (l & 15);
    int r1 = r0 + 16;
    if (r0 > N_NODES - 1) r0 = N_NODES - 1;
    if (r1 > N_NODES - 1) r1 = N_NODES - 1;
    const int ko = (l >> 4) * 8;  // ushort offset of this lane's 8 bf16 in a 32-k step

    short8 a1[2][4], a2[2][4];
#pragma unroll
    for (int ks = 0; ks < 4; ++ks) {
        a1[0][ks] = *(const short8*)(in1 + (size_t)r0 * HID + ks * 32 + ko);
        a1[1][ks] = *(const short8*)(in1 + (size_t)r1 * HID + ks * 32 + ko);
        if (DUAL) {
            a2[0][ks] = *(const short8*)(in2 + (size_t)r0 * HID + ks * 32 + ko);
            a2[1][ks] = *(const short8*)(in2 + (size_t)r1 * HID + ks * 32 + ko);
        }
    }

    const int cL = l & 15;
    const int rfrag = (l >> 4) * 4;
    const int rr = l >> 2;
    const int c4 = (l & 3) * 4;
    const int ntBase1 = w * MY1;

    // B double-buffer (statically indexed under full unroll)
    short8 bh[2], bl[2], b2h[2], b2l[2];
    {
        const unsigned short* bp = B1 + ((size_t)(ntBase1 * 4) * 64 + l) * 8;
        bh[0] = *(const short8*)bp;
        bl[0] = *(const short8*)(bp + LO1);
        if (DUAL) {
            const unsigned short* bp2 = B2 + ((size_t)(ntBase1 * 4) * 64 + l) * 8;
            b2h[0] = *(const short8*)bp2;
            b2l[0] = *(const short8*)(bp2 + LO1);
        }
    }

#pragma unroll
    for (int m = 0; m < MY1; ++m) {
        const int nt = ntBase1 + m;
        f32x4 acc0 = {0.f, 0.f, 0.f, 0.f};
        f32x4 acc1 = {0.f, 0.f, 0.f, 0.f};
#pragma unroll
        for (int ks = 0; ks < 4; ++ks) {
            const int step = m * 4 + ks;
            const int cur = step & 1;
            const int nxt = cur ^ 1;
            if (step + 1 < MY1 * 4) {
                const size_t g = (size_t)(ntBase1 * 4 + step + 1) * 64 + l;
                const unsigned short* bp = B1 + g * 8;
                bh[nxt] = *(const short8*)bp;
                bl[nxt] = *(const short8*)(bp + LO1);
                if (DUAL) {
                    const unsigned short* bp2 = B2 + g * 8;
                    b2h[nxt] = *(const short8*)bp2;
                    b2l[nxt] = *(const short8*)(bp2 + LO1);
                }
            }
            acc0 = __builtin_amdgcn_mfma_f32_16x16x32_bf16(a1[0][ks], bh[cur], acc0, 0, 0, 0);
            acc1 = __builtin_amdgcn_mfma_f32_16x16x32_bf16(a1[1][ks], bh[cur], acc1, 0, 0, 0);
            acc0 = __builtin_amdgcn_mfma_f32_16x16x32_bf16(a1[0][ks], bl[cur], acc0, 0, 0, 0);
            acc1 = __builtin_amdgcn_mfma_f32_16x16x32_bf16(a1[1][ks], bl[cur], acc1, 0, 0, 0);
            if (DUAL) {
                acc0 = __builtin_amdgcn_mfma_f32_16x16x32_bf16(a2[0][ks], b2h[cur], acc0, 0, 0, 0);
                acc1 = __builtin_amdgcn_mfma_f32_16x16x32_bf16(a2[1][ks], b2h[cur], acc1, 0, 0, 0);
                acc0 = __builtin_amdgcn_mfma_f32_16x16x32_bf16(a2[0][ks], b2l[cur], acc0, 0, 0, 0);
                acc1 = __builtin_amdgcn_mfma_f32_16x16x32_bf16(a2[1][ks], b2l[cur], acc1, 0, 0, 0);
            }
        }

        float bc = bias1[nt * 16 + cL];
#pragma unroll
        for (int reg = 0; reg < 4; ++reg) {
            float v0 = acc0[reg] + bc;
            float v1 = acc1[reg] + bc;
            if (ACT1 == 1) { v0 = gelu_fast(v0); v1 = gelu_fast(v1); }
            if (FUSE2) {
                int rl = rfrag + reg;
                int cs = (nt * 16 + cL) ^ ((rl & 7) << 3);  // same XOR for rl and rl+16
                hA[rl][cs] = f2bf(v0);
                hA[rl + 16][cs] = f2bf(v1);
            }
            if (STORE1) {
                tile[w][0][rfrag + reg][cL] = v0;
                tile[w][1][rfrag + reg][cL] = v1;
            }
        }
        if (STORE1) {
            asm volatile("s_waitcnt lgkmcnt(0)" ::: "memory");
#pragma unroll
            for (int f = 0; f < 2; ++f) {
                float4 vv = *(const float4*)&tile[w][f][rr][c4];
                int row = blockRow + f * 16 + rr;
                if (row < N_NODES) {
                    short4_t o;
                    o[0] = f2bf(vv.x); o[1] = f2bf(vv.y);
                    o[2] = f2bf(vv.z); o[3] = f2bf(vv.w);
                    *(short4_t*)((unsigned short*)out1 + (size_t)row * (NT1 * 16) + nt * 16 + c4) = o;
                }
            }
            asm volatile("s_waitcnt lgkmcnt(0)" ::: "memory");
        }
    }

    // ---------------- fused second GEMM: out2 = act2(hA @ W3 + bias3) -------
    if (FUSE2) {
        __syncthreads();  // hA written by all 4 waves
        short8 c1[2][4];
        const int rA = l & 15;
#pragma unroll
        for (int ks = 0; ks < 4; ++ks) {
            int b0 = (ks * 32 + ko) ^ ((rA & 7) << 3);
            c1[0][ks] = *(const short8*)&hA[rA][b0];
            c1[1][ks] = *(const short8*)&hA[rA + 16][b0];  // (rA+16)&7 == rA&7
        }
        const int ntBase2 = w * MY2;
        {
            const unsigned short* bp = B3 + ((size_t)(ntBase2 * 4) * 64 + l) * 8;
            bh[0] = *(const short8*)bp;
            bl[0] = *(const short8*)(bp + LO2);
        }
#pragma unroll
        for (int m = 0; m < MY2; ++m) {
            const int nt = ntBase2 + m;
            f32x4 acc0 = {0.f, 0.f, 0.f, 0.f};
            f32x4 acc1 = {0.f, 0.f, 0.f, 0.f};
#pragma unroll
            for (int ks = 0; ks < 4; ++ks) {
                const int step = m * 4 + ks;
                const int cur = step & 1;
                const int nxt = cur ^ 1;
                if (step + 1 < MY2 * 4) {
                    const unsigned short* bp = B3 + ((size_t)(ntBase2 * 4 + step + 1) * 64 + l) * 8;
                    bh[nxt] = *(const short8*)bp;
                    bl[nxt] = *(const short8*)(bp + LO2);
                }
                acc0 = __builtin_amdgcn_mfma_f32_16x16x32_bf16(c1[0][ks], bh[cur], acc0, 0, 0, 0);
                acc1 = __builtin_amdgcn_mfma_f32_16x16x32_bf16(c1[1][ks], bh[cur], acc1, 0, 0, 0);
                acc0 = __builtin_amdgcn_mfma_f32_16x16x32_bf16(c1[0][ks], bl[cur], acc0, 0, 0, 0);
                acc1 = __builtin_amdgcn_mfma_f32_16x16x32_bf16(c1[1][ks], bl[cur], acc1, 0, 0, 0);
            }
            float bc = bias3[nt * 16 + cL];
#pragma unroll
            for (int reg = 0; reg < 4; ++reg) {
                float v0 = acc0[reg] + bc;
                float v1 = acc1[reg] + bc;
                if (ACT2 == 1) { v0 = gelu_fast(v0); v1 = gelu_fast(v1); }
                tile[w][0][rfrag + reg][cL] = v0;
                tile[w][1][rfrag + reg][cL] = v1;
            }
            asm volatile("s_waitcnt lgkmcnt(0)" ::: "memory");
#pragma unroll
            for (int f = 0; f < 2; ++f) {
                float4 vv = *(const float4*)&tile[w][f][rr][c4];
                int row = blockRow + f * 16 + rr;
                if (row < N_NODES) {
                    if (OBF2) {
                        short4_t o;
                        o[0] = f2bf(vv.x); o[1] = f2bf(vv.y);
                        o[2] = f2bf(vv.z); o[3] = f2bf(vv.w);
                        *(short4_t*)((unsigned short*)out2 + (size_t)row * (NT2 * 16) + nt * 16 + c4) = o;
                    } else {
                        *(float4*)((float*)out2 + (size_t)row * (NT2 * 16) + nt * 16 + c4) = vv;
                    }
                }
            }
            asm volatile("s_waitcnt lgkmcnt(0)" ::: "memory");
        }
    }
}

// ---------------------------------------------------------------------------
// CSR build.  count_deg fused with edge-index echo (both read ei once).
// ---------------------------------------------------------------------------
__global__ void count_deg_echo(const int* __restrict__ ei, int* __restrict__ deg,
                               float* __restrict__ echo) {
    int e = blockIdx.x * 256 + threadIdx.x;
    if (e < 2 * N_EDGES) {
        int v = ei[e];
        echo[e] = (float)v;
        if (e >= N_EDGES) atomicAdd(&deg[v], 1);
    }
}

// One-kernel exclusive scan via atomic cursor. Block bases nondeterministic,
// but per-node segment SETS are identical and max is order-invariant.
__global__ void build_off(const int* __restrict__ deg, int* __restrict__ off,
                          int* __restrict__ cursor) {
    __shared__ int sm[256];
    __shared__ int base;
    int t = threadIdx.x;
    int i = blockIdx.x * 256 + t;
    int v = (i < N_NODES) ? deg[i] : 0;
    sm[t] = v;
    __syncthreads();
    for (int s = 1; s < 256; s <<= 1) {
        int tv = (t >= s) ? sm[t - s] : 0;
        __syncthreads();
        sm[t] += tv;
        __syncthreads();
    }
    if (t == 255) base = atomicAdd(cursor, sm[255]);
    __syncthreads();
    if (i < N_NODES) off[i] = base + sm[t] - v;
}

__global__ void fill_csr(const int* __restrict__ ei, const int* __restrict__ off,
                         int* __restrict__ cnt, int* __restrict__ csr) {
    int e = blockIdx.x * 256 + threadIdx.x;
    if (e < N_EDGES) {
        int dst = ei[N_EDGES + e];
        int p = atomicAdd(&cnt[dst], 1);
        csr[off[dst] + p] = ei[e];
    }
}

// ---------------------------------------------------------------------------
// Gather segment max over bf16 rows: one wave per node, ushort2 per lane.
// acc=0 init realizes relu(max(.)) + isolated-node-zero. Output bf16 exact.
// ---------------------------------------------------------------------------
__global__ __launch_bounds__(256) void seg_max_bf(const unsigned short* __restrict__ y,
                                                  const int* __restrict__ csr,
                                                  const int* __restrict__ off,
                                                  const int* __restrict__ deg,
                                                  unsigned short* __restrict__ agg) {
    int n = blockIdx.x * 4 + (threadIdx.x >> 6);
    int lane = threadIdx.x & 63;
    int s = off[n];
    int d = deg[n];
    const unsigned short* yb = y + lane * 2;
    float a0 = 0.f, a1 = 0.f;
    int i = 0;
    for (; i + 4 <= d; i += 4) {
        int s0 = csr[s + i], s1 = csr[s + i + 1], s2 = csr[s + i + 2], s3 = csr[s + i + 3];
        unsigned v0 = *(const unsigned*)(yb + (size_t)s0 * HID);
        unsigned v1 = *(const unsigned*)(yb + (size_t)s1 * HID);
        unsigned v2 = *(const unsigned*)(yb + (size_t)s2 * HID);
        unsigned v3 = *(const unsigned*)(yb + (size_t)s3 * HID);
        a0 = fmaxf(a0, fmaxf(fmaxf(__uint_as_float(v0 << 16), __uint_as_float(v1 << 16)),
                             fmaxf(__uint_as_float(v2 << 16), __uint_as_float(v3 << 16))));
        a1 = fmaxf(a1, fmaxf(fmaxf(__uint_as_float(v0 & 0xffff0000u), __uint_as_float(v1 & 0xffff0000u)),
                             fmaxf(__uint_as_float(v2 & 0xffff0000u), __uint_as_float(v3 & 0xffff0000u))));
    }
    for (; i < d; ++i) {
        int s0 = csr[s + i];
        unsigned v0 = *(const unsigned*)(yb + (size_t)s0 * HID);
        a0 = fmaxf(a0, __uint_as_float(v0 << 16));
        a1 = fmaxf(a1, __uint_as_float(v0 & 0xffff0000u));
    }
    unsigned o = (unsigned)f2bf(a0) | ((unsigned)f2bf(a1) << 16);
    *(unsigned*)(agg + (size_t)n * HID + lane * 2) = o;
}

extern "C" void kernel_launch(void* const* d_in, const int* in_sizes, int n_in,
                              void* d_out, int out_size, void* d_ws, size_t ws_size,
                              hipStream_t stream) {
    const float* x    = (const float*)d_in[0];
    const int*   ei   = (const int*)d_in[1];
    const float* Wp1  = (const float*)d_in[2];
    const float* bp1  = (const float*)d_in[3];
    const float* Wl1  = (const float*)d_in[4];
    const float* bl1  = (const float*)d_in[5];
    const float* Wr1  = (const float*)d_in[6];
    const float* Wp2  = (const float*)d_in[7];
    const float* bp2  = (const float*)d_in[8];
    const float* Wl2  = (const float*)d_in[9];
    const float* bl2  = (const float*)d_in[10];
    const float* Wr2  = (const float*)d_in[11];
    const float* Wlin = (const float*)d_in[12];
    const float* blin = (const float*)d_in[13];
    float* out = (float*)d_out;

    // ws layout (ushort units for bf16 region)
    unsigned short* wpack = (unsigned short*)d_ws;            // 262144
    unsigned short* xbf   = wpack + 262144;
    unsigned short* ybf   = xbf + (size_t)N_NODES * HID;
    unsigned short* aggbf = ybf + (size_t)N_NODES * HID;
    unsigned short* h1bf  = aggbf + (size_t)N_NODES * HID;
    int* deg    = (int*)(h1bf + (size_t)N_NODES * HID);
    int* cnt    = deg + N_NODES;
    int* cursor = cnt + N_NODES;   // 4 ints, zeroed with deg/cnt (25001 int4)
    int* off    = cursor + 4;
    int* csr    = off + N_NODES;

    const unsigned short* Bp1 = wpack + 0;
    const unsigned short* Bl1 = wpack + 32768;
    const unsigned short* Br1 = wpack + 65536;
    const unsigned short* Bp2 = wpack + 98304;
    const unsigned short* Bl2 = wpack + 131072;
    const unsigned short* Br2 = wpack + 163840;
    const unsigned short* Blin = wpack + 196608;

    const int RB32 = (N_NODES + 31) / 32;     // 1563 blocks of 256 thr (32 rows)
    const int NPB  = (N_NODES + 255) / 256;

    // prep: pack weights + zero deg/cnt/cursor + convert x (one launch)
    hipLaunchKernelGGL(prep, dim3(PACK_BLOCKS + ZERO_BLOCKS + CVT_BLOCKS), dim3(256), 0, stream,
                       x, xbf, Wp1, Wl1, Wr1, Wp2, Wl2, Wr2, Wlin, wpack, deg);

    // CSR build (+ edge echo fused)
    hipLaunchKernelGGL(count_deg_echo, dim3((2 * N_EDGES + 255) / 256), dim3(256), 0, stream,
                       ei, deg, out + (size_t)N_NODES * 256);
    hipLaunchKernelGGL(build_off, dim3(NPB), dim3(256), 0, stream, deg, off, cursor);
    hipLaunchKernelGGL(fill_csr, dim3((N_EDGES + 255) / 256), dim3(256), 0, stream,
                       ei, off, cnt, csr);

    // ---------------- layer 1: y1 = xbf @ Wp1 + bp1 ----------------
    hipLaunchKernelGGL((mfma_linear<8, false, 0, true, false, 8, 0, true>),
                       dim3(RB32), dim3(256), 0, stream,
                       xbf, nullptr, Bp1, nullptr, bp1, ybf, nullptr, nullptr, nullptr);
    hipLaunchKernelGGL(seg_max_bf, dim3(N_NODES / 4), dim3(256), 0, stream,
                       ybf, csr, off, deg, aggbf);

    // fused: h1 = gelu(agg@Wl1 + x@Wr1 + bl1) [store]; y2 = h1@Wp2 + bp2
    hipLaunchKernelGGL((mfma_linear<8, true, 1, true, true, 8, 0, true>),
                       dim3(RB32), dim3(256), 0, stream,
                       aggbf, xbf, Bl1, Br1, bl1, h1bf, Bp2, bp2, ybf);

    // ---------------- layer 2 ----------------
    hipLaunchKernelGGL(seg_max_bf, dim3(N_NODES / 4), dim3(256), 0, stream,
                       ybf, csr, off, deg, aggbf);

    // fused: h2 = gelu(agg@Wl2 + h1@Wr2 + bl2) [no store]; out = gelu(h2@Wlin + blin) f32
    hipLaunchKernelGGL((mfma_linear<8, true, 1, false, true, 16, 1, false>),
                       dim3(RB32), dim3(256), 0, stream,
                       aggbf, h1bf, Bl2, Br2, bl2, nullptr, Blin, blin, out);
}

// Round 9
// 217.540 us; speedup vs baseline: 8.4935x; 1.0233x over previous
//
#include <hip/hip_runtime.h>

#define N_NODES 50000
#define N_EDGES 600000
#define HID 128

typedef __attribute__((ext_vector_type(8))) short short8;
typedef __attribute__((ext_vector_type(4))) short short4_t;
typedef __attribute__((ext_vector_type(4))) float f32x4;

__device__ __forceinline__ unsigned short f2bf(float f) {
    unsigned u = __float_as_uint(f);
    unsigned r = u + 0x7FFFu + ((u >> 16) & 1u);  // RNE
    return (unsigned short)(r >> 16);
}
__device__ __forceinline__ float bf2f(unsigned short h) {
    return __uint_as_float(((unsigned)h) << 16);
}

// gelu(tanh approx) == x / (1 + exp(-2u)), u = 0.79788456*(x + 0.044715 x^3)
__device__ __forceinline__ float gelu_fast(float x) {
    float u = 0.7978845608028654f * (x + 0.044715f * x * x * x);
    return x / (1.0f + __expf(-2.0f * u));
}

// ---------------------------------------------------------------------------
// prep: weight pack (blocks 0..895) + zero deg/cnt/cursor + x f32->bf16.
// Pack layout (verified R3-R8): n = nt*16+(lane&15), k = ks*32+(lane>>4)*8+j.
// ---------------------------------------------------------------------------
#define PACK_BLOCKS 896
#define ZERO_BLOCKS 98
#define CVT_BLOCKS  3125
__global__ void prep(const float* __restrict__ x, unsigned short* __restrict__ xbf,
                     const float* __restrict__ Wp1, const float* __restrict__ Wl1,
                     const float* __restrict__ Wr1, const float* __restrict__ Wp2,
                     const float* __restrict__ Wl2, const float* __restrict__ Wr2,
                     const float* __restrict__ Wlin, unsigned short* __restrict__ wpack,
                     int* __restrict__ zbase) {
    int b = blockIdx.x;
    if (b < PACK_BLOCKS) {
        int which = b >> 7;
        const float* W;
        int count, base;
        switch (which) {
            case 0: W = Wp1; count = 16384; base = 0; break;
            case 1: W = Wl1; count = 16384; base = 32768; break;
            case 2: W = Wr1; count = 16384; base = 65536; break;
            case 3: W = Wp2; count = 16384; base = 98304; break;
            case 4: W = Wl2; count = 16384; base = 131072; break;
            case 5: W = Wr2; count = 16384; base = 163840; break;
            default: W = Wlin; count = 32768; base = 196608; break;
        }
        int idx = (b & 127) * 256 + threadIdx.x;
        if (idx >= count) return;
        int j = idx & 7;
        int lane = (idx >> 3) & 63;
        int ks = (idx >> 9) & 3;
        int nt = idx >> 11;
        int c = nt * 16 + (lane & 15);
        int k = ks * 32 + (lane >> 4) * 8 + j;
        float v = W[c * 128 + k];
        unsigned short hi = f2bf(v);
        unsigned short lo = f2bf(v - bf2f(hi));
        wpack[base + idx] = hi;
        wpack[base + count + idx] = lo;
    } else if (b < PACK_BLOCKS + ZERO_BLOCKS) {
        int i = (b - PACK_BLOCKS) * 256 + threadIdx.x;
        if (i < 25001) ((int4*)zbase)[i] = make_int4(0, 0, 0, 0);
    } else {
        int tid = (b - PACK_BLOCKS - ZERO_BLOCKS) * 256 + threadIdx.x;
        size_t i8 = (size_t)tid * 8;
        if (i8 >= (size_t)N_NODES * HID) return;
        float4 v0 = *(const float4*)(x + i8);
        float4 v1 = *(const float4*)(x + i8 + 4);
        short8 o;
        o[0] = f2bf(v0.x); o[1] = f2bf(v0.y); o[2] = f2bf(v0.z); o[3] = f2bf(v0.w);
        o[4] = f2bf(v1.x); o[5] = f2bf(v1.y); o[6] = f2bf(v1.z); o[7] = f2bf(v1.w);
        *(short8*)(xbf + i8) = o;
    }
}

// ---------------------------------------------------------------------------
// MFMA linear, column-split across 4 waves (R9: batched epilogue).
// Block = 256 thr = 4 waves over 32 rows; wave w owns NT/4 output tiles.
// Stage 1: h = act1(bias1 + in1@W1 (+ in2@W2)) -> bf16 into swizzled
//   hA[32][128] (cs = c ^ ((row&7)<<3)); ONE __syncthreads; if STORE1,
//   2-pass coalesced store (16B/thread, 256B-contiguous rows) from hA.
// Stage 2 (FUSE2): A-frags from hA. bf16 out (OBF2): same pattern via hB.
//   f32 out (final, 256 cols): two column-halves through padded fT[32][132]
//   -> 512B-contiguous f32 stores (full cache lines for the 51 MB write).
// R8 lesson: per-nt LDS bounce with 2x lgkmcnt(0) per tile + 32B strided
// stores caused 2.3x write amplification and VALU-serial epilogue.
// ---------------------------------------------------------------------------
template <int NT1, bool DUAL, int ACT1, bool STORE1, bool FUSE2, int NT2, int ACT2, bool OBF2>
__global__ __launch_bounds__(256, 2) void mfma_linear(
        const unsigned short* __restrict__ in1, const unsigned short* __restrict__ in2,
        const unsigned short* __restrict__ B1, const unsigned short* __restrict__ B2,
        const float* __restrict__ bias1, void* __restrict__ out1,
        const unsigned short* __restrict__ B3, const float* __restrict__ bias3,
        void* __restrict__ out2) {
    constexpr int LO1 = NT1 * 2048;
    constexpr int LO2 = NT2 * 2048;
    constexpr int MY1 = NT1 / 4;
    __shared__ alignas(16) unsigned short hA[32][128];
    __shared__ alignas(16) unsigned short hB[(FUSE2 && OBF2) ? 32 : 1][128];
    __shared__ alignas(16) float fT[(FUSE2 && !OBF2) ? 32 : 1][132];

    const int t = threadIdx.x;
    const int w = t >> 6;
    const int l = t & 63;
    const int blockRow = blockIdx.x * 32;

    int r0 = blockRow + (l & 15);
    int r1 = r0 + 16;
    if (r0 > N_NODES - 1) r0 = N_NODES - 1;
    if (r1 > N_NODES - 1) r1 = N_NODES - 1;
    const int ko = (l >> 4) * 8;

    short8 a1[2][4], a2[2][4];
#pragma unroll
    for (int ks = 0; ks < 4; ++ks) {
        a1[0][ks] = *(const short8*)(in1 + (size_t)r0 * HID + ks * 32 + ko);
        a1[1][ks] = *(const short8*)(in1 + (size_t)r1 * HID + ks * 32 + ko);
        if (DUAL) {
            a2[0][ks] = *(const short8*)(in2 + (size_t)r0 * HID + ks * 32 + ko);
            a2[1][ks] = *(const short8*)(in2 + (size_t)r1 * HID + ks * 32 + ko);
        }
    }

    const int cL = l & 15;
    const int rfrag = (l >> 4) * 4;

    short8 bh[2], bl[2], b2h[2], b2l[2];
    {
        const unsigned short* bp = B1 + ((size_t)(w * MY1 * 4) * 64 + l) * 8;
        bh[0] = *(const short8*)bp;
        bl[0] = *(const short8*)(bp + LO1);
        if (DUAL) {
            const unsigned short* bp2 = B2 + ((size_t)(w * MY1 * 4) * 64 + l) * 8;
            b2h[0] = *(const short8*)bp2;
            b2l[0] = *(const short8*)(bp2 + LO1);
        }
    }

#pragma unroll
    for (int m = 0; m < MY1; ++m) {
        const int nt = w * MY1 + m;
        f32x4 acc0 = {0.f, 0.f, 0.f, 0.f};
        f32x4 acc1 = {0.f, 0.f, 0.f, 0.f};
#pragma unroll
        for (int ks = 0; ks < 4; ++ks) {
            const int step = m * 4 + ks;
            const int cur = step & 1;
            const int nxt = cur ^ 1;
            if (step + 1 < MY1 * 4) {
                const size_t g = (size_t)(w * MY1 * 4 + step + 1) * 64 + l;
                const unsigned short* bp = B1 + g * 8;
                bh[nxt] = *(const short8*)bp;
                bl[nxt] = *(const short8*)(bp + LO1);
                if (DUAL) {
                    const unsigned short* bp2 = B2 + g * 8;
                    b2h[nxt] = *(const short8*)bp2;
                    b2l[nxt] = *(const short8*)(bp2 + LO1);
                }
            }
            acc0 = __builtin_amdgcn_mfma_f32_16x16x32_bf16(a1[0][ks], bh[cur], acc0, 0, 0, 0);
            acc1 = __builtin_amdgcn_mfma_f32_16x16x32_bf16(a1[1][ks], bh[cur], acc1, 0, 0, 0);
            acc0 = __builtin_amdgcn_mfma_f32_16x16x32_bf16(a1[0][ks], bl[cur], acc0, 0, 0, 0);
            acc1 = __builtin_amdgcn_mfma_f32_16x16x32_bf16(a1[1][ks], bl[cur], acc1, 0, 0, 0);
            if (DUAL) {
                acc0 = __builtin_amdgcn_mfma_f32_16x16x32_bf16(a2[0][ks], b2h[cur], acc0, 0, 0, 0);
                acc1 = __builtin_amdgcn_mfma_f32_16x16x32_bf16(a2[1][ks], b2h[cur], acc1, 0, 0, 0);
                acc0 = __builtin_amdgcn_mfma_f32_16x16x32_bf16(a2[0][ks], b2l[cur], acc0, 0, 0, 0);
                acc1 = __builtin_amdgcn_mfma_f32_16x16x32_bf16(a2[1][ks], b2l[cur], acc1, 0, 0, 0);
            }
        }
        float bc = bias1[nt * 16 + cL];
#pragma unroll
        for (int reg = 0; reg < 4; ++reg) {
            float v0 = acc0[reg] + bc;
            float v1 = acc1[reg] + bc;
            if (ACT1 == 1) { v0 = gelu_fast(v0); v1 = gelu_fast(v1); }
            int rl = rfrag + reg;
            int cs = (nt * 16 + cL) ^ ((rl & 7) << 3);
            hA[rl][cs] = f2bf(v0);
            hA[rl + 16][cs] = f2bf(v1);
        }
    }
    __syncthreads();

    if (STORE1) {
#pragma unroll
        for (int p = 0; p < 2; ++p) {
            int idx = p * 256 + t;
            int row = idx >> 4;
            int c0 = (idx & 15) * 8;
            int cs0 = c0 ^ ((row & 7) << 3);
            short8 v = *(const short8*)&hA[row][cs0];
            int grow = blockRow + row;
            if (grow < N_NODES)
                *(short8*)((unsigned short*)out1 + (size_t)grow * (NT1 * 16) + c0) = v;
        }
    }

    // ---------------- fused second GEMM: out2 = act2(hA @ W3 + bias3) -------
    if (FUSE2) {
        short8 c1[2][4];
        const int rA = l & 15;
#pragma unroll
        for (int ks = 0; ks < 4; ++ks) {
            int b0 = (ks * 32 + ko) ^ ((rA & 7) << 3);
            c1[0][ks] = *(const short8*)&hA[rA][b0];
            c1[1][ks] = *(const short8*)&hA[rA + 16][b0];
        }
        if (OBF2) {
            // ---- bf16 output path (NT2 cols = 128), via hB ----
            constexpr int MY2 = NT2 / 4;
            {
                const unsigned short* bp = B3 + ((size_t)(w * MY2 * 4) * 64 + l) * 8;
                bh[0] = *(const short8*)bp;
                bl[0] = *(const short8*)(bp + LO2);
            }
#pragma unroll
            for (int m = 0; m < MY2; ++m) {
                const int nt = w * MY2 + m;
                f32x4 acc0 = {0.f, 0.f, 0.f, 0.f};
                f32x4 acc1 = {0.f, 0.f, 0.f, 0.f};
#pragma unroll
                for (int ks = 0; ks < 4; ++ks) {
                    const int step = m * 4 + ks;
                    const int cur = step & 1;
                    const int nxt = cur ^ 1;
                    if (step + 1 < MY2 * 4) {
                        const unsigned short* bp = B3 + ((size_t)(w * MY2 * 4 + step + 1) * 64 + l) * 8;
                        bh[nxt] = *(const short8*)bp;
                        bl[nxt] = *(const short8*)(bp + LO2);
                    }
                    acc0 = __builtin_amdgcn_mfma_f32_16x16x32_bf16(c1[0][ks], bh[cur], acc0, 0, 0, 0);
                    acc1 = __builtin_amdgcn_mfma_f32_16x16x32_bf16(c1[1][ks], bh[cur], acc1, 0, 0, 0);
                    acc0 = __builtin_amdgcn_mfma_f32_16x16x32_bf16(c1[0][ks], bl[cur], acc0, 0, 0, 0);
                    acc1 = __builtin_amdgcn_mfma_f32_16x16x32_bf16(c1[1][ks], bl[cur], acc1, 0, 0, 0);
                }
                float bc = bias3[nt * 16 + cL];
#pragma unroll
                for (int reg = 0; reg < 4; ++reg) {
                    float v0 = acc0[reg] + bc;
                    float v1 = acc1[reg] + bc;
                    if (ACT2 == 1) { v0 = gelu_fast(v0); v1 = gelu_fast(v1); }
                    int rl = rfrag + reg;
                    int cs = (nt * 16 + cL) ^ ((rl & 7) << 3);
                    hB[rl][cs] = f2bf(v0);
                    hB[rl + 16][cs] = f2bf(v1);
                }
            }
            __syncthreads();
#pragma unroll
            for (int p = 0; p < 2; ++p) {
                int idx = p * 256 + t;
                int row = idx >> 4;
                int c0 = (idx & 15) * 8;
                int cs0 = c0 ^ ((row & 7) << 3);
                short8 v = *(const short8*)&hB[row][cs0];
                int grow = blockRow + row;
                if (grow < N_NODES)
                    *(short8*)((unsigned short*)out2 + (size_t)grow * (NT2 * 16) + c0) = v;
            }
        } else {
            // ---- f32 output path (NT2=16, 256 cols) in two column-halves ----
#pragma unroll
            for (int h = 0; h < 2; ++h) {
                const int ntb = h * 8 + w * 2;  // this wave's first nt in half h
                {
                    const unsigned short* bp = B3 + ((size_t)(ntb * 4) * 64 + l) * 8;
                    bh[0] = *(const short8*)bp;
                    bl[0] = *(const short8*)(bp + LO2);
                }
#pragma unroll
                for (int m = 0; m < 2; ++m) {
                    const int nt = ntb + m;
                    f32x4 acc0 = {0.f, 0.f, 0.f, 0.f};
                    f32x4 acc1 = {0.f, 0.f, 0.f, 0.f};
#pragma unroll
                    for (int ks = 0; ks < 4; ++ks) {
                        const int step = m * 4 + ks;
                        const int cur = step & 1;
                        const int nxt = cur ^ 1;
                        if (step + 1 < 8) {
                            const unsigned short* bp = B3 + ((size_t)(ntb * 4 + step + 1) * 64 + l) * 8;
                            bh[nxt] = *(const short8*)bp;
                            bl[nxt] = *(const short8*)(bp + LO2);
                        }
                        acc0 = __builtin_amdgcn_mfma_f32_16x16x32_bf16(c1[0][ks], bh[cur], acc0, 0, 0, 0);
                        acc1 = __builtin_amdgcn_mfma_f32_16x16x32_bf16(c1[1][ks], bh[cur], acc1, 0, 0, 0);
                        acc0 = __builtin_amdgcn_mfma_f32_16x16x32_bf16(c1[0][ks], bl[cur], acc0, 0, 0, 0);
                        acc1 = __builtin_amdgcn_mfma_f32_16x16x32_bf16(c1[1][ks], bl[cur], acc1, 0, 0, 0);
                    }
                    float bc = bias3[nt * 16 + cL];
                    int ct = (nt - h * 8) * 16 + cL;  // col within half-tile
#pragma unroll
                    for (int reg = 0; reg < 4; ++reg) {
                        float v0 = acc0[reg] + bc;
                        float v1 = acc1[reg] + bc;
                        if (ACT2 == 1) { v0 = gelu_fast(v0); v1 = gelu_fast(v1); }
                        fT[rfrag + reg][ct] = v0;
                        fT[rfrag + reg + 16][ct] = v1;
                    }
                }
                __syncthreads();
#pragma unroll
                for (int p = 0; p < 4; ++p) {
                    int idx = p * 256 + t;
                    int row = idx >> 5;
                    int s4 = (idx & 31) * 4;
                    float4 v = *(const float4*)&fT[row][s4];
                    int grow = blockRow + row;
                    if (grow < N_NODES)
                        *(float4*)((float*)out2 + (size_t)grow * 256 + h * 128 + s4) = v;
                }
                __syncthreads();
            }
        }
    }
}

// ---------------------------------------------------------------------------
// CSR build.  count_deg fused with edge-index echo.
// ---------------------------------------------------------------------------
__global__ void count_deg_echo(const int* __restrict__ ei, int* __restrict__ deg,
                               float* __restrict__ echo) {
    int e = blockIdx.x * 256 + threadIdx.x;
    if (e < 2 * N_EDGES) {
        int v = ei[e];
        echo[e] = (float)v;
        if (e >= N_EDGES) atomicAdd(&deg[v], 1);
    }
}

// One-kernel exclusive scan via atomic cursor (order-invariant downstream).
__global__ void build_off(const int* __restrict__ deg, int* __restrict__ off,
                          int* __restrict__ cursor) {
    __shared__ int sm[256];
    __shared__ int base;
    int t = threadIdx.x;
    int i = blockIdx.x * 256 + t;
    int v = (i < N_NODES) ? deg[i] : 0;
    sm[t] = v;
    __syncthreads();
    for (int s = 1; s < 256; s <<= 1) {
        int tv = (t >= s) ? sm[t - s] : 0;
        __syncthreads();
        sm[t] += tv;
        __syncthreads();
    }
    if (t == 255) base = atomicAdd(cursor, sm[255]);
    __syncthreads();
    if (i < N_NODES) off[i] = base + sm[t] - v;
}

__global__ void fill_csr(const int* __restrict__ ei, const int* __restrict__ off,
                         int* __restrict__ cnt, int* __restrict__ csr) {
    int e = blockIdx.x * 256 + threadIdx.x;
    if (e < N_EDGES) {
        int dst = ei[N_EDGES + e];
        int p = atomicAdd(&cnt[dst], 1);
        csr[off[dst] + p] = ei[e];
    }
}

// ---------------------------------------------------------------------------
// Gather segment max over bf16 rows: one wave per node, ushort2 per lane.
// ---------------------------------------------------------------------------
__global__ __launch_bounds__(256) void seg_max_bf(const unsigned short* __restrict__ y,
                                                  const int* __restrict__ csr,
                                                  const int* __restrict__ off,
                                                  const int* __restrict__ deg,
                                                  unsigned short* __restrict__ agg) {
    int n = blockIdx.x * 4 + (threadIdx.x >> 6);
    int lane = threadIdx.x & 63;
    int s = off[n];
    int d = deg[n];
    const unsigned short* yb = y + lane * 2;
    float a0 = 0.f, a1 = 0.f;
    int i = 0;
    for (; i + 4 <= d; i += 4) {
        int s0 = csr[s + i], s1 = csr[s + i + 1], s2 = csr[s + i + 2], s3 = csr[s + i + 3];
        unsigned v0 = *(const unsigned*)(yb + (size_t)s0 * HID);
        unsigned v1 = *(const unsigned*)(yb + (size_t)s1 * HID);
        unsigned v2 = *(const unsigned*)(yb + (size_t)s2 * HID);
        unsigned v3 = *(const unsigned*)(yb + (size_t)s3 * HID);
        a0 = fmaxf(a0, fmaxf(fmaxf(__uint_as_float(v0 << 16), __uint_as_float(v1 << 16)),
                             fmaxf(__uint_as_float(v2 << 16), __uint_as_float(v3 << 16))));
        a1 = fmaxf(a1, fmaxf(fmaxf(__uint_as_float(v0 & 0xffff0000u), __uint_as_float(v1 & 0xffff0000u)),
                             fmaxf(__uint_as_float(v2 & 0xffff0000u), __uint_as_float(v3 & 0xffff0000u))));
    }
    for (; i < d; ++i) {
        int s0 = csr[s + i];
        unsigned v0 = *(const unsigned*)(yb + (size_t)s0 * HID);
        a0 = fmaxf(a0, __uint_as_float(v0 << 16));
        a1 = fmaxf(a1, __uint_as_float(v0 & 0xffff0000u));
    }
    unsigned o = (unsigned)f2bf(a0) | ((unsigned)f2bf(a1) << 16);
    *(unsigned*)(agg + (size_t)n * HID + lane * 2) = o;
}

extern "C" void kernel_launch(void* const* d_in, const int* in_sizes, int n_in,
                              void* d_out, int out_size, void* d_ws, size_t ws_size,
                              hipStream_t stream) {
    const float* x    = (const float*)d_in[0];
    const int*   ei   = (const int*)d_in[1];
    const float* Wp1  = (const float*)d_in[2];
    const float* bp1  = (const float*)d_in[3];
    const float* Wl1  = (const float*)d_in[4];
    const float* bl1  = (const float*)d_in[5];
    const float* Wr1  = (const float*)d_in[6];
    const float* Wp2  = (const float*)d_in[7];
    const float* bp2  = (const float*)d_in[8];
    const float* Wl2  = (const float*)d_in[9];
    const float* bl2  = (const float*)d_in[10];
    const float* Wr2  = (const float*)d_in[11];
    const float* Wlin = (const float*)d_in[12];
    const float* blin = (const float*)d_in[13];
    float* out = (float*)d_out;

    unsigned short* wpack = (unsigned short*)d_ws;
    unsigned short* xbf   = wpack + 262144;
    unsigned short* ybf   = xbf + (size_t)N_NODES * HID;
    unsigned short* aggbf = ybf + (size_t)N_NODES * HID;
    unsigned short* h1bf  = aggbf + (size_t)N_NODES * HID;
    int* deg    = (int*)(h1bf + (size_t)N_NODES * HID);
    int* cnt    = deg + N_NODES;
    int* cursor = cnt + N_NODES;
    int* off    = cursor + 4;
    int* csr    = off + N_NODES;

    const unsigned short* Bp1 = wpack + 0;
    const unsigned short* Bl1 = wpack + 32768;
    const unsigned short* Br1 = wpack + 65536;
    const unsigned short* Bp2 = wpack + 98304;
    const unsigned short* Bl2 = wpack + 131072;
    const unsigned short* Br2 = wpack + 163840;
    const unsigned short* Blin = wpack + 196608;

    const int RB32 = (N_NODES + 31) / 32;
    const int NPB  = (N_NODES + 255) / 256;

    hipLaunchKernelGGL(prep, dim3(PACK_BLOCKS + ZERO_BLOCKS + CVT_BLOCKS), dim3(256), 0, stream,
                       x, xbf, Wp1, Wl1, Wr1, Wp2, Wl2, Wr2, Wlin, wpack, deg);

    hipLaunchKernelGGL(count_deg_echo, dim3((2 * N_EDGES + 255) / 256), dim3(256), 0, stream,
                       ei, deg, out + (size_t)N_NODES * 256);
    hipLaunchKernelGGL(build_off, dim3(NPB), dim3(256), 0, stream, deg, off, cursor);
    hipLaunchKernelGGL(fill_csr, dim3((N_EDGES + 255) / 256), dim3(256), 0, stream,
                       ei, off, cnt, csr);

    // layer 1: y1 = xbf @ Wp1 + bp1
    hipLaunchKernelGGL((mfma_linear<8, false, 0, true, false, 8, 0, true>),
                       dim3(RB32), dim3(256), 0, stream,
                       xbf, nullptr, Bp1, nullptr, bp1, ybf, nullptr, nullptr, nullptr);
    hipLaunchKernelGGL(seg_max_bf, dim3(N_NODES / 4), dim3(256), 0, stream,
                       ybf, csr, off, deg, aggbf);

    // fused: h1 = gelu(agg@Wl1 + x@Wr1 + bl1) [store]; y2 = h1@Wp2 + bp2
    hipLaunchKernelGGL((mfma_linear<8, true, 1, true, true, 8, 0, true>),
                       dim3(RB32), dim3(256), 0, stream,
                       aggbf, xbf, Bl1, Br1, bl1, h1bf, Bp2, bp2, ybf);

    // layer 2
    hipLaunchKernelGGL(seg_max_bf, dim3(N_NODES / 4), dim3(256), 0, stream,
                       ybf, csr, off, deg, aggbf);

    // fused: h2 = gelu(agg@Wl2 + h1@Wr2 + bl2); out = gelu(h2@Wlin + blin) f32
    hipLaunchKernelGGL((mfma_linear<8, true, 1, false, true, 16, 1, false>),
                       dim3(RB32), dim3(256), 0, stream,
                       aggbf, h1bf, Bl2, Br2, bl2, nullptr, Blin, blin, out);
}

// Round 10
// 203.570 us; speedup vs baseline: 9.0763x; 1.0686x over previous
//
#include <hip/hip_runtime.h>

#define N_NODES 50000
#define N_EDGES 600000
#define HID 128

typedef __attribute__((ext_vector_type(8))) short short8;
typedef __attribute__((ext_vector_type(4))) float f32x4;

__device__ __forceinline__ unsigned short f2bf(float f) {
    unsigned u = __float_as_uint(f);
    unsigned r = u + 0x7FFFu + ((u >> 16) & 1u);  // RNE
    return (unsigned short)(r >> 16);
}
__device__ __forceinline__ float bf2f(unsigned short h) {
    return __uint_as_float(((unsigned)h) << 16);
}

// gelu(tanh approx) == x / (1 + exp(-2u)), u = 0.79788456*(x + 0.044715 x^3)
__device__ __forceinline__ float gelu_fast(float x) {
    float u = 0.7978845608028654f * (x + 0.044715f * x * x * x);
    return x / (1.0f + __expf(-2.0f * u));
}

// ---------------------------------------------------------------------------
// prep: weight pack (hi-only bf16, R10) + zero deg/cnt/cursor + x f32->bf16.
// Pack layout (verified R3-R9): n = nt*16+(lane&15), k = ks*32+(lane>>4)*8+j.
// R10: dropped the lo region (2-term split -> 1-term). Error analysis: bf16
// half-ulp 2^-9 rel on W -> per-GEMM 5-sigma output err ~6e-3, total ~+0.03.
// ---------------------------------------------------------------------------
#define PACK_BLOCKS 512          // 6 x 64 + 128 (Wlin)
#define ZERO_BLOCKS 98           // 25001 int4 = deg+cnt+cursor
#define CVT_BLOCKS  3125         // 50000*128/8/256
__global__ void prep(const float* __restrict__ x, unsigned short* __restrict__ xbf,
                     const float* __restrict__ Wp1, const float* __restrict__ Wl1,
                     const float* __restrict__ Wr1, const float* __restrict__ Wp2,
                     const float* __restrict__ Wl2, const float* __restrict__ Wr2,
                     const float* __restrict__ Wlin, unsigned short* __restrict__ wpack,
                     int* __restrict__ zbase) {
    int b = blockIdx.x;
    if (b < PACK_BLOCKS) {
        const float* W;
        int base, idx;
        if (b < 384) {
            int which = b >> 6;
            switch (which) {
                case 0: W = Wp1; break;
                case 1: W = Wl1; break;
                case 2: W = Wr1; break;
                case 3: W = Wp2; break;
                case 4: W = Wl2; break;
                default: W = Wr2; break;
            }
            base = which * 16384;
            idx = (b & 63) * 256 + threadIdx.x;
        } else {
            W = Wlin;
            base = 98304;
            idx = (b - 384) * 256 + threadIdx.x;
        }
        int j = idx & 7;
        int lane = (idx >> 3) & 63;
        int ks = (idx >> 9) & 3;
        int nt = idx >> 11;
        int c = nt * 16 + (lane & 15);
        int k = ks * 32 + (lane >> 4) * 8 + j;
        wpack[base + idx] = f2bf(W[c * 128 + k]);
    } else if (b < PACK_BLOCKS + ZERO_BLOCKS) {
        int i = (b - PACK_BLOCKS) * 256 + threadIdx.x;
        if (i < 25001) ((int4*)zbase)[i] = make_int4(0, 0, 0, 0);
    } else {
        int tid = (b - PACK_BLOCKS - ZERO_BLOCKS) * 256 + threadIdx.x;
        size_t i8 = (size_t)tid * 8;
        if (i8 >= (size_t)N_NODES * HID) return;
        float4 v0 = *(const float4*)(x + i8);
        float4 v1 = *(const float4*)(x + i8 + 4);
        short8 o;
        o[0] = f2bf(v0.x); o[1] = f2bf(v0.y); o[2] = f2bf(v0.z); o[3] = f2bf(v0.w);
        o[4] = f2bf(v1.x); o[5] = f2bf(v1.y); o[6] = f2bf(v1.z); o[7] = f2bf(v1.w);
        *(short8*)(xbf + i8) = o;
    }
}

// ---------------------------------------------------------------------------
// MFMA linear, column-split across 4 waves, 1-term bf16 (R10).
// Block = 256 thr = 4 waves over 32 rows; wave w owns NT/4 output tiles.
// Stage 1: h = act1(bias1 + in1@W1 (+ in2@W2)) -> bf16 into swizzled
//   hA[32][128]; ONE __syncthreads; if STORE1, coalesced 2-pass store.
// Stage 2 (FUSE2): A-frags from hA. bf16 out via hB (same pattern);
//   f32 out (final, 256 cols) via padded fT[32][132] in two column-halves.
// ---------------------------------------------------------------------------
template <int NT1, bool DUAL, int ACT1, bool STORE1, bool FUSE2, int NT2, int ACT2, bool OBF2>
__global__ __launch_bounds__(256, 2) void mfma_linear(
        const unsigned short* __restrict__ in1, const unsigned short* __restrict__ in2,
        const unsigned short* __restrict__ B1, const unsigned short* __restrict__ B2,
        const float* __restrict__ bias1, void* __restrict__ out1,
        const unsigned short* __restrict__ B3, const float* __restrict__ bias3,
        void* __restrict__ out2) {
    constexpr int MY1 = NT1 / 4;
    __shared__ alignas(16) unsigned short hA[32][128];
    __shared__ alignas(16) unsigned short hB[(FUSE2 && OBF2) ? 32 : 1][128];
    __shared__ alignas(16) float fT[(FUSE2 && !OBF2) ? 32 : 1][132];

    const int t = threadIdx.x;
    const int w = t >> 6;
    const int l = t & 63;
    const int blockRow = blockIdx.x * 32;

    int r0 = blockRow + (l & 15);
    int r1 = r0 + 16;
    if (r0 > N_NODES - 1) r0 = N_NODES - 1;
    if (r1 > N_NODES - 1) r1 = N_NODES - 1;
    const int ko = (l >> 4) * 8;

    short8 a1[2][4], a2[2][4];
#pragma unroll
    for (int ks = 0; ks < 4; ++ks) {
        a1[0][ks] = *(const short8*)(in1 + (size_t)r0 * HID + ks * 32 + ko);
        a1[1][ks] = *(const short8*)(in1 + (size_t)r1 * HID + ks * 32 + ko);
        if (DUAL) {
            a2[0][ks] = *(const short8*)(in2 + (size_t)r0 * HID + ks * 32 + ko);
            a2[1][ks] = *(const short8*)(in2 + (size_t)r1 * HID + ks * 32 + ko);
        }
    }

    const int cL = l & 15;
    const int rfrag = (l >> 4) * 4;

    short8 b1[2], b2[2];
    {
        const unsigned short* bp = B1 + ((size_t)(w * MY1 * 4) * 64 + l) * 8;
        b1[0] = *(const short8*)bp;
        if (DUAL) {
            const unsigned short* bp2 = B2 + ((size_t)(w * MY1 * 4) * 64 + l) * 8;
            b2[0] = *(const short8*)bp2;
        }
    }

#pragma unroll
    for (int m = 0; m < MY1; ++m) {
        const int nt = w * MY1 + m;
        f32x4 acc0 = {0.f, 0.f, 0.f, 0.f};
        f32x4 acc1 = {0.f, 0.f, 0.f, 0.f};
#pragma unroll
        for (int ks = 0; ks < 4; ++ks) {
            const int step = m * 4 + ks;
            const int cur = step & 1;
            const int nxt = cur ^ 1;
            if (step + 1 < MY1 * 4) {
                const size_t g = (size_t)(w * MY1 * 4 + step + 1) * 64 + l;
                b1[nxt] = *(const short8*)(B1 + g * 8);
                if (DUAL) b2[nxt] = *(const short8*)(B2 + g * 8);
            }
            acc0 = __builtin_amdgcn_mfma_f32_16x16x32_bf16(a1[0][ks], b1[cur], acc0, 0, 0, 0);
            acc1 = __builtin_amdgcn_mfma_f32_16x16x32_bf16(a1[1][ks], b1[cur], acc1, 0, 0, 0);
            if (DUAL) {
                acc0 = __builtin_amdgcn_mfma_f32_16x16x32_bf16(a2[0][ks], b2[cur], acc0, 0, 0, 0);
                acc1 = __builtin_amdgcn_mfma_f32_16x16x32_bf16(a2[1][ks], b2[cur], acc1, 0, 0, 0);
            }
        }
        float bc = bias1[nt * 16 + cL];
#pragma unroll
        for (int reg = 0; reg < 4; ++reg) {
            float v0 = acc0[reg] + bc;
            float v1 = acc1[reg] + bc;
            if (ACT1 == 1) { v0 = gelu_fast(v0); v1 = gelu_fast(v1); }
            int rl = rfrag + reg;
            int cs = (nt * 16 + cL) ^ ((rl & 7) << 3);
            hA[rl][cs] = f2bf(v0);
            hA[rl + 16][cs] = f2bf(v1);
        }
    }
    __syncthreads();

    if (STORE1) {
#pragma unroll
        for (int p = 0; p < 2; ++p) {
            int idx = p * 256 + t;
            int row = idx >> 4;
            int c0 = (idx & 15) * 8;
            int cs0 = c0 ^ ((row & 7) << 3);
            short8 v = *(const short8*)&hA[row][cs0];
            int grow = blockRow + row;
            if (grow < N_NODES)
                *(short8*)((unsigned short*)out1 + (size_t)grow * (NT1 * 16) + c0) = v;
        }
    }

    // ---------------- fused second GEMM: out2 = act2(hA @ W3 + bias3) -------
    if (FUSE2) {
        short8 c1[2][4];
        const int rA = l & 15;
#pragma unroll
        for (int ks = 0; ks < 4; ++ks) {
            int b0 = (ks * 32 + ko) ^ ((rA & 7) << 3);
            c1[0][ks] = *(const short8*)&hA[rA][b0];
            c1[1][ks] = *(const short8*)&hA[rA + 16][b0];
        }
        if (OBF2) {
            constexpr int MY2 = NT2 / 4;
            b1[0] = *(const short8*)(B3 + ((size_t)(w * MY2 * 4) * 64 + l) * 8);
#pragma unroll
            for (int m = 0; m < MY2; ++m) {
                const int nt = w * MY2 + m;
                f32x4 acc0 = {0.f, 0.f, 0.f, 0.f};
                f32x4 acc1 = {0.f, 0.f, 0.f, 0.f};
#pragma unroll
                for (int ks = 0; ks < 4; ++ks) {
                    const int step = m * 4 + ks;
                    const int cur = step & 1;
                    const int nxt = cur ^ 1;
                    if (step + 1 < MY2 * 4)
                        b1[nxt] = *(const short8*)(B3 + ((size_t)(w * MY2 * 4 + step + 1) * 64 + l) * 8);
                    acc0 = __builtin_amdgcn_mfma_f32_16x16x32_bf16(c1[0][ks], b1[cur], acc0, 0, 0, 0);
                    acc1 = __builtin_amdgcn_mfma_f32_16x16x32_bf16(c1[1][ks], b1[cur], acc1, 0, 0, 0);
                }
                float bc = bias3[nt * 16 + cL];
#pragma unroll
                for (int reg = 0; reg < 4; ++reg) {
                    float v0 = acc0[reg] + bc;
                    float v1 = acc1[reg] + bc;
                    if (ACT2 == 1) { v0 = gelu_fast(v0); v1 = gelu_fast(v1); }
                    int rl = rfrag + reg;
                    int cs = (nt * 16 + cL) ^ ((rl & 7) << 3);
                    hB[rl][cs] = f2bf(v0);
                    hB[rl + 16][cs] = f2bf(v1);
                }
            }
            __syncthreads();
#pragma unroll
            for (int p = 0; p < 2; ++p) {
                int idx = p * 256 + t;
                int row = idx >> 4;
                int c0 = (idx & 15) * 8;
                int cs0 = c0 ^ ((row & 7) << 3);
                short8 v = *(const short8*)&hB[row][cs0];
                int grow = blockRow + row;
                if (grow < N_NODES)
                    *(short8*)((unsigned short*)out2 + (size_t)grow * (NT2 * 16) + c0) = v;
            }
        } else {
            // f32 output (NT2=16, 256 cols) in two column-halves via fT
#pragma unroll
            for (int h = 0; h < 2; ++h) {
                const int ntb = h * 8 + w * 2;
                b1[0] = *(const short8*)(B3 + ((size_t)(ntb * 4) * 64 + l) * 8);
#pragma unroll
                for (int m = 0; m < 2; ++m) {
                    const int nt = ntb + m;
                    f32x4 acc0 = {0.f, 0.f, 0.f, 0.f};
                    f32x4 acc1 = {0.f, 0.f, 0.f, 0.f};
#pragma unroll
                    for (int ks = 0; ks < 4; ++ks) {
                        const int step = m * 4 + ks;
                        const int cur = step & 1;
                        const int nxt = cur ^ 1;
                        if (step + 1 < 8)
                            b1[nxt] = *(const short8*)(B3 + ((size_t)(ntb * 4 + step + 1) * 64 + l) * 8);
                        acc0 = __builtin_amdgcn_mfma_f32_16x16x32_bf16(c1[0][ks], b1[cur], acc0, 0, 0, 0);
                        acc1 = __builtin_amdgcn_mfma_f32_16x16x32_bf16(c1[1][ks], b1[cur], acc1, 0, 0, 0);
                    }
                    float bc = bias3[nt * 16 + cL];
                    int ct = (nt - h * 8) * 16 + cL;
#pragma unroll
                    for (int reg = 0; reg < 4; ++reg) {
                        float v0 = acc0[reg] + bc;
                        float v1 = acc1[reg] + bc;
                        if (ACT2 == 1) { v0 = gelu_fast(v0); v1 = gelu_fast(v1); }
                        fT[rfrag + reg][ct] = v0;
                        fT[rfrag + reg + 16][ct] = v1;
                    }
                }
                __syncthreads();
#pragma unroll
                for (int p = 0; p < 4; ++p) {
                    int idx = p * 256 + t;
                    int row = idx >> 5;
                    int s4 = (idx & 31) * 4;
                    float4 v = *(const float4*)&fT[row][s4];
                    int grow = blockRow + row;
                    if (grow < N_NODES)
                        *(float4*)((float*)out2 + (size_t)grow * 256 + h * 128 + s4) = v;
                }
                __syncthreads();
            }
        }
    }
}

// ---------------------------------------------------------------------------
// CSR build.  count_deg fused with edge-index echo.
// ---------------------------------------------------------------------------
__global__ void count_deg_echo(const int* __restrict__ ei, int* __restrict__ deg,
                               float* __restrict__ echo) {
    int e = blockIdx.x * 256 + threadIdx.x;
    if (e < 2 * N_EDGES) {
        int v = ei[e];
        echo[e] = (float)v;
        if (e >= N_EDGES) atomicAdd(&deg[v], 1);
    }
}

// One-kernel exclusive scan via atomic cursor (order-invariant downstream).
__global__ void build_off(const int* __restrict__ deg, int* __restrict__ off,
                          int* __restrict__ cursor) {
    __shared__ int sm[256];
    __shared__ int base;
    int t = threadIdx.x;
    int i = blockIdx.x * 256 + t;
    int v = (i < N_NODES) ? deg[i] : 0;
    sm[t] = v;
    __syncthreads();
    for (int s = 1; s < 256; s <<= 1) {
        int tv = (t >= s) ? sm[t - s] : 0;
        __syncthreads();
        sm[t] += tv;
        __syncthreads();
    }
    if (t == 255) base = atomicAdd(cursor, sm[255]);
    __syncthreads();
    if (i < N_NODES) off[i] = base + sm[t] - v;
}

__global__ void fill_csr(const int* __restrict__ ei, const int* __restrict__ off,
                         int* __restrict__ cnt, int* __restrict__ csr) {
    int e = blockIdx.x * 256 + threadIdx.x;
    if (e < N_EDGES) {
        int dst = ei[N_EDGES + e];
        int p = atomicAdd(&cnt[dst], 1);
        csr[off[dst] + p] = ei[e];
    }
}

// ---------------------------------------------------------------------------
// Gather segment max over bf16 rows: one wave per node, ushort2 per lane.
// ---------------------------------------------------------------------------
__global__ __launch_bounds__(256) void seg_max_bf(const unsigned short* __restrict__ y,
                                                  const int* __restrict__ csr,
                                                  const int* __restrict__ off,
                                                  const int* __restrict__ deg,
                                                  unsigned short* __restrict__ agg) {
    int n = blockIdx.x * 4 + (threadIdx.x >> 6);
    int lane = threadIdx.x & 63;
    int s = off[n];
    int d = deg[n];
    const unsigned short* yb = y + lane * 2;
    float a0 = 0.f, a1 = 0.f;
    int i = 0;
    for (; i + 4 <= d; i += 4) {
        int s0 = csr[s + i], s1 = csr[s + i + 1], s2 = csr[s + i + 2], s3 = csr[s + i + 3];
        unsigned v0 = *(const unsigned*)(yb + (size_t)s0 * HID);
        unsigned v1 = *(const unsigned*)(yb + (size_t)s1 * HID);
        unsigned v2 = *(const unsigned*)(yb + (size_t)s2 * HID);
        unsigned v3 = *(const unsigned*)(yb + (size_t)s3 * HID);
        a0 = fmaxf(a0, fmaxf(fmaxf(__uint_as_float(v0 << 16), __uint_as_float(v1 << 16)),
                             fmaxf(__uint_as_float(v2 << 16), __uint_as_float(v3 << 16))));
        a1 = fmaxf(a1, fmaxf(fmaxf(__uint_as_float(v0 & 0xffff0000u), __uint_as_float(v1 & 0xffff0000u)),
                             fmaxf(__uint_as_float(v2 & 0xffff0000u), __uint_as_float(v3 & 0xffff0000u))));
    }
    for (; i < d; ++i) {
        int s0 = csr[s + i];
        unsigned v0 = *(const unsigned*)(yb + (size_t)s0 * HID);
        a0 = fmaxf(a0, __uint_as_float(v0 << 16));
        a1 = fmaxf(a1, __uint_as_float(v0 & 0xffff0000u));
    }
    unsigned o = (unsigned)f2bf(a0) | ((unsigned)f2bf(a1) << 16);
    *(unsigned*)(agg + (size_t)n * HID + lane * 2) = o;
}

extern "C" void kernel_launch(void* const* d_in, const int* in_sizes, int n_in,
                              void* d_out, int out_size, void* d_ws, size_t ws_size,
                              hipStream_t stream) {
    const float* x    = (const float*)d_in[0];
    const int*   ei   = (const int*)d_in[1];
    const float* Wp1  = (const float*)d_in[2];
    const float* bp1  = (const float*)d_in[3];
    const float* Wl1  = (const float*)d_in[4];
    const float* bl1  = (const float*)d_in[5];
    const float* Wr1  = (const float*)d_in[6];
    const float* Wp2  = (const float*)d_in[7];
    const float* bp2  = (const float*)d_in[8];
    const float* Wl2  = (const float*)d_in[9];
    const float* bl2  = (const float*)d_in[10];
    const float* Wr2  = (const float*)d_in[11];
    const float* Wlin = (const float*)d_in[12];
    const float* blin = (const float*)d_in[13];
    float* out = (float*)d_out;

    // ws layout (ushort units for bf16 region); wpack now hi-only = 131072
    unsigned short* wpack = (unsigned short*)d_ws;
    unsigned short* xbf   = wpack + 131072;
    unsigned short* ybf   = xbf + (size_t)N_NODES * HID;
    unsigned short* aggbf = ybf + (size_t)N_NODES * HID;
    unsigned short* h1bf  = aggbf + (size_t)N_NODES * HID;
    int* deg    = (int*)(h1bf + (size_t)N_NODES * HID);
    int* cnt    = deg + N_NODES;
    int* cursor = cnt + N_NODES;
    int* off    = cursor + 4;
    int* csr    = off + N_NODES;

    const unsigned short* Bp1 = wpack + 0;
    const unsigned short* Bl1 = wpack + 16384;
    const unsigned short* Br1 = wpack + 32768;
    const unsigned short* Bp2 = wpack + 49152;
    const unsigned short* Bl2 = wpack + 65536;
    const unsigned short* Br2 = wpack + 81920;
    const unsigned short* Blin = wpack + 98304;

    const int RB32 = (N_NODES + 31) / 32;
    const int NPB  = (N_NODES + 255) / 256;

    hipLaunchKernelGGL(prep, dim3(PACK_BLOCKS + ZERO_BLOCKS + CVT_BLOCKS), dim3(256), 0, stream,
                       x, xbf, Wp1, Wl1, Wr1, Wp2, Wl2, Wr2, Wlin, wpack, deg);

    hipLaunchKernelGGL(count_deg_echo, dim3((2 * N_EDGES + 255) / 256), dim3(256), 0, stream,
                       ei, deg, out + (size_t)N_NODES * 256);
    hipLaunchKernelGGL(build_off, dim3(NPB), dim3(256), 0, stream, deg, off, cursor);
    hipLaunchKernelGGL(fill_csr, dim3((N_EDGES + 255) / 256), dim3(256), 0, stream,
                       ei, off, cnt, csr);

    // layer 1: y1 = xbf @ Wp1 + bp1
    hipLaunchKernelGGL((mfma_linear<8, false, 0, true, false, 8, 0, true>),
                       dim3(RB32), dim3(256), 0, stream,
                       xbf, nullptr, Bp1, nullptr, bp1, ybf, nullptr, nullptr, nullptr);
    hipLaunchKernelGGL(seg_max_bf, dim3(N_NODES / 4), dim3(256), 0, stream,
                       ybf, csr, off, deg, aggbf);

    // fused: h1 = gelu(agg@Wl1 + x@Wr1 + bl1) [store]; y2 = h1@Wp2 + bp2
    hipLaunchKernelGGL((mfma_linear<8, true, 1, true, true, 8, 0, true>),
                       dim3(RB32), dim3(256), 0, stream,
                       aggbf, xbf, Bl1, Br1, bl1, h1bf, Bp2, bp2, ybf);

    // layer 2
    hipLaunchKernelGGL(seg_max_bf, dim3(N_NODES / 4), dim3(256), 0, stream,
                       ybf, csr, off, deg, aggbf);

    // fused: h2 = gelu(agg@Wl2 + h1@Wr2 + bl2); out = gelu(h2@Wlin + blin) f32
    hipLaunchKernelGGL((mfma_linear<8, true, 1, false, true, 16, 1, false>),
                       dim3(RB32), dim3(256), 0, stream,
                       aggbf, h1bf, Bl2, Br2, bl2, nullptr, Blin, blin, out);
}

// Round 11
// 178.461 us; speedup vs baseline: 10.3533x; 1.1407x over previous
//
#include <hip/hip_runtime.h>

#define N_NODES 50000
#define N_EDGES 600000
#define HID 128

typedef __attribute__((ext_vector_type(8))) short short8;
typedef __attribute__((ext_vector_type(4))) float f32x4;

__device__ __forceinline__ unsigned short f2bf(float f) {
    unsigned u = __float_as_uint(f);
    unsigned r = u + 0x7FFFu + ((u >> 16) & 1u);  // RNE
    return (unsigned short)(r >> 16);
}
__device__ __forceinline__ float bf2f(unsigned short h) {
    return __uint_as_float(((unsigned)h) << 16);
}

// gelu(tanh approx) == x / (1 + exp(-2u)), u = 0.79788456*(x + 0.044715 x^3)
__device__ __forceinline__ float gelu_fast(float x) {
    float u = 0.7978845608028654f * (x + 0.044715f * x * x * x);
    return x / (1.0f + __expf(-2.0f * u));
}

// ---------------------------------------------------------------------------
// prep: weight pack (hi-only bf16) + zero deg/cursor + x f32->bf16.
// Pack layout (verified R3-R10): n = nt*16+(lane&15), k = ks*32+(lane>>4)*8+j.
// ---------------------------------------------------------------------------
#define PACK_BLOCKS 512          // 6 x 64 + 128 (Wlin)
#define ZERO_BLOCKS 49           // 12501 int4 = deg(50000)+cursor(4)
#define CVT_BLOCKS  3125         // 50000*128/8/256
__global__ void prep(const float* __restrict__ x, unsigned short* __restrict__ xbf,
                     const float* __restrict__ Wp1, const float* __restrict__ Wl1,
                     const float* __restrict__ Wr1, const float* __restrict__ Wp2,
                     const float* __restrict__ Wl2, const float* __restrict__ Wr2,
                     const float* __restrict__ Wlin, unsigned short* __restrict__ wpack,
                     int* __restrict__ zbase) {
    int b = blockIdx.x;
    if (b < PACK_BLOCKS) {
        const float* W;
        int base, idx;
        if (b < 384) {
            int which = b >> 6;
            switch (which) {
                case 0: W = Wp1; break;
                case 1: W = Wl1; break;
                case 2: W = Wr1; break;
                case 3: W = Wp2; break;
                case 4: W = Wl2; break;
                default: W = Wr2; break;
            }
            base = which * 16384;
            idx = (b & 63) * 256 + threadIdx.x;
        } else {
            W = Wlin;
            base = 98304;
            idx = (b - 384) * 256 + threadIdx.x;
        }
        int j = idx & 7;
        int lane = (idx >> 3) & 63;
        int ks = (idx >> 9) & 3;
        int nt = idx >> 11;
        int c = nt * 16 + (lane & 15);
        int k = ks * 32 + (lane >> 4) * 8 + j;
        wpack[base + idx] = f2bf(W[c * 128 + k]);
    } else if (b < PACK_BLOCKS + ZERO_BLOCKS) {
        int i = (b - PACK_BLOCKS) * 256 + threadIdx.x;
        if (i < 12501) ((int4*)zbase)[i] = make_int4(0, 0, 0, 0);
    } else {
        int tid = (b - PACK_BLOCKS - ZERO_BLOCKS) * 256 + threadIdx.x;
        size_t i8 = (size_t)tid * 8;
        if (i8 >= (size_t)N_NODES * HID) return;
        float4 v0 = *(const float4*)(x + i8);
        float4 v1 = *(const float4*)(x + i8 + 4);
        short8 o;
        o[0] = f2bf(v0.x); o[1] = f2bf(v0.y); o[2] = f2bf(v0.z); o[3] = f2bf(v0.w);
        o[4] = f2bf(v1.x); o[5] = f2bf(v1.y); o[6] = f2bf(v1.z); o[7] = f2bf(v1.w);
        *(short8*)(xbf + i8) = o;
    }
}

// count + rank: rank[e] = arrival order within dst segment (R11: moves the
// atomic out of the fill path; csr segment SETS stay fixed, max is
// order-invariant -> output bit-identical).
__global__ void count_rank(const int* __restrict__ ei, int* __restrict__ deg,
                           int* __restrict__ rank) {
    int e = blockIdx.x * 256 + threadIdx.x;
    if (e < N_EDGES) {
        int dst = ei[N_EDGES + e];
        rank[e] = atomicAdd(&deg[dst], 1);
    }
}

// One-kernel exclusive scan via atomic cursor (order-invariant downstream).
__global__ void build_off(const int* __restrict__ deg, int* __restrict__ off,
                          int* __restrict__ cursor) {
    __shared__ int sm[256];
    __shared__ int base;
    int t = threadIdx.x;
    int i = blockIdx.x * 256 + t;
    int v = (i < N_NODES) ? deg[i] : 0;
    sm[t] = v;
    __syncthreads();
    for (int s = 1; s < 256; s <<= 1) {
        int tv = (t >= s) ? sm[t - s] : 0;
        __syncthreads();
        sm[t] += tv;
        __syncthreads();
    }
    if (t == 255) base = atomicAdd(cursor, sm[255]);
    __syncthreads();
    if (i < N_NODES) off[i] = base + sm[t] - v;
}

// ---------------------------------------------------------------------------
// combo (R11): block-role split {csr-fill | edge echo | lin1} in ONE launch.
// The latency-bound scatter (fill) overlaps with compute-bound lin1 and the
// streaming echo. fill blocks first (longest tail). All three complete at the
// launch boundary; seg_max (next launch) needs ybf + csr.
// ---------------------------------------------------------------------------
#define FB   2344   // fill blocks (600000/256)
#define EB4  1172   // echo blocks (1200000/4/256)
#define LB   1563   // lin1 blocks (50000/32)
__global__ __launch_bounds__(256, 2) void combo(
        const int* __restrict__ ei, const int* __restrict__ off,
        const int* __restrict__ rank, int* __restrict__ csr,
        float* __restrict__ echo,
        const unsigned short* __restrict__ in1, const unsigned short* __restrict__ B1,
        const float* __restrict__ bias1, unsigned short* __restrict__ out1) {
    int b = blockIdx.x;
    int t = threadIdx.x;
    if (b < FB) {
        // ---- csr fill: pure scattered store (rank precomputed) ----
        int e = b * 256 + t;
        if (e < N_EDGES) {
            int dst = ei[N_EDGES + e];
            csr[off[dst] + rank[e]] = ei[e];
        }
        return;
    }
    if (b < FB + EB4) {
        // ---- edge echo, int4 -> float4 ----
        int idx = (b - FB) * 256 + t;
        int i = idx * 4;
        if (i < 2 * N_EDGES) {
            int4 v = *(const int4*)(ei + i);
            float4 f = make_float4((float)v.x, (float)v.y, (float)v.z, (float)v.w);
            *(float4*)(echo + i) = f;
        }
        return;
    }
    // ---- lin1: y1 = in1 @ B1 + bias1 (bf16 out), column-split 4 waves ----
    {
        __shared__ alignas(16) unsigned short hA[32][128];
        const int bid = b - FB - EB4;
        const int w = t >> 6;
        const int l = t & 63;
        const int blockRow = bid * 32;

        int r0 = blockRow + (l & 15);
        int r1 = r0 + 16;
        if (r0 > N_NODES - 1) r0 = N_NODES - 1;
        if (r1 > N_NODES - 1) r1 = N_NODES - 1;
        const int ko = (l >> 4) * 8;

        short8 a1[2][4];
#pragma unroll
        for (int ks = 0; ks < 4; ++ks) {
            a1[0][ks] = *(const short8*)(in1 + (size_t)r0 * HID + ks * 32 + ko);
            a1[1][ks] = *(const short8*)(in1 + (size_t)r1 * HID + ks * 32 + ko);
        }
        const int cL = l & 15;
        const int rfrag = (l >> 4) * 4;

        // depth-2 B prefetch ring (slots = step%3, static under full unroll)
        short8 b1r[3];
        const size_t gb = (size_t)(w * 8) * 64 + l;  // MY1=2 -> 8 steps
        b1r[0] = *(const short8*)(B1 + (gb + 0 * 64) * 8);
        b1r[1] = *(const short8*)(B1 + (gb + 1 * 64) * 8);
#pragma unroll
        for (int m = 0; m < 2; ++m) {
            const int nt = w * 2 + m;
            f32x4 acc0 = {0.f, 0.f, 0.f, 0.f};
            f32x4 acc1 = {0.f, 0.f, 0.f, 0.f};
#pragma unroll
            for (int ks = 0; ks < 4; ++ks) {
                const int step = m * 4 + ks;
                const int cur = step % 3;
                if (step + 2 < 8)
                    b1r[(step + 2) % 3] = *(const short8*)(B1 + (gb + (size_t)(step + 2) * 64) * 8);
                acc0 = __builtin_amdgcn_mfma_f32_16x16x32_bf16(a1[0][ks], b1r[cur], acc0, 0, 0, 0);
                acc1 = __builtin_amdgcn_mfma_f32_16x16x32_bf16(a1[1][ks], b1r[cur], acc1, 0, 0, 0);
            }
            float bc = bias1[nt * 16 + cL];
#pragma unroll
            for (int reg = 0; reg < 4; ++reg) {
                int rl = rfrag + reg;
                int cs = (nt * 16 + cL) ^ ((rl & 7) << 3);
                hA[rl][cs] = f2bf(acc0[reg] + bc);
                hA[rl + 16][cs] = f2bf(acc1[reg] + bc);
            }
        }
        __syncthreads();
#pragma unroll
        for (int p = 0; p < 2; ++p) {
            int idx = p * 256 + t;
            int row = idx >> 4;
            int c0 = (idx & 15) * 8;
            int cs0 = c0 ^ ((row & 7) << 3);
            short8 v = *(const short8*)&hA[row][cs0];
            int grow = blockRow + row;
            if (grow < N_NODES)
                *(short8*)(out1 + (size_t)grow * HID + c0) = v;
        }
    }
}

// ---------------------------------------------------------------------------
// Fused dual-GEMM + second-stage kernel (1-term bf16, depth-2 B ring).
// Stage 1: h = act1(bias1 + in1@W1 + in2@W2) -> swizzled hA; opt. bf16 store.
// Stage 2: out2 = act2(bias3 + h@W3); bf16 via hB or f32 via padded fT.
// ---------------------------------------------------------------------------
template <bool STORE1, int NT2, int ACT2, bool OBF2>
__global__ __launch_bounds__(256, 2) void mfma_fused(
        const unsigned short* __restrict__ in1, const unsigned short* __restrict__ in2,
        const unsigned short* __restrict__ B1, const unsigned short* __restrict__ B2,
        const float* __restrict__ bias1, void* __restrict__ out1,
        const unsigned short* __restrict__ B3, const float* __restrict__ bias3,
        void* __restrict__ out2) {
    __shared__ alignas(16) unsigned short hA[32][128];
    __shared__ alignas(16) unsigned short hB[OBF2 ? 32 : 1][128];
    __shared__ alignas(16) float fT[OBF2 ? 1 : 32][132];

    const int t = threadIdx.x;
    const int w = t >> 6;
    const int l = t & 63;
    const int blockRow = blockIdx.x * 32;

    int r0 = blockRow + (l & 15);
    int r1 = r0 + 16;
    if (r0 > N_NODES - 1) r0 = N_NODES - 1;
    if (r1 > N_NODES - 1) r1 = N_NODES - 1;
    const int ko = (l >> 4) * 8;

    short8 a1[2][4], a2[2][4];
#pragma unroll
    for (int ks = 0; ks < 4; ++ks) {
        a1[0][ks] = *(const short8*)(in1 + (size_t)r0 * HID + ks * 32 + ko);
        a1[1][ks] = *(const short8*)(in1 + (size_t)r1 * HID + ks * 32 + ko);
        a2[0][ks] = *(const short8*)(in2 + (size_t)r0 * HID + ks * 32 + ko);
        a2[1][ks] = *(const short8*)(in2 + (size_t)r1 * HID + ks * 32 + ko);
    }
    const int cL = l & 15;
    const int rfrag = (l >> 4) * 4;

    // ---- stage 1 (MY1=2 -> 8 steps), depth-2 ring on B1,B2 ----
    {
        short8 b1r[3], b2r[3];
        const size_t gb = (size_t)(w * 8) * 64 + l;
        b1r[0] = *(const short8*)(B1 + (gb + 0 * 64) * 8);
        b2r[0] = *(const short8*)(B2 + (gb + 0 * 64) * 8);
        b1r[1] = *(const short8*)(B1 + (gb + 1 * 64) * 8);
        b2r[1] = *(const short8*)(B2 + (gb + 1 * 64) * 8);
#pragma unroll
        for (int m = 0; m < 2; ++m) {
            const int nt = w * 2 + m;
            f32x4 acc0 = {0.f, 0.f, 0.f, 0.f};
            f32x4 acc1 = {0.f, 0.f, 0.f, 0.f};
#pragma unroll
            for (int ks = 0; ks < 4; ++ks) {
                const int step = m * 4 + ks;
                const int cur = step % 3;
                if (step + 2 < 8) {
                    const int s2 = (step + 2) % 3;
                    b1r[s2] = *(const short8*)(B1 + (gb + (size_t)(step + 2) * 64) * 8);
                    b2r[s2] = *(const short8*)(B2 + (gb + (size_t)(step + 2) * 64) * 8);
                }
                acc0 = __builtin_amdgcn_mfma_f32_16x16x32_bf16(a1[0][ks], b1r[cur], acc0, 0, 0, 0);
                acc1 = __builtin_amdgcn_mfma_f32_16x16x32_bf16(a1[1][ks], b1r[cur], acc1, 0, 0, 0);
                acc0 = __builtin_amdgcn_mfma_f32_16x16x32_bf16(a2[0][ks], b2r[cur], acc0, 0, 0, 0);
                acc1 = __builtin_amdgcn_mfma_f32_16x16x32_bf16(a2[1][ks], b2r[cur], acc1, 0, 0, 0);
            }
            float bc = bias1[nt * 16 + cL];
#pragma unroll
            for (int reg = 0; reg < 4; ++reg) {
                float v0 = gelu_fast(acc0[reg] + bc);
                float v1 = gelu_fast(acc1[reg] + bc);
                int rl = rfrag + reg;
                int cs = (nt * 16 + cL) ^ ((rl & 7) << 3);
                hA[rl][cs] = f2bf(v0);
                hA[rl + 16][cs] = f2bf(v1);
            }
        }
    }
    __syncthreads();

    if (STORE1) {
#pragma unroll
        for (int p = 0; p < 2; ++p) {
            int idx = p * 256 + t;
            int row = idx >> 4;
            int c0 = (idx & 15) * 8;
            int cs0 = c0 ^ ((row & 7) << 3);
            short8 v = *(const short8*)&hA[row][cs0];
            int grow = blockRow + row;
            if (grow < N_NODES)
                *(short8*)((unsigned short*)out1 + (size_t)grow * HID + c0) = v;
        }
    }

    // ---- stage 2: A-frags from hA ----
    short8 c1[2][4];
    const int rA = l & 15;
#pragma unroll
    for (int ks = 0; ks < 4; ++ks) {
        int b0 = (ks * 32 + ko) ^ ((rA & 7) << 3);
        c1[0][ks] = *(const short8*)&hA[rA][b0];
        c1[1][ks] = *(const short8*)&hA[rA + 16][b0];
    }
    if (OBF2) {
        // bf16 out (NT2=8 cols=128)
        short8 b1r[3];
        const size_t gb = (size_t)(w * 8) * 64 + l;
        b1r[0] = *(const short8*)(B3 + (gb + 0 * 64) * 8);
        b1r[1] = *(const short8*)(B3 + (gb + 1 * 64) * 8);
#pragma unroll
        for (int m = 0; m < 2; ++m) {
            const int nt = w * 2 + m;
            f32x4 acc0 = {0.f, 0.f, 0.f, 0.f};
            f32x4 acc1 = {0.f, 0.f, 0.f, 0.f};
#pragma unroll
            for (int ks = 0; ks < 4; ++ks) {
                const int step = m * 4 + ks;
                const int cur = step % 3;
                if (step + 2 < 8)
                    b1r[(step + 2) % 3] = *(const short8*)(B3 + (gb + (size_t)(step + 2) * 64) * 8);
                acc0 = __builtin_amdgcn_mfma_f32_16x16x32_bf16(c1[0][ks], b1r[cur], acc0, 0, 0, 0);
                acc1 = __builtin_amdgcn_mfma_f32_16x16x32_bf16(c1[1][ks], b1r[cur], acc1, 0, 0, 0);
            }
            float bc = bias3[nt * 16 + cL];
#pragma unroll
            for (int reg = 0; reg < 4; ++reg) {
                float v0 = acc0[reg] + bc;
                float v1 = acc1[reg] + bc;
                if (ACT2 == 1) { v0 = gelu_fast(v0); v1 = gelu_fast(v1); }
                int rl = rfrag + reg;
                int cs = (nt * 16 + cL) ^ ((rl & 7) << 3);
                hB[rl][cs] = f2bf(v0);
                hB[rl + 16][cs] = f2bf(v1);
            }
        }
        __syncthreads();
#pragma unroll
        for (int p = 0; p < 2; ++p) {
            int idx = p * 256 + t;
            int row = idx >> 4;
            int c0 = (idx & 15) * 8;
            int cs0 = c0 ^ ((row & 7) << 3);
            short8 v = *(const short8*)&hB[row][cs0];
            int grow = blockRow + row;
            if (grow < N_NODES)
                *(short8*)((unsigned short*)out2 + (size_t)grow * (NT2 * 16) + c0) = v;
        }
    } else {
        // f32 out (NT2=16, 256 cols) in two column-halves via fT
#pragma unroll
        for (int h = 0; h < 2; ++h) {
            const int ntb = h * 8 + w * 2;
            short8 b1r[3];
            const size_t gb = (size_t)(ntb * 4) * 64 + l;
            b1r[0] = *(const short8*)(B3 + (gb + 0 * 64) * 8);
            b1r[1] = *(const short8*)(B3 + (gb + 1 * 64) * 8);
#pragma unroll
            for (int m = 0; m < 2; ++m) {
                const int nt = ntb + m;
                f32x4 acc0 = {0.f, 0.f, 0.f, 0.f};
                f32x4 acc1 = {0.f, 0.f, 0.f, 0.f};
#pragma unroll
                for (int ks = 0; ks < 4; ++ks) {
                    const int step = m * 4 + ks;
                    const int cur = step % 3;
                    if (step + 2 < 8)
                        b1r[(step + 2) % 3] = *(const short8*)(B3 + (gb + (size_t)(step + 2) * 64) * 8);
                    acc0 = __builtin_amdgcn_mfma_f32_16x16x32_bf16(c1[0][ks], b1r[cur], acc0, 0, 0, 0);
                    acc1 = __builtin_amdgcn_mfma_f32_16x16x32_bf16(c1[1][ks], b1r[cur], acc1, 0, 0, 0);
                }
                float bc = bias3[nt * 16 + cL];
                int ct = (nt - h * 8) * 16 + cL;
#pragma unroll
                for (int reg = 0; reg < 4; ++reg) {
                    float v0 = acc0[reg] + bc;
                    float v1 = acc1[reg] + bc;
                    if (ACT2 == 1) { v0 = gelu_fast(v0); v1 = gelu_fast(v1); }
                    fT[rfrag + reg][ct] = v0;
                    fT[rfrag + reg + 16][ct] = v1;
                }
            }
            __syncthreads();
#pragma unroll
            for (int p = 0; p < 4; ++p) {
                int idx = p * 256 + t;
                int row = idx >> 5;
                int s4 = (idx & 31) * 4;
                float4 v = *(const float4*)&fT[row][s4];
                int grow = blockRow + row;
                if (grow < N_NODES)
                    *(float4*)((float*)out2 + (size_t)grow * 256 + h * 128 + s4) = v;
            }
            __syncthreads();
        }
    }
}

// ---------------------------------------------------------------------------
// Gather segment max over bf16 rows: one wave per node, ushort2 per lane.
// ---------------------------------------------------------------------------
__global__ __launch_bounds__(256) void seg_max_bf(const unsigned short* __restrict__ y,
                                                  const int* __restrict__ csr,
                                                  const int* __restrict__ off,
                                                  const int* __restrict__ deg,
                                                  unsigned short* __restrict__ agg) {
    int n = blockIdx.x * 4 + (threadIdx.x >> 6);
    int lane = threadIdx.x & 63;
    int s = off[n];
    int d = deg[n];
    const unsigned short* yb = y + lane * 2;
    float a0 = 0.f, a1 = 0.f;
    int i = 0;
    for (; i + 4 <= d; i += 4) {
        int s0 = csr[s + i], s1 = csr[s + i + 1], s2 = csr[s + i + 2], s3 = csr[s + i + 3];
        unsigned v0 = *(const unsigned*)(yb + (size_t)s0 * HID);
        unsigned v1 = *(const unsigned*)(yb + (size_t)s1 * HID);
        unsigned v2 = *(const unsigned*)(yb + (size_t)s2 * HID);
        unsigned v3 = *(const unsigned*)(yb + (size_t)s3 * HID);
        a0 = fmaxf(a0, fmaxf(fmaxf(__uint_as_float(v0 << 16), __uint_as_float(v1 << 16)),
                             fmaxf(__uint_as_float(v2 << 16), __uint_as_float(v3 << 16))));
        a1 = fmaxf(a1, fmaxf(fmaxf(__uint_as_float(v0 & 0xffff0000u), __uint_as_float(v1 & 0xffff0000u)),
                             fmaxf(__uint_as_float(v2 & 0xffff0000u), __uint_as_float(v3 & 0xffff0000u))));
    }
    for (; i < d; ++i) {
        int s0 = csr[s + i];
        unsigned v0 = *(const unsigned*)(yb + (size_t)s0 * HID);
        a0 = fmaxf(a0, __uint_as_float(v0 << 16));
        a1 = fmaxf(a1, __uint_as_float(v0 & 0xffff0000u));
    }
    unsigned o = (unsigned)f2bf(a0) | ((unsigned)f2bf(a1) << 16);
    *(unsigned*)(agg + (size_t)n * HID + lane * 2) = o;
}

extern "C" void kernel_launch(void* const* d_in, const int* in_sizes, int n_in,
                              void* d_out, int out_size, void* d_ws, size_t ws_size,
                              hipStream_t stream) {
    const float* x    = (const float*)d_in[0];
    const int*   ei   = (const int*)d_in[1];
    const float* Wp1  = (const float*)d_in[2];
    const float* bp1  = (const float*)d_in[3];
    const float* Wl1  = (const float*)d_in[4];
    const float* bl1  = (const float*)d_in[5];
    const float* Wr1  = (const float*)d_in[6];
    const float* Wp2  = (const float*)d_in[7];
    const float* bp2  = (const float*)d_in[8];
    const float* Wl2  = (const float*)d_in[9];
    const float* bl2  = (const float*)d_in[10];
    const float* Wr2  = (const float*)d_in[11];
    const float* Wlin = (const float*)d_in[12];
    const float* blin = (const float*)d_in[13];
    float* out = (float*)d_out;

    // ws layout (ushort units for bf16 region); wpack hi-only = 131072
    unsigned short* wpack = (unsigned short*)d_ws;
    unsigned short* xbf   = wpack + 131072;
    unsigned short* ybf   = xbf + (size_t)N_NODES * HID;
    unsigned short* aggbf = ybf + (size_t)N_NODES * HID;
    unsigned short* h1bf  = aggbf + (size_t)N_NODES * HID;
    int* deg    = (int*)(h1bf + (size_t)N_NODES * HID);  // 50000
    int* cursor = deg + N_NODES;                          // 4 (zeroed w/ deg)
    int* off    = cursor + 4;                             // 50000
    int* rank   = off + N_NODES;                          // 600000
    int* csr    = rank + N_EDGES;                         // 600000

    const unsigned short* Bp1 = wpack + 0;
    const unsigned short* Bl1 = wpack + 16384;
    const unsigned short* Br1 = wpack + 32768;
    const unsigned short* Bp2 = wpack + 49152;
    const unsigned short* Bl2 = wpack + 65536;
    const unsigned short* Br2 = wpack + 81920;
    const unsigned short* Blin = wpack + 98304;

    const int RB32 = (N_NODES + 31) / 32;   // 1563
    const int NPB  = (N_NODES + 255) / 256; // 196

    // 1. prep: pack weights + zero deg/cursor + convert x
    hipLaunchKernelGGL(prep, dim3(PACK_BLOCKS + ZERO_BLOCKS + CVT_BLOCKS), dim3(256), 0, stream,
                       x, xbf, Wp1, Wl1, Wr1, Wp2, Wl2, Wr2, Wlin, wpack, deg);

    // 2. count + rank
    hipLaunchKernelGGL(count_rank, dim3((N_EDGES + 255) / 256), dim3(256), 0, stream,
                       ei, deg, rank);

    // 3. offsets
    hipLaunchKernelGGL(build_off, dim3(NPB), dim3(256), 0, stream, deg, off, cursor);

    // 4. combo: csr-fill + edge-echo + lin1 (y1 = xbf@Wp1 + bp1), overlapped
    hipLaunchKernelGGL(combo, dim3(FB + EB4 + LB), dim3(256), 0, stream,
                       ei, off, rank, csr, out + (size_t)N_NODES * 256,
                       xbf, Bp1, bp1, ybf);

    // 5. seg_max layer 1
    hipLaunchKernelGGL(seg_max_bf, dim3(N_NODES / 4), dim3(256), 0, stream,
                       ybf, csr, off, deg, aggbf);

    // 6. fused: h1 = gelu(agg@Wl1 + x@Wr1 + bl1) [store]; y2 = h1@Wp2 + bp2
    hipLaunchKernelGGL((mfma_fused<true, 8, 0, true>), dim3(RB32), dim3(256), 0, stream,
                       aggbf, xbf, Bl1, Br1, bl1, h1bf, Bp2, bp2, ybf);

    // 7. seg_max layer 2
    hipLaunchKernelGGL(seg_max_bf, dim3(N_NODES / 4), dim3(256), 0, stream,
                       ybf, csr, off, deg, aggbf);

    // 8. fused: h2 = gelu(agg@Wl2 + h1@Wr2 + bl2); out = gelu(h2@Wlin + blin) f32
    hipLaunchKernelGGL((mfma_fused<false, 16, 1, false>), dim3(RB32), dim3(256), 0, stream,
                       aggbf, h1bf, Bl2, Br2, bl2, nullptr, Blin, blin, out);
}